// Round 3
// 804.117 us; speedup vs baseline: 1.0557x; 1.0557x over previous
//
#include <hip/hip_runtime.h>
#include <hip/hip_bf16.h>
#include <math.h>

typedef __hip_bfloat16 bf16;
typedef __attribute__((ext_vector_type(8))) short bf16x8;   // 8 bf16 (4 VGPRs)
typedef __attribute__((ext_vector_type(4))) float f32x4;

__device__ __forceinline__ float b2f(bf16 x){ return __bfloat162float(x); }
__device__ __forceinline__ bf16  f2b(float x){ return __float2bfloat16(x); }

// async global->LDS 16B (m97 pattern): LDS dest = wave-uniform base + lane*16
__device__ __forceinline__ void gld16(const bf16* g, bf16* l){
    __builtin_amdgcn_global_load_lds(
        (const __attribute__((address_space(1))) unsigned int*)g,
        (__attribute__((address_space(3))) unsigned int*)l, 16, 0, 0);
}

#define NTOK 197
#define NBATCH 64
#define NHEAD 8
#define DHEAD 96
#define DIMC 768
#define NROWS (NBATCH * NTOK)   // 12608
#define VTS 224                 // vt row stride (bf16), cols 197..223 zero-padded (by QKV epilogue)
#define SMS 206                 // LDS score row stride (f32): 52,736B -> 3 blocks/CU
#define SBS 224                 // bf16 P row stride (448B, 16B-aligned); aliases S (safe: reg-buffered)
#define MHALF 6304              // MLP row-chunk

// ---------------- workspace layout (bytes) ----------------
#define OFF_P   0ull
#define OFF_W   32768ull
#define SZ_QKVW 3538944ull
#define SZ_PRJW 1179648ull
#define SZ_M1W  4718592ull
#define SZ_M2W  4718592ull
#define OFF_H   14188544ull     // h -> ao -> mid(38.7MB spans OFF_H..OFF_K)
#define SZ_H    19365888ull
#define OFF_Q   33554432ull     // q
#define OFF_K   52920320ull     // k -> h2
#define OFF_V   72286208ull     // vt (22.02MB) -> x1b ; end 94,306,304 (< proven 96.9MB)

// ---------------- fused f32 -> bf16 weight convert (4 segments) ----------------
__global__ __launch_bounds__(256) void w_cvt_all(
    const float* __restrict__ s0, const float* __restrict__ s1,
    const float* __restrict__ s2, const float* __restrict__ s3, bf16* __restrict__ d)
{
    int i = blockIdx.x*256 + threadIdx.x;   // quad index, total 1,769,472
    const float* s; int off;
    if (i < 442368){ s=s0; off=i; }
    else if (i < 589824){ s=s1; off=i-442368; }
    else if (i < 1179648){ s=s2; off=i-589824; }
    else { s=s3; off=i-1179648; }
    float4 v = ((const float4*)s)[off];
    bf16 t[4] = {f2b(v.x), f2b(v.y), f2b(v.z), f2b(v.w)};
    ((ushort4*)d)[i] = *(ushort4*)t;
}

// ---------------- position-bias MLP (841 rows, tiny, all f32) ----------------
// NOTE: output is PREMIXED over heads: pout[idx][o] = sum_h pre_w[o,h] * p[idx,h]
__global__ __launch_bounds__(64) void pos_mlp(
    const float* __restrict__ biases, const float* __restrict__ pp_w, const float* __restrict__ pp_b,
    const float* __restrict__ ln1w, const float* __restrict__ ln1b,
    const float* __restrict__ f1w,  const float* __restrict__ f1b,
    const float* __restrict__ ln2w, const float* __restrict__ ln2b,
    const float* __restrict__ f2w,  const float* __restrict__ f2b,
    const float* __restrict__ ln3w, const float* __restrict__ ln3b,
    const float* __restrict__ f3w,  const float* __restrict__ f3b,
    const float* __restrict__ pre_w,
    float* __restrict__ pout)
{
    const int row = blockIdx.x, j = threadIdx.x;
    __shared__ float va[48], vb[48], pf[8];
    float b0 = biases[row*2], b1 = biases[row*2+1];
    if (j < 48) va[j] = b0*pp_w[j*2] + b1*pp_w[j*2+1] + pp_b[j];
    __syncthreads();
    {   float s=0.f, s2=0.f;
        for (int i=0;i<48;i++){ float t=va[i]; s+=t; s2+=t*t; }
        float mean=s*(1.f/48.f), var=s2*(1.f/48.f)-mean*mean, inv=rsqrtf(var+1e-5f);
        float r=0.f;
        if (j < 48){
            r = f1b[j];
            for (int i=0;i<48;i++){
                float t = fmaxf((va[i]-mean)*inv*ln1w[i] + ln1b[i], 0.f);
                r += t * f1w[j*48+i];
            }
        }
        __syncthreads();
        if (j < 48) vb[j] = r;
    }
    __syncthreads();
    {   float s=0.f, s2=0.f;
        for (int i=0;i<48;i++){ float t=vb[i]; s+=t; s2+=t*t; }
        float mean=s*(1.f/48.f), var=s2*(1.f/48.f)-mean*mean, inv=rsqrtf(var+1e-5f);
        float r=0.f;
        if (j < 48){
            r = f2b[j];
            for (int i=0;i<48;i++){
                float t = fmaxf((vb[i]-mean)*inv*ln2w[i] + ln2b[i], 0.f);
                r += t * f2w[j*48+i];
            }
        }
        __syncthreads();
        if (j < 48) va[j] = r;
    }
    __syncthreads();
    {   float s=0.f, s2=0.f;
        for (int i=0;i<48;i++){ float t=va[i]; s+=t; s2+=t*t; }
        float mean=s*(1.f/48.f), var=s2*(1.f/48.f)-mean*mean, inv=rsqrtf(var+1e-5f);
        if (j < 8){
            float r = f3b[j];
            for (int i=0;i<48;i++){
                float t = fmaxf((va[i]-mean)*inv*ln3w[i] + ln3b[i], 0.f);
                r += t * f3w[j*48+i];
            }
            pf[j] = r;
        }
    }
    __syncthreads();
    if (j < 8){
        float s = 0.f;
        #pragma unroll
        for (int hh=0; hh<8; hh++) s += pre_w[j*8+hh]*pf[hh];
        pout[row*8+j] = s;
    }
}

// ---------------- LayerNorm over 768 (f32 or bf16 in, bf16 out) ----------------
__device__ __forceinline__ float ldf(const bf16& x){ return __bfloat162float(x); }
__device__ __forceinline__ float ldf(const float& x){ return x; }

template<typename TIN>
__global__ __launch_bounds__(256) void ln768(
    const TIN* __restrict__ x, const float* __restrict__ w, const float* __restrict__ b,
    bf16* __restrict__ out)
{
    const int row = blockIdx.x, tid = threadIdx.x;
    const int wv = tid >> 6, ln = tid & 63;
    __shared__ float rs[4], rs2[4];
    const TIN* xr = x + (size_t)row * DIMC;
    float v0 = ldf(xr[tid]), v1 = ldf(xr[tid+256]), v2 = ldf(xr[tid+512]);
    float s = v0+v1+v2, s2 = v0*v0+v1*v1+v2*v2;
    #pragma unroll
    for (int off=32; off; off>>=1){ s += __shfl_xor(s,off,64); s2 += __shfl_xor(s2,off,64); }
    if (ln == 0){ rs[wv]=s; rs2[wv]=s2; }
    __syncthreads();
    s = rs[0]+rs[1]+rs[2]+rs[3]; s2 = rs2[0]+rs2[1]+rs2[2]+rs2[3];
    float mean = s*(1.f/768.f), var = s2*(1.f/768.f) - mean*mean;
    float inv = rsqrtf(var + 1e-5f);
    size_t base = (size_t)row * DIMC;
    out[base+tid]     = f2b((v0-mean)*inv*w[tid]     + b[tid]);
    out[base+tid+256] = f2b((v1-mean)*inv*w[tid+256] + b[tid+256]);
    out[base+tid+512] = f2b((v2-mean)*inv*w[tid+512] + b[tid+512]);
}

// ---------------- l2-normalize q,k rows (96 elems, bf16 in-place); q rows also * min(scale,100)
__global__ __launch_bounds__(256) void l2norm_qk(bf16* __restrict__ q, bf16* __restrict__ k,
                                                 const float* __restrict__ scale)
{
    const int wv = threadIdx.x >> 6, ln = threadIdx.x & 63;
    const size_t NR = (size_t)NBATCH*NHEAD*NTOK;
    size_t row = (size_t)blockIdx.x * 4 + wv;
    bool isq = row < NR;
    bf16* ptr = isq ? (q + row*DHEAD) : (k + (row-NR)*DHEAD);
    float x0 = b2f(ptr[ln]);
    float x1 = (ln < 32) ? b2f(ptr[64+ln]) : 0.f;
    float ss = x0*x0 + x1*x1;
    #pragma unroll
    for (int off=32; off; off>>=1) ss += __shfl_xor(ss,off,64);
    float inv = 1.f / fmaxf(sqrtf(ss), 1e-12f);
    if (isq){
        int h = (int)((row / NTOK) & (NHEAD-1));
        inv *= fminf(scale[h], 100.f);
    }
    ptr[ln] = f2b(x0*inv);
    if (ln < 32) ptr[64+ln] = f2b(x1*inv);
}

// ---------------- MFMA attention: XCD-swizzled 1D grid, (batch, 8-token q-tile) ----------------
// v2b: SMS 228->206 (3 blocks/CU via LDS alone; no min-waves clamp), premixed bias table,
//      scale folded into q, 16-lane-group softmax, PV V-prefetch + hoisted P fragments.
__global__ __launch_bounds__(256) void attn_mfma(
    const bf16* __restrict__ q, const bf16* __restrict__ k, const bf16* __restrict__ vt,
    const float* __restrict__ p,    // premixed (841 x 8, o-indexed)
    const float* __restrict__ pre_w, const float* __restrict__ post_w,
    bf16* __restrict__ ao)
{
    const int id = blockIdx.x;
    const int r8 = id & 7, t8 = id >> 3;
    const int bx = t8 % 25, b = r8 + 8*(t8/25);
    const int n0 = bx*8;
    const int tid = threadIdx.x, wv = tid>>6, ln = tid&63;
    const int fr = ln&15, fq = ln>>4;
    __shared__ float S[NHEAD*8*SMS];         // 52,736 B f32 scores
    __shared__ float s_pre[64], s_post[64];
    bf16* Sb = (bf16*)S;                     // P bf16 alias, row stride SBS=224 (448B)
    if (tid < 64){ s_pre[tid]=pre_w[tid]; s_post[tid]=post_w[tid]; }

    // ---- stage 1: raw (pre-scaled) scores S[h][nq][m], 13 K-tiles, 2-deep k prefetch
    #pragma unroll
    for (int hh=0; hh<2; hh++){
        const int h = wv + hh*4;
        int qr = n0 + fr; if (qr > 196) qr = 196;
        const bf16* qrow = q + ((size_t)(b*NHEAD+h)*NTOK + qr)*DHEAD + fq*8;
        bf16x8 a0 = *(const bf16x8*)(qrow);
        bf16x8 a1 = *(const bf16x8*)(qrow+32);
        bf16x8 a2 = *(const bf16x8*)(qrow+64);
        const bf16* kb0 = k + (size_t)(b*NHEAD+h)*NTOK*DHEAD + fq*8;
        auto krow = [&](int mt){ int nr = mt*16+fr; if (nr>196) nr=196; return kb0 + (size_t)nr*DHEAD; };
        const bf16* kp0 = krow(0);
        bf16x8 c00 = *(const bf16x8*)(kp0), c01 = *(const bf16x8*)(kp0+32), c02 = *(const bf16x8*)(kp0+64);
        const bf16* kp1 = krow(1);
        bf16x8 c10 = *(const bf16x8*)(kp1), c11 = *(const bf16x8*)(kp1+32), c12 = *(const bf16x8*)(kp1+64);
        #pragma unroll
        for (int mt=0; mt<13; mt++){
            bf16x8 p0, p1, p2;
            if (mt < 11){
                const bf16* kn = krow(mt+2);
                p0 = *(const bf16x8*)(kn); p1 = *(const bf16x8*)(kn+32); p2 = *(const bf16x8*)(kn+64);
            }
            f32x4 acc = {};
            acc = __builtin_amdgcn_mfma_f32_16x16x32_bf16(a0, c00, acc,0,0,0);
            acc = __builtin_amdgcn_mfma_f32_16x16x32_bf16(a1, c01, acc,0,0,0);
            acc = __builtin_amdgcn_mfma_f32_16x16x32_bf16(a2, c02, acc,0,0,0);
            int col = mt*16 + fr;
            if (fq < 2 && col < SMS){
                #pragma unroll
                for (int i=0;i<4;i++)
                    S[(h*8 + fq*4+i)*SMS + col] = acc[i];
            }
            c00=c10; c01=c11; c02=c12;
            if (mt < 11){ c10=p0; c11=p1; c12=p2; }
        }
    }
    __syncthreads();

    // ---- stage 2: premix + premixed bias + geometric mask (cols 197..205 -> -1e9)
    {
        const int sco[8] = {1,1,4,4,7,7,1000,1000};
        const int nq = tid >> 5, l32 = tid & 31;
        int n = n0 + nq; if (n > 196) n = 196;
        const bool nAlways = (n == 0);
        int ri=0, ci=0;
        if (!nAlways){ ri=(n-1)/14; ci=(n-1)-ri*14; }
        for (int m = l32; m < SMS; m += 32){
            if (m >= 197){
                #pragma unroll
                for (int o=0;o<8;o++) S[(o*8+nq)*SMS+m] = -1e9f;
                continue;
            }
            bool always = nAlways || (m==0);
            int rj=0, cj=0;
            if (m > 0){ rj=(m-1)/14; cj=(m-1)-rj*14; }
            int dr = ri-rj; if (dr<0) dr=-dr;
            int dc = ci-cj; if (dc<0) dc=-dc;
            int idx = always ? 730 : (ri-rj+13)*27 + (ci-cj+13);
            const float* pv = p + idx*8;
            float sh[8];
            #pragma unroll
            for (int h2=0;h2<8;h2++) sh[h2] = S[(h2*8+nq)*SMS+m];
            float ov[8];
            #pragma unroll
            for (int o=0;o<8;o++){
                float v = pv[o];
                #pragma unroll
                for (int h2=0;h2<8;h2++) v += s_pre[o*8+h2]*sh[h2];
                bool on = always || (dr<=sco[o] && dc<=sco[o]);
                ov[o] = on ? v : -1e9f;
            }
            #pragma unroll
            for (int o=0;o<8;o++) S[(o*8+nq)*SMS+m] = ov[o];
        }
    }
    __syncthreads();

    // ---- stage 3: softmax per (o,nq) row over 206 cols — 16-lane groups, 4 rows/wave concurrent
    {
        const int g = ln >> 4, l16 = ln & 15;
        #pragma unroll
        for (int rr=0; rr<4; rr++){
            float* row = &S[(wv*16 + rr*4 + g)*SMS];
            float mx = -3e38f;
            for (int m=l16; m<SMS; m+=16) mx = fmaxf(mx, row[m]);
            #pragma unroll
            for (int off=8; off; off>>=1) mx = fmaxf(mx, __shfl_xor(mx,off,64));
            float sum = 0.f;
            for (int m=l16; m<SMS; m+=16){ float e=__expf(row[m]-mx); row[m]=e; sum+=e; }
            #pragma unroll
            for (int off=8; off; off>>=1) sum += __shfl_xor(sum,off,64);
            float inv = 1.f/sum;
            for (int m=l16; m<SMS; m+=16) row[m] *= inv;
        }
    }
    __syncthreads();

    // ---- stage 3.5: postmix -> regs -> barrier -> bf16 P (stride SBS, pad cols zeroed)
    {
        const int nq = tid >> 5, l32 = tid & 31;
        float ov[7][8];
        #pragma unroll
        for (int kk=0; kk<7; kk++){
            int m = l32 + 32*kk;
            if (m < 197){
                float ph[8];
                #pragma unroll
                for (int o=0;o<8;o++) ph[o] = S[(o*8+nq)*SMS+m];
                #pragma unroll
                for (int o2=0;o2<8;o2++){
                    float v=0.f;
                    #pragma unroll
                    for (int o=0;o<8;o++) v += s_post[o2*8+o]*ph[o];
                    ov[kk][o2]=v;
                }
            }
        }
        __syncthreads();
        #pragma unroll
        for (int kk=0; kk<7; kk++){
            int m = l32 + 32*kk;   // covers 0..223 exactly
            #pragma unroll
            for (int o=0;o<8;o++)
                Sb[(o*8+nq)*SBS + m] = (m < 197) ? f2b(ov[kk][o]) : f2b(0.f);
        }
    }
    __syncthreads();

    // ---- stage 4: P @ V via MFMA; P frags hoisted, V double-buffered across dt
    const int frA = fr & 7;
    #pragma unroll
    for (int hh=0; hh<2; hh++){
        const int h = wv + hh*4;
        const bf16* vbase = vt + (size_t)(b*NHEAD+h)*DHEAD*VTS;
        bf16x8 pa[7];
        #pragma unroll
        for (int ks=0; ks<7; ks++)
            pa[ks] = *(const bf16x8*)(Sb + (h*8+frA)*SBS + ks*32 + fq*8);
        bf16x8 bv[7], bn[7];
        #pragma unroll
        for (int ks=0; ks<7; ks++)
            bv[ks] = *(const bf16x8*)(vbase + (size_t)fr*VTS + ks*32 + fq*8);
        #pragma unroll
        for (int dt=0; dt<6; dt++){
            if (dt < 5){
                #pragma unroll
                for (int ks=0; ks<7; ks++)
                    bn[ks] = *(const bf16x8*)(vbase + (size_t)((dt+1)*16+fr)*VTS + ks*32 + fq*8);
            }
            f32x4 acc = {};
            #pragma unroll
            for (int ks=0; ks<7; ks++)
                acc = __builtin_amdgcn_mfma_f32_16x16x32_bf16(pa[ks], bv[ks], acc,0,0,0);
            #pragma unroll
            for (int i=0;i<4;i++){
                int nq = fq*4+i, n = n0+nq;
                if (nq < 8 && n < NTOK)
                    ao[((size_t)b*NTOK+n)*DIMC + h*DHEAD + dt*16+fr] = f2b(acc[i]);
            }
            #pragma unroll
            for (int ks=0; ks<7; ks++) bv[ks] = bn[ks];
        }
    }
}

// ---------------- m97-style MFMA GEMM: 128x128 tile, BK=64 (2x 128x32 sub-tiles) ----------------
enum { EPI_QKV=0, EPI_X1=1, EPI_GELU=2, EPI_OUT=3 };

template<int EPI>
__global__ __launch_bounds__(256) void gemm128(
    const bf16* __restrict__ A, int lda, int M,
    const bf16* __restrict__ B, int ldb,
    int K,
    const float* __restrict__ bias,
    const float* __restrict__ resid_f,  // X1: x (f32)
    const bf16* __restrict__ resid_b,   // OUT: x1b
    float* __restrict__ dst_f,          // OUT: final out
    bf16* __restrict__ dst_b, int lddb, // X1: x1b ; GELU: mid
    int row_off,                        // OUT: global row offset
    bf16* __restrict__ qo, bf16* __restrict__ ko, bf16* __restrict__ vto)
{
    __shared__ bf16 As[2*128*32];   // two K-32 sub-tiles
    __shared__ bf16 Bs[2*128*32];
    const int tid = threadIdx.x;
    const int wv = tid >> 6, ln = tid & 63;
    const int fr = ln & 15, fq = ln >> 4;
    const int wr = (wv & 1)*64, wc = (wv >> 1)*64;
    const int m0 = blockIdx.y*128, n0 = blockIdx.x*128;
    const int lnrow = ln >> 2, lncol = (ln & 3)*8;
    f32x4 acc[4][4] = {};
    for (int k0=0; k0<K; k0+=64){
        #pragma unroll
        for (int t=0;t<2;t++){
            #pragma unroll
            for (int c=0;c<2;c++){
                int rA = m0 + (c*4+wv)*16 + lnrow;
                if (rA >= M) rA = M-1;
                gld16(A + (size_t)rA*lda + k0 + t*32 + lncol, &As[t*4096 + (c*4+wv)*16*32]);
                int rB = n0 + (c*4+wv)*16 + lnrow;
                gld16(B + (size_t)rB*ldb + k0 + t*32 + lncol, &Bs[t*4096 + (c*4+wv)*16*32]);
            }
        }
        __syncthreads();
        #pragma unroll
        for (int t=0;t<2;t++){
            bf16x8 af[4], bfv[4];
            #pragma unroll
            for (int i=0;i<4;i++){
                af[i]  = *(const bf16x8*)&As[t*4096 + (wr + i*16 + fr)*32 + fq*8];
                bfv[i] = *(const bf16x8*)&Bs[t*4096 + (wc + i*16 + fr)*32 + fq*8];
            }
            #pragma unroll
            for (int mi=0;mi<4;mi++)
                #pragma unroll
                for (int ni=0;ni<4;ni++)
                    acc[mi][ni] = __builtin_amdgcn_mfma_f32_16x16x32_bf16(af[mi], bfv[ni], acc[mi][ni],0,0,0);
        }
        __syncthreads();
    }
    #pragma unroll
    for (int mi=0;mi<4;mi++){
        #pragma unroll
        for (int ni=0;ni<4;ni++){
            #pragma unroll
            for (int i=0;i<4;i++){
                int row = m0 + wr + mi*16 + fq*4 + i;
                int col = n0 + wc + ni*16 + fr;
                if (row >= M) continue;
                float val = acc[mi][ni][i];
                if constexpr (EPI == EPI_QKV){
                    int which = col/768, rem = col - which*768;
                    int hh = rem/96, di = rem - hh*96;
                    int bb = row/NTOK, nn = row - bb*NTOK;
                    if (which == 0)      qo[(((size_t)bb*NHEAD+hh)*NTOK+nn)*DHEAD + di] = f2b(val);
                    else if (which == 1) ko[(((size_t)bb*NHEAD+hh)*NTOK+nn)*DHEAD + di] = f2b(val);
                    else {
                        vto[(((size_t)bb*NHEAD+hh)*DHEAD+di)*VTS + nn] = f2b(val);
                        if (nn < VTS - NTOK)   // fused vt pad-zero (cols 197..223)
                            vto[(((size_t)bb*NHEAD+hh)*DHEAD+di)*VTS + NTOK + nn] = f2b(0.f);
                    }
                } else if constexpr (EPI == EPI_X1){
                    dst_b[(size_t)row*DIMC + col] = f2b(val + bias[col] + resid_f[(size_t)row*DIMC + col]);
                } else if constexpr (EPI == EPI_GELU){
                    float t = val + bias[col];
                    t = 0.5f*t*(1.f + erff(t*0.70710678118654752f));
                    dst_b[(size_t)row*lddb + col] = f2b(t);
                } else { // EPI_OUT
                    size_t g = (size_t)(row + row_off)*DIMC + col;
                    dst_f[g] = val + bias[col] + b2f(resid_b[g]);
                }
            }
        }
    }
}

extern "C" void kernel_launch(void* const* d_in, const int* in_sizes, int n_in,
                              void* d_out, int out_size, void* d_ws, size_t ws_size,
                              hipStream_t stream)
{
    const float* x        = (const float*)d_in[0];
    const float* norm1_w  = (const float*)d_in[1];
    const float* norm1_b  = (const float*)d_in[2];
    const float* qkv_w    = (const float*)d_in[3];
    const float* scale    = (const float*)d_in[4];
    const float* pp_w     = (const float*)d_in[5];
    const float* pp_b     = (const float*)d_in[6];
    const float* ln1_w    = (const float*)d_in[7];
    const float* ln1_b    = (const float*)d_in[8];
    const float* fcp1_w   = (const float*)d_in[9];
    const float* fcp1_b   = (const float*)d_in[10];
    const float* ln2_w    = (const float*)d_in[11];
    const float* ln2_b    = (const float*)d_in[12];
    const float* fcp2_w   = (const float*)d_in[13];
    const float* fcp2_b   = (const float*)d_in[14];
    const float* ln3_w    = (const float*)d_in[15];
    const float* ln3_b    = (const float*)d_in[16];
    const float* fcp3_w   = (const float*)d_in[17];
    const float* fcp3_b   = (const float*)d_in[18];
    const float* pre_w    = (const float*)d_in[19];
    const float* post_w   = (const float*)d_in[20];
    const float* proj_w   = (const float*)d_in[21];
    const float* proj_b   = (const float*)d_in[22];
    const float* nrm2_w   = (const float*)d_in[23];
    const float* nrm2_b   = (const float*)d_in[24];
    const float* m1_w     = (const float*)d_in[25];
    const float* m1_b     = (const float*)d_in[26];
    const float* m2_w     = (const float*)d_in[27];
    const float* m2_b     = (const float*)d_in[28];
    const float* biases   = (const float*)d_in[30];
    float* out = (float*)d_out;

    char* ws = (char*)d_ws;
    float* p      = (float*)(ws + OFF_P);
    bf16*  qkvw_b = (bf16*)(ws + OFF_W);
    bf16*  prjw_b = (bf16*)(ws + OFF_W + SZ_QKVW);
    bf16*  m1w_b  = (bf16*)(ws + OFF_W + SZ_QKVW + SZ_PRJW);
    bf16*  m2w_b  = (bf16*)(ws + OFF_W + SZ_QKVW + SZ_PRJW + SZ_M1W);
    bf16*  h   = (bf16*)(ws + OFF_H);     // LN1 out -> ao -> mid (spans OFF_H..OFF_K)
    bf16*  qb  = (bf16*)(ws + OFF_Q);
    bf16*  kb  = (bf16*)(ws + OFF_K);     // -> h2
    bf16*  vt  = (bf16*)(ws + OFF_V);     // -> x1b
    bf16*  ao  = (bf16*)(ws + OFF_H);
    bf16*  x1b = (bf16*)(ws + OFF_V);
    bf16*  h2  = (bf16*)(ws + OFF_K);
    bf16*  mid = (bf16*)(ws + OFF_H);     // 6304x3072 bf16 = 38.7MB

    w_cvt_all<<<6912, 256, 0, stream>>>(qkv_w, proj_w, m1_w, m2_w, qkvw_b);
    pos_mlp<<<841, 64, 0, stream>>>(biases, pp_w, pp_b, ln1_w, ln1_b, fcp1_w, fcp1_b,
                                    ln2_w, ln2_b, fcp2_w, fcp2_b, ln3_w, ln3_b, fcp3_w, fcp3_b,
                                    pre_w, p);
    ln768<float><<<NROWS, 256, 0, stream>>>(x, norm1_w, norm1_b, h);
    gemm128<EPI_QKV><<<dim3(18, 99), 256, 0, stream>>>(
        h, DIMC, NROWS, qkvw_b, DIMC, DIMC, nullptr, nullptr, nullptr, nullptr,
        nullptr, 0, 0, qb, kb, vt);
    l2norm_qk<<<(NBATCH*NHEAD*NTOK*2)/4, 256, 0, stream>>>(qb, kb, scale);
    attn_mfma<<<1600, 256, 0, stream>>>(qb, kb, vt, p, pre_w, post_w, ao);
    gemm128<EPI_X1><<<dim3(6, 99), 256, 0, stream>>>(
        ao, DIMC, NROWS, prjw_b, DIMC, DIMC, proj_b, x, nullptr, nullptr,
        x1b, 0, 0, nullptr, nullptr, nullptr);
    ln768<bf16><<<NROWS, 256, 0, stream>>>(x1b, nrm2_w, nrm2_b, h2);
    for (int c=0; c<2; c++){
        const int r0 = c*MHALF;
        gemm128<EPI_GELU><<<dim3(24, 50), 256, 0, stream>>>(
            h2 + (size_t)r0*DIMC, DIMC, MHALF, m1w_b, DIMC, DIMC, m1_b,
            nullptr, nullptr, nullptr, mid, 3072, 0, nullptr, nullptr, nullptr);
        gemm128<EPI_OUT><<<dim3(6, 50), 256, 0, stream>>>(
            mid, 3072, MHALF, m2w_b, 3072, 3072, m2_b,
            nullptr, x1b, out, nullptr, 0, r0, nullptr, nullptr, nullptr);
    }
    (void)in_sizes; (void)n_in; (void)out_size; (void)ws_size;
}

// Round 5
// 787.053 us; speedup vs baseline: 1.0786x; 1.0217x over previous
//
#include <hip/hip_runtime.h>
#include <hip/hip_bf16.h>
#include <math.h>

typedef __hip_bfloat16 bf16;
typedef __attribute__((ext_vector_type(8))) short bf16x8;   // 8 bf16 (4 VGPRs)
typedef __attribute__((ext_vector_type(4))) float f32x4;

__device__ __forceinline__ float b2f(bf16 x){ return __bfloat162float(x); }
__device__ __forceinline__ bf16  f2b(float x){ return __float2bfloat16(x); }
__device__ __forceinline__ float us2f(unsigned short u){ bf16 t; *(unsigned short*)&t = u; return __bfloat162float(t); }

// async global->LDS 16B (m97 pattern): LDS dest = wave-uniform base + lane*16
__device__ __forceinline__ void gld16(const bf16* g, bf16* l){
    __builtin_amdgcn_global_load_lds(
        (const __attribute__((address_space(1))) unsigned int*)g,
        (__attribute__((address_space(3))) unsigned int*)l, 16, 0, 0);
}

#define NTOK 197
#define NBATCH 64
#define NHEAD 8
#define DHEAD 96
#define DIMC 768
#define NROWS (NBATCH * NTOK)   // 12608
#define VTS 224                 // vt row stride (bf16), cols 197..223 zero-padded (by QKV epilogue)
#define SMS 200                 // LDS score row stride (f32): 200%32==8 -> stage-3 concurrent rows 2-way free
#define SBS 224                 // bf16 P row stride (448B, 16B-aligned); aliases S (safe: reg-buffered)
#define MHALF 6304              // MLP row-chunk

// ---------------- workspace layout (bytes) ----------------
#define OFF_P   0ull
#define OFF_W   32768ull
#define SZ_QKVW 3538944ull
#define SZ_PRJW 1179648ull
#define SZ_M1W  4718592ull
#define SZ_M2W  4718592ull
#define OFF_H   14188544ull     // h -> ao -> mid(38.7MB spans OFF_H..OFF_K)
#define SZ_H    19365888ull
#define OFF_Q   33554432ull     // q
#define OFF_K   52920320ull     // k -> h2
#define OFF_V   72286208ull     // vt (22.02MB) -> x1b ; end 94,306,304 (< proven 96.9MB)

// ---------------- fused f32 -> bf16 weight convert (4 segments) ----------------
__global__ __launch_bounds__(256) void w_cvt_all(
    const float* __restrict__ s0, const float* __restrict__ s1,
    const float* __restrict__ s2, const float* __restrict__ s3, bf16* __restrict__ d)
{
    int i = blockIdx.x*256 + threadIdx.x;   // quad index, total 1,769,472
    const float* s; int off;
    if (i < 442368){ s=s0; off=i; }
    else if (i < 589824){ s=s1; off=i-442368; }
    else if (i < 1179648){ s=s2; off=i-589824; }
    else { s=s3; off=i-1179648; }
    float4 v = ((const float4*)s)[off];
    bf16 t[4] = {f2b(v.x), f2b(v.y), f2b(v.z), f2b(v.w)};
    ((ushort4*)d)[i] = *(ushort4*)t;
}

// ---------------- position-bias MLP (841 rows, tiny, all f32) ----------------
// NOTE: output is PREMIXED over heads: pout[idx][o] = sum_h pre_w[o,h] * p[idx,h]
__global__ __launch_bounds__(64) void pos_mlp(
    const float* __restrict__ biases, const float* __restrict__ pp_w, const float* __restrict__ pp_b,
    const float* __restrict__ ln1w, const float* __restrict__ ln1b,
    const float* __restrict__ f1w,  const float* __restrict__ f1b,
    const float* __restrict__ ln2w, const float* __restrict__ ln2b,
    const float* __restrict__ f2w,  const float* __restrict__ f2b,
    const float* __restrict__ ln3w, const float* __restrict__ ln3b,
    const float* __restrict__ f3w,  const float* __restrict__ f3b,
    const float* __restrict__ pre_w,
    float* __restrict__ pout)
{
    const int row = blockIdx.x, j = threadIdx.x;
    __shared__ float va[48], vb[48], pf[8];
    float b0 = biases[row*2], b1 = biases[row*2+1];
    if (j < 48) va[j] = b0*pp_w[j*2] + b1*pp_w[j*2+1] + pp_b[j];
    __syncthreads();
    {   float s=0.f, s2=0.f;
        for (int i=0;i<48;i++){ float t=va[i]; s+=t; s2+=t*t; }
        float mean=s*(1.f/48.f), var=s2*(1.f/48.f)-mean*mean, inv=rsqrtf(var+1e-5f);
        float r=0.f;
        if (j < 48){
            r = f1b[j];
            for (int i=0;i<48;i++){
                float t = fmaxf((va[i]-mean)*inv*ln1w[i] + ln1b[i], 0.f);
                r += t * f1w[j*48+i];
            }
        }
        __syncthreads();
        if (j < 48) vb[j] = r;
    }
    __syncthreads();
    {   float s=0.f, s2=0.f;
        for (int i=0;i<48;i++){ float t=vb[i]; s+=t; s2+=t*t; }
        float mean=s*(1.f/48.f), var=s2*(1.f/48.f)-mean*mean, inv=rsqrtf(var+1e-5f);
        float r=0.f;
        if (j < 48){
            r = f2b[j];
            for (int i=0;i<48;i++){
                float t = fmaxf((vb[i]-mean)*inv*ln2w[i] + ln2b[i], 0.f);
                r += t * f2w[j*48+i];
            }
        }
        __syncthreads();
        if (j < 48) va[j] = r;
    }
    __syncthreads();
    {   float s=0.f, s2=0.f;
        for (int i=0;i<48;i++){ float t=va[i]; s+=t; s2+=t*t; }
        float mean=s*(1.f/48.f), var=s2*(1.f/48.f)-mean*mean, inv=rsqrtf(var+1e-5f);
        if (j < 8){
            float r = f3b[j];
            for (int i=0;i<48;i++){
                float t = fmaxf((va[i]-mean)*inv*ln3w[i] + ln3b[i], 0.f);
                r += t * f3w[j*48+i];
            }
            pf[j] = r;
        }
    }
    __syncthreads();
    if (j < 8){
        float s = 0.f;
        #pragma unroll
        for (int hh=0; hh<8; hh++) s += pre_w[j*8+hh]*pf[hh];
        pout[row*8+j] = s;
    }
}

// ---------------- LayerNorm over 768 (f32 or bf16 in, bf16 out), vectorized loads ----------------
template<typename TIN>
__global__ __launch_bounds__(256) void ln768(
    const TIN* __restrict__ x, const float* __restrict__ w, const float* __restrict__ b,
    bf16* __restrict__ out)
{
    const int row = blockIdx.x, tid = threadIdx.x;
    const int wv = tid >> 6, ln = tid & 63;
    __shared__ float rs[4], rs2[4];
    const TIN* xr = x + (size_t)row * DIMC;
    float v[4] = {0.f,0.f,0.f,0.f};
    if (tid < 192){
        if constexpr (sizeof(TIN) == 4){
            float4 t4 = ((const float4*)xr)[tid];
            v[0]=t4.x; v[1]=t4.y; v[2]=t4.z; v[3]=t4.w;
        } else {
            ushort4 t4 = ((const ushort4*)xr)[tid];
            v[0]=us2f(t4.x); v[1]=us2f(t4.y); v[2]=us2f(t4.z); v[3]=us2f(t4.w);
        }
    }
    float s = v[0]+v[1]+v[2]+v[3];
    float s2 = v[0]*v[0]+v[1]*v[1]+v[2]*v[2]+v[3]*v[3];
    #pragma unroll
    for (int off=32; off; off>>=1){ s += __shfl_xor(s,off,64); s2 += __shfl_xor(s2,off,64); }
    if (ln == 0){ rs[wv]=s; rs2[wv]=s2; }
    __syncthreads();
    s = rs[0]+rs[1]+rs[2]+rs[3]; s2 = rs2[0]+rs2[1]+rs2[2]+rs2[3];
    float mean = s*(1.f/768.f), var = s2*(1.f/768.f) - mean*mean;
    float inv = rsqrtf(var + 1e-5f);
    if (tid < 192){
        float4 w4 = ((const float4*)w)[tid];
        float4 b4 = ((const float4*)b)[tid];
        bf16 o[4];
        o[0] = f2b((v[0]-mean)*inv*w4.x + b4.x);
        o[1] = f2b((v[1]-mean)*inv*w4.y + b4.y);
        o[2] = f2b((v[2]-mean)*inv*w4.z + b4.z);
        o[3] = f2b((v[3]-mean)*inv*w4.w + b4.w);
        ((ushort4*)(out + (size_t)row*DIMC))[tid] = *(ushort4*)o;
    }
}

// ---------------- l2-normalize q,k rows (96 elems, bf16 in-place); q rows also * min(scale,100)
// v3: 16-lane groups, bf16x8 loads (16B/lane), 16 rows per 256-thread block
__global__ __launch_bounds__(256) void l2norm_qk(bf16* __restrict__ q, bf16* __restrict__ k,
                                                 const float* __restrict__ scale)
{
    const int wv = threadIdx.x >> 6, ln = threadIdx.x & 63;
    const int g = ln >> 4, j = ln & 15;
    const size_t NR = (size_t)NBATCH*NHEAD*NTOK;
    size_t row = (size_t)blockIdx.x*16 + wv*4 + g;
    bool isq = row < NR;
    bf16* ptr = isq ? (q + row*DHEAD) : (k + (row-NR)*DHEAD);
    float xv[8];
    float ss = 0.f;
    if (j < 12){
        bf16x8 vv = *(const bf16x8*)(ptr + j*8);
        #pragma unroll
        for (int e=0;e<8;e++){ float f = us2f((unsigned short)vv[e]); xv[e]=f; ss += f*f; }
    }
    #pragma unroll
    for (int off=8; off; off>>=1) ss += __shfl_xor(ss, off, 64);
    float inv = 1.f / fmaxf(sqrtf(ss), 1e-12f);
    if (isq){
        int h = (int)((row / NTOK) & (NHEAD-1));
        inv *= fminf(scale[h], 100.f);
    }
    if (j < 12){
        bf16x8 ov;
        #pragma unroll
        for (int e=0;e<8;e++){ bf16 t = f2b(xv[e]*inv); ov[e] = *(short*)&t; }
        *(bf16x8*)(ptr + j*8) = ov;
    }
}

// ---------------- MFMA attention: XCD-swizzled 1D grid, (batch, 8-token q-tile) ----------------
// v3: SMS=200 (stride%32==8 -> softmax concurrent-row banks 2-way free), premixed bias table,
//     scale folded into q, 16-lane-group softmax, PV V-prefetch + hoisted P fragments.
__global__ __launch_bounds__(256) void attn_mfma(
    const bf16* __restrict__ q, const bf16* __restrict__ k, const bf16* __restrict__ vt,
    const float* __restrict__ p,    // premixed (841 x 8, o-indexed)
    const float* __restrict__ pre_w, const float* __restrict__ post_w,
    bf16* __restrict__ ao)
{
    const int id = blockIdx.x;
    const int r8 = id & 7, t8 = id >> 3;
    const int bx = t8 % 25, b = r8 + 8*(t8/25);
    const int n0 = bx*8;
    const int tid = threadIdx.x, wv = tid>>6, ln = tid&63;
    const int fr = ln&15, fq = ln>>4;
    __shared__ float S[NHEAD*8*SMS];         // 51,200 B f32 scores
    __shared__ float s_pre[64], s_post[64];
    bf16* Sb = (bf16*)S;                     // P bf16 alias, row stride SBS=224 (448B)
    if (tid < 64){ s_pre[tid]=pre_w[tid]; s_post[tid]=post_w[tid]; }

    // ---- stage 1: raw (pre-scaled) scores S[h][nq][m], 13 K-tiles, 2-deep k prefetch
    #pragma unroll
    for (int hh=0; hh<2; hh++){
        const int h = wv + hh*4;
        int qr = n0 + fr; if (qr > 196) qr = 196;
        const bf16* qrow = q + ((size_t)(b*NHEAD+h)*NTOK + qr)*DHEAD + fq*8;
        bf16x8 a0 = *(const bf16x8*)(qrow);
        bf16x8 a1 = *(const bf16x8*)(qrow+32);
        bf16x8 a2 = *(const bf16x8*)(qrow+64);
        const bf16* kb0 = k + (size_t)(b*NHEAD+h)*NTOK*DHEAD + fq*8;
        auto krow = [&](int mt){ int nr = mt*16+fr; if (nr>196) nr=196; return kb0 + (size_t)nr*DHEAD; };
        const bf16* kp0 = krow(0);
        bf16x8 c00 = *(const bf16x8*)(kp0), c01 = *(const bf16x8*)(kp0+32), c02 = *(const bf16x8*)(kp0+64);
        const bf16* kp1 = krow(1);
        bf16x8 c10 = *(const bf16x8*)(kp1), c11 = *(const bf16x8*)(kp1+32), c12 = *(const bf16x8*)(kp1+64);
        #pragma unroll
        for (int mt=0; mt<13; mt++){
            bf16x8 p0, p1, p2;
            if (mt < 11){
                const bf16* kn = krow(mt+2);
                p0 = *(const bf16x8*)(kn); p1 = *(const bf16x8*)(kn+32); p2 = *(const bf16x8*)(kn+64);
            }
            f32x4 acc = {};
            acc = __builtin_amdgcn_mfma_f32_16x16x32_bf16(a0, c00, acc,0,0,0);
            acc = __builtin_amdgcn_mfma_f32_16x16x32_bf16(a1, c01, acc,0,0,0);
            acc = __builtin_amdgcn_mfma_f32_16x16x32_bf16(a2, c02, acc,0,0,0);
            int col = mt*16 + fr;
            if (fq < 2 && col < SMS){
                #pragma unroll
                for (int i=0;i<4;i++)
                    S[(h*8 + fq*4+i)*SMS + col] = acc[i];
            }
            c00=c10; c01=c11; c02=c12;
            if (mt < 11){ c10=p0; c11=p1; c12=p2; }
        }
    }
    __syncthreads();

    // ---- stage 2: premix + premixed bias + geometric mask (cols 197..199 -> -1e9)
    {
        const int sco[8] = {1,1,4,4,7,7,1000,1000};
        const int nq = tid >> 5, l32 = tid & 31;
        int n = n0 + nq; if (n > 196) n = 196;
        const bool nAlways = (n == 0);
        int ri=0, ci=0;
        if (!nAlways){ ri=(n-1)/14; ci=(n-1)-ri*14; }
        for (int m = l32; m < SMS; m += 32){
            if (m >= 197){
                #pragma unroll
                for (int o=0;o<8;o++) S[(o*8+nq)*SMS+m] = -1e9f;
                continue;
            }
            bool always = nAlways || (m==0);
            int rj=0, cj=0;
            if (m > 0){ rj=(m-1)/14; cj=(m-1)-rj*14; }
            int dr = ri-rj; if (dr<0) dr=-dr;
            int dc = ci-cj; if (dc<0) dc=-dc;
            int idx = always ? 730 : (ri-rj+13)*27 + (ci-cj+13);
            const float* pv = p + idx*8;
            float sh[8];
            #pragma unroll
            for (int h2=0;h2<8;h2++) sh[h2] = S[(h2*8+nq)*SMS+m];
            float ov[8];
            #pragma unroll
            for (int o=0;o<8;o++){
                float v = pv[o];
                #pragma unroll
                for (int h2=0;h2<8;h2++) v += s_pre[o*8+h2]*sh[h2];
                bool on = always || (dr<=sco[o] && dc<=sco[o]);
                ov[o] = on ? v : -1e9f;
            }
            #pragma unroll
            for (int o=0;o<8;o++) S[(o*8+nq)*SMS+m] = ov[o];
        }
    }
    __syncthreads();

    // ---- stage 3: softmax per (o,nq) row over 200 cols — 16-lane groups, 4 rows/wave concurrent
    {
        const int g = ln >> 4, l16 = ln & 15;
        #pragma unroll
        for (int rr=0; rr<4; rr++){
            float* row = &S[(wv*16 + rr*4 + g)*SMS];
            float mx = -3e38f;
            for (int m=l16; m<SMS; m+=16) mx = fmaxf(mx, row[m]);
            #pragma unroll
            for (int off=8; off; off>>=1) mx = fmaxf(mx, __shfl_xor(mx,off,64));
            float sum = 0.f;
            for (int m=l16; m<SMS; m+=16){ float e=__expf(row[m]-mx); row[m]=e; sum+=e; }
            #pragma unroll
            for (int off=8; off; off>>=1) sum += __shfl_xor(sum,off,64);
            float inv = 1.f/sum;
            for (int m=l16; m<SMS; m+=16) row[m] *= inv;
        }
    }
    __syncthreads();

    // ---- stage 3.5: postmix -> regs -> barrier -> bf16 P (stride SBS, pad cols zeroed)
    {
        const int nq = tid >> 5, l32 = tid & 31;
        float ov[7][8];
        #pragma unroll
        for (int kk=0; kk<7; kk++){
            int m = l32 + 32*kk;
            if (m < 197){
                float ph[8];
                #pragma unroll
                for (int o=0;o<8;o++) ph[o] = S[(o*8+nq)*SMS+m];
                #pragma unroll
                for (int o2=0;o2<8;o2++){
                    float v=0.f;
                    #pragma unroll
                    for (int o=0;o<8;o++) v += s_post[o2*8+o]*ph[o];
                    ov[kk][o2]=v;
                }
            }
        }
        __syncthreads();
        #pragma unroll
        for (int kk=0; kk<7; kk++){
            int m = l32 + 32*kk;   // covers 0..223 exactly
            #pragma unroll
            for (int o=0;o<8;o++)
                Sb[(o*8+nq)*SBS + m] = (m < 197) ? f2b(ov[kk][o]) : f2b(0.f);
        }
    }
    __syncthreads();

    // ---- stage 4: P @ V via MFMA; P frags hoisted, V double-buffered across dt
    const int frA = fr & 7;
    #pragma unroll
    for (int hh=0; hh<2; hh++){
        const int h = wv + hh*4;
        const bf16* vbase = vt + (size_t)(b*NHEAD+h)*DHEAD*VTS;
        bf16x8 pa[7];
        #pragma unroll
        for (int ks=0; ks<7; ks++)
            pa[ks] = *(const bf16x8*)(Sb + (h*8+frA)*SBS + ks*32 + fq*8);
        bf16x8 bv[7], bn[7];
        #pragma unroll
        for (int ks=0; ks<7; ks++)
            bv[ks] = *(const bf16x8*)(vbase + (size_t)fr*VTS + ks*32 + fq*8);
        #pragma unroll
        for (int dt=0; dt<6; dt++){
            if (dt < 5){
                #pragma unroll
                for (int ks=0; ks<7; ks++)
                    bn[ks] = *(const bf16x8*)(vbase + (size_t)((dt+1)*16+fr)*VTS + ks*32 + fq*8);
            }
            f32x4 acc = {};
            #pragma unroll
            for (int ks=0; ks<7; ks++)
                acc = __builtin_amdgcn_mfma_f32_16x16x32_bf16(pa[ks], bv[ks], acc,0,0,0);
            #pragma unroll
            for (int i=0;i<4;i++){
                int nq = fq*4+i, n = n0+nq;
                if (nq < 8 && n < NTOK)
                    ao[((size_t)b*NTOK+n)*DIMC + h*DHEAD + dt*16+fr] = f2b(acc[i]);
            }
            #pragma unroll
            for (int ks=0; ks<7; ks++) bv[ks] = bn[ks];
        }
    }
}

// ---------------- m97-style MFMA GEMM: 128x128 tile, BK=64 (2x 128x32 sub-tiles) ----------------
enum { EPI_QKV=0, EPI_X1=1, EPI_GELU=2, EPI_OUT=3 };

template<int EPI>
__global__ __launch_bounds__(256) void gemm128(
    const bf16* __restrict__ A, int lda, int M,
    const bf16* __restrict__ B, int ldb,
    int K,
    const float* __restrict__ bias,
    const float* __restrict__ resid_f,  // X1: x (f32)
    const bf16* __restrict__ resid_b,   // OUT: x1b
    float* __restrict__ dst_f,          // OUT: final out
    bf16* __restrict__ dst_b, int lddb, // X1: x1b ; GELU: mid
    int row_off,                        // OUT: global row offset
    bf16* __restrict__ qo, bf16* __restrict__ ko, bf16* __restrict__ vto)
{
    __shared__ bf16 As[2*128*32];   // two K-32 sub-tiles
    __shared__ bf16 Bs[2*128*32];
    const int tid = threadIdx.x;
    const int wv = tid >> 6, ln = tid & 63;
    const int fr = ln & 15, fq = ln >> 4;
    const int wr = (wv & 1)*64, wc = (wv >> 1)*64;
    const int m0 = blockIdx.y*128, n0 = blockIdx.x*128;
    const int lnrow = ln >> 2, lncol = (ln & 3)*8;
    f32x4 acc[4][4] = {};
    for (int k0=0; k0<K; k0+=64){
        #pragma unroll
        for (int t=0;t<2;t++){
            #pragma unroll
            for (int c=0;c<2;c++){
                int rA = m0 + (c*4+wv)*16 + lnrow;
                if (rA >= M) rA = M-1;
                gld16(A + (size_t)rA*lda + k0 + t*32 + lncol, &As[t*4096 + (c*4+wv)*16*32]);
                int rB = n0 + (c*4+wv)*16 + lnrow;
                gld16(B + (size_t)rB*ldb + k0 + t*32 + lncol, &Bs[t*4096 + (c*4+wv)*16*32]);
            }
        }
        __syncthreads();
        #pragma unroll
        for (int t=0;t<2;t++){
            bf16x8 af[4], bfv[4];
            #pragma unroll
            for (int i=0;i<4;i++){
                af[i]  = *(const bf16x8*)&As[t*4096 + (wr + i*16 + fr)*32 + fq*8];
                bfv[i] = *(const bf16x8*)&Bs[t*4096 + (wc + i*16 + fr)*32 + fq*8];
            }
            #pragma unroll
            for (int mi=0;mi<4;mi++)
                #pragma unroll
                for (int ni=0;ni<4;ni++)
                    acc[mi][ni] = __builtin_amdgcn_mfma_f32_16x16x32_bf16(af[mi], bfv[ni], acc[mi][ni],0,0,0);
        }
        __syncthreads();
    }
    #pragma unroll
    for (int mi=0;mi<4;mi++){
        #pragma unroll
        for (int ni=0;ni<4;ni++){
            #pragma unroll
            for (int i=0;i<4;i++){
                int row = m0 + wr + mi*16 + fq*4 + i;
                int col = n0 + wc + ni*16 + fr;
                if (row >= M) continue;
                float val = acc[mi][ni][i];
                if constexpr (EPI == EPI_QKV){
                    int which = col/768, rem = col - which*768;
                    int hh = rem/96, di = rem - hh*96;
                    int bb = row/NTOK, nn = row - bb*NTOK;
                    if (which == 0)      qo[(((size_t)bb*NHEAD+hh)*NTOK+nn)*DHEAD + di] = f2b(val);
                    else if (which == 1) ko[(((size_t)bb*NHEAD+hh)*NTOK+nn)*DHEAD + di] = f2b(val);
                    else {
                        vto[(((size_t)bb*NHEAD+hh)*DHEAD+di)*VTS + nn] = f2b(val);
                        if (nn < VTS - NTOK)   // fused vt pad-zero (cols 197..223)
                            vto[(((size_t)bb*NHEAD+hh)*DHEAD+di)*VTS + NTOK + nn] = f2b(0.f);
                    }
                } else if constexpr (EPI == EPI_X1){
                    dst_b[(size_t)row*DIMC + col] = f2b(val + bias[col] + resid_f[(size_t)row*DIMC + col]);
                } else if constexpr (EPI == EPI_GELU){
                    float t = val + bias[col];
                    t = 0.5f*t*(1.f + erff(t*0.70710678118654752f));
                    dst_b[(size_t)row*lddb + col] = f2b(t);
                } else { // EPI_OUT
                    size_t g = (size_t)(row + row_off)*DIMC + col;
                    dst_f[g] = val + bias[col] + b2f(resid_b[g]);
                }
            }
        }
    }
}

extern "C" void kernel_launch(void* const* d_in, const int* in_sizes, int n_in,
                              void* d_out, int out_size, void* d_ws, size_t ws_size,
                              hipStream_t stream)
{
    const float* x        = (const float*)d_in[0];
    const float* norm1_w  = (const float*)d_in[1];
    const float* norm1_b  = (const float*)d_in[2];
    const float* qkv_w    = (const float*)d_in[3];
    const float* scale    = (const float*)d_in[4];
    const float* pp_w     = (const float*)d_in[5];
    const float* pp_b     = (const float*)d_in[6];
    const float* ln1_w    = (const float*)d_in[7];
    const float* ln1_b    = (const float*)d_in[8];
    const float* fcp1_w   = (const float*)d_in[9];
    const float* fcp1_b   = (const float*)d_in[10];
    const float* ln2_w    = (const float*)d_in[11];
    const float* ln2_b    = (const float*)d_in[12];
    const float* fcp2_w   = (const float*)d_in[13];
    const float* fcp2_b   = (const float*)d_in[14];
    const float* ln3_w    = (const float*)d_in[15];
    const float* ln3_b    = (const float*)d_in[16];
    const float* fcp3_w   = (const float*)d_in[17];
    const float* fcp3_b   = (const float*)d_in[18];
    const float* pre_w    = (const float*)d_in[19];
    const float* post_w   = (const float*)d_in[20];
    const float* proj_w   = (const float*)d_in[21];
    const float* proj_b   = (const float*)d_in[22];
    const float* nrm2_w   = (const float*)d_in[23];
    const float* nrm2_b   = (const float*)d_in[24];
    const float* m1_w     = (const float*)d_in[25];
    const float* m1_b     = (const float*)d_in[26];
    const float* m2_w     = (const float*)d_in[27];
    const float* m2_b     = (const float*)d_in[28];
    const float* biases   = (const float*)d_in[30];
    float* out = (float*)d_out;

    char* ws = (char*)d_ws;
    float* p      = (float*)(ws + OFF_P);
    bf16*  qkvw_b = (bf16*)(ws + OFF_W);
    bf16*  prjw_b = (bf16*)(ws + OFF_W + SZ_QKVW);
    bf16*  m1w_b  = (bf16*)(ws + OFF_W + SZ_QKVW + SZ_PRJW);
    bf16*  m2w_b  = (bf16*)(ws + OFF_W + SZ_QKVW + SZ_PRJW + SZ_M1W);
    bf16*  h   = (bf16*)(ws + OFF_H);     // LN1 out -> ao -> mid (spans OFF_H..OFF_K)
    bf16*  qb  = (bf16*)(ws + OFF_Q);
    bf16*  kb  = (bf16*)(ws + OFF_K);     // -> h2
    bf16*  vt  = (bf16*)(ws + OFF_V);     // -> x1b
    bf16*  ao  = (bf16*)(ws + OFF_H);
    bf16*  x1b = (bf16*)(ws + OFF_V);
    bf16*  h2  = (bf16*)(ws + OFF_K);
    bf16*  mid = (bf16*)(ws + OFF_H);     // 6304x3072 bf16 = 38.7MB

    w_cvt_all<<<6912, 256, 0, stream>>>(qkv_w, proj_w, m1_w, m2_w, qkvw_b);
    pos_mlp<<<841, 64, 0, stream>>>(biases, pp_w, pp_b, ln1_w, ln1_b, fcp1_w, fcp1_b,
                                    ln2_w, ln2_b, fcp2_w, fcp2_b, ln3_w, ln3_b, fcp3_w, fcp3_b,
                                    pre_w, p);
    ln768<float><<<NROWS, 256, 0, stream>>>(x, norm1_w, norm1_b, h);
    gemm128<EPI_QKV><<<dim3(18, 99), 256, 0, stream>>>(
        h, DIMC, NROWS, qkvw_b, DIMC, DIMC, nullptr, nullptr, nullptr, nullptr,
        nullptr, 0, 0, qb, kb, vt);
    l2norm_qk<<<(NBATCH*NHEAD*NTOK*2)/16, 256, 0, stream>>>(qb, kb, scale);
    attn_mfma<<<1600, 256, 0, stream>>>(qb, kb, vt, p, pre_w, post_w, ao);
    gemm128<EPI_X1><<<dim3(6, 99), 256, 0, stream>>>(
        ao, DIMC, NROWS, prjw_b, DIMC, DIMC, proj_b, x, nullptr, nullptr,
        x1b, 0, 0, nullptr, nullptr, nullptr);
    ln768<bf16><<<NROWS, 256, 0, stream>>>(x1b, nrm2_w, nrm2_b, h2);
    for (int c=0; c<2; c++){
        const int r0 = c*MHALF;
        gemm128<EPI_GELU><<<dim3(24, 50), 256, 0, stream>>>(
            h2 + (size_t)r0*DIMC, DIMC, MHALF, m1w_b, DIMC, DIMC, m1_b,
            nullptr, nullptr, nullptr, mid, 3072, 0, nullptr, nullptr, nullptr);
        gemm128<EPI_OUT><<<dim3(6, 50), 256, 0, stream>>>(
            mid, 3072, MHALF, m2w_b, 3072, 3072, m2_b,
            nullptr, x1b, out, nullptr, 0, r0, nullptr, nullptr, nullptr);
    }
    (void)in_sizes; (void)n_in; (void)out_size; (void)ws_size;
}

// Round 6
// 786.555 us; speedup vs baseline: 1.0793x; 1.0006x over previous
//
#include <hip/hip_runtime.h>
#include <hip/hip_bf16.h>
#include <math.h>

typedef __hip_bfloat16 bf16;
typedef __attribute__((ext_vector_type(8))) short bf16x8;   // 8 bf16 (4 VGPRs)
typedef __attribute__((ext_vector_type(4))) float f32x4;

__device__ __forceinline__ float b2f(bf16 x){ return __bfloat162float(x); }
__device__ __forceinline__ bf16  f2b(float x){ return __float2bfloat16(x); }
__device__ __forceinline__ float us2f(unsigned short u){ bf16 t; *(unsigned short*)&t = u; return __bfloat162float(t); }

// async global->LDS 16B (m97 pattern): LDS dest = wave-uniform base + lane*16
__device__ __forceinline__ void gld16(const bf16* g, bf16* l){
    __builtin_amdgcn_global_load_lds(
        (const __attribute__((address_space(1))) unsigned int*)g,
        (__attribute__((address_space(3))) unsigned int*)l, 16, 0, 0);
}

#define NTOK 197
#define NBATCH 64
#define NHEAD 8
#define DHEAD 96
#define DIMC 768
#define NROWS (NBATCH * NTOK)   // 12608
#define VTS 224                 // vt row stride (bf16), cols 197..223 zero-padded (by QKV epilogue)
#define SMS 200                 // LDS score row stride (f32)
#define SBS 224                 // bf16 P row stride (448B, 16B-aligned); aliases S (barrier-fenced)
#define MHALF 6304              // MLP row-chunk

// ---------------- workspace layout (bytes) ----------------
#define OFF_P   0ull
#define OFF_W   32768ull
#define SZ_QKVW 3538944ull
#define SZ_PRJW 1179648ull
#define SZ_M1W  4718592ull
#define SZ_M2W  4718592ull
#define OFF_H   14188544ull     // h -> ao -> mid(38.7MB spans OFF_H..OFF_K)
#define SZ_H    19365888ull
#define OFF_Q   33554432ull     // q
#define OFF_K   52920320ull     // k -> h2
#define OFF_V   72286208ull     // vt (22.02MB) -> x1b ; end 94,306,304 (< proven 96.9MB)

// ---------------- fused f32 -> bf16 weight convert (4 segments) ----------------
__global__ __launch_bounds__(256) void w_cvt_all(
    const float* __restrict__ s0, const float* __restrict__ s1,
    const float* __restrict__ s2, const float* __restrict__ s3, bf16* __restrict__ d)
{
    int i = blockIdx.x*256 + threadIdx.x;   // quad index, total 1,769,472
    const float* s; int off;
    if (i < 442368){ s=s0; off=i; }
    else if (i < 589824){ s=s1; off=i-442368; }
    else if (i < 1179648){ s=s2; off=i-589824; }
    else { s=s3; off=i-1179648; }
    float4 v = ((const float4*)s)[off];
    bf16 t[4] = {f2b(v.x), f2b(v.y), f2b(v.z), f2b(v.w)};
    ((ushort4*)d)[i] = *(ushort4*)t;
}

// ---------------- position-bias MLP (841 rows, tiny, all f32) ----------------
// NOTE: output is PREMIXED over heads: pout[idx][o] = sum_h pre_w[o,h] * p[idx,h]
__global__ __launch_bounds__(64) void pos_mlp(
    const float* __restrict__ biases, const float* __restrict__ pp_w, const float* __restrict__ pp_b,
    const float* __restrict__ ln1w, const float* __restrict__ ln1b,
    const float* __restrict__ f1w,  const float* __restrict__ f1b,
    const float* __restrict__ ln2w, const float* __restrict__ ln2b,
    const float* __restrict__ f2w,  const float* __restrict__ f2b,
    const float* __restrict__ ln3w, const float* __restrict__ ln3b,
    const float* __restrict__ f3w,  const float* __restrict__ f3b,
    const float* __restrict__ pre_w,
    float* __restrict__ pout)
{
    const int row = blockIdx.x, j = threadIdx.x;
    __shared__ float va[48], vb[48], pf[8];
    float b0 = biases[row*2], b1 = biases[row*2+1];
    if (j < 48) va[j] = b0*pp_w[j*2] + b1*pp_w[j*2+1] + pp_b[j];
    __syncthreads();
    {   float s=0.f, s2=0.f;
        for (int i=0;i<48;i++){ float t=va[i]; s+=t; s2+=t*t; }
        float mean=s*(1.f/48.f), var=s2*(1.f/48.f)-mean*mean, inv=rsqrtf(var+1e-5f);
        float r=0.f;
        if (j < 48){
            r = f1b[j];
            for (int i=0;i<48;i++){
                float t = fmaxf((va[i]-mean)*inv*ln1w[i] + ln1b[i], 0.f);
                r += t * f1w[j*48+i];
            }
        }
        __syncthreads();
        if (j < 48) vb[j] = r;
    }
    __syncthreads();
    {   float s=0.f, s2=0.f;
        for (int i=0;i<48;i++){ float t=vb[i]; s+=t; s2+=t*t; }
        float mean=s*(1.f/48.f), var=s2*(1.f/48.f)-mean*mean, inv=rsqrtf(var+1e-5f);
        float r=0.f;
        if (j < 48){
            r = f2b[j];
            for (int i=0;i<48;i++){
                float t = fmaxf((vb[i]-mean)*inv*ln2w[i] + ln2b[i], 0.f);
                r += t * f2w[j*48+i];
            }
        }
        __syncthreads();
        if (j < 48) va[j] = r;
    }
    __syncthreads();
    {   float s=0.f, s2=0.f;
        for (int i=0;i<48;i++){ float t=va[i]; s+=t; s2+=t*t; }
        float mean=s*(1.f/48.f), var=s2*(1.f/48.f)-mean*mean, inv=rsqrtf(var+1e-5f);
        if (j < 8){
            float r = f3b[j];
            for (int i=0;i<48;i++){
                float t = fmaxf((va[i]-mean)*inv*ln3w[i] + ln3b[i], 0.f);
                r += t * f3w[j*48+i];
            }
            pf[j] = r;
        }
    }
    __syncthreads();
    if (j < 8){
        float s = 0.f;
        #pragma unroll
        for (int hh=0; hh<8; hh++) s += pre_w[j*8+hh]*pf[hh];
        pout[row*8+j] = s;
    }
}

// ---------------- LayerNorm over 768 (f32 or bf16 in, bf16 out), vectorized loads ----------------
template<typename TIN>
__global__ __launch_bounds__(256) void ln768(
    const TIN* __restrict__ x, const float* __restrict__ w, const float* __restrict__ b,
    bf16* __restrict__ out)
{
    const int row = blockIdx.x, tid = threadIdx.x;
    const int wv = tid >> 6, ln = tid & 63;
    __shared__ float rs[4], rs2[4];
    const TIN* xr = x + (size_t)row * DIMC;
    float v[4] = {0.f,0.f,0.f,0.f};
    if (tid < 192){
        if constexpr (sizeof(TIN) == 4){
            float4 t4 = ((const float4*)xr)[tid];
            v[0]=t4.x; v[1]=t4.y; v[2]=t4.z; v[3]=t4.w;
        } else {
            ushort4 t4 = ((const ushort4*)xr)[tid];
            v[0]=us2f(t4.x); v[1]=us2f(t4.y); v[2]=us2f(t4.z); v[3]=us2f(t4.w);
        }
    }
    float s = v[0]+v[1]+v[2]+v[3];
    float s2 = v[0]*v[0]+v[1]*v[1]+v[2]*v[2]+v[3]*v[3];
    #pragma unroll
    for (int off=32; off; off>>=1){ s += __shfl_xor(s,off,64); s2 += __shfl_xor(s2,off,64); }
    if (ln == 0){ rs[wv]=s; rs2[wv]=s2; }
    __syncthreads();
    s = rs[0]+rs[1]+rs[2]+rs[3]; s2 = rs2[0]+rs2[1]+rs2[2]+rs2[3];
    float mean = s*(1.f/768.f), var = s2*(1.f/768.f) - mean*mean;
    float inv = rsqrtf(var + 1e-5f);
    if (tid < 192){
        float4 w4 = ((const float4*)w)[tid];
        float4 b4 = ((const float4*)b)[tid];
        bf16 o[4];
        o[0] = f2b((v[0]-mean)*inv*w4.x + b4.x);
        o[1] = f2b((v[1]-mean)*inv*w4.y + b4.y);
        o[2] = f2b((v[2]-mean)*inv*w4.z + b4.z);
        o[3] = f2b((v[3]-mean)*inv*w4.w + b4.w);
        ((ushort4*)(out + (size_t)row*DIMC))[tid] = *(ushort4*)o;
    }
}

// ---------------- l2-normalize q,k rows (96 elems, bf16 in-place); q rows also * min(scale,100)
__global__ __launch_bounds__(256) void l2norm_qk(bf16* __restrict__ q, bf16* __restrict__ k,
                                                 const float* __restrict__ scale)
{
    const int wv = threadIdx.x >> 6, ln = threadIdx.x & 63;
    const int g = ln >> 4, j = ln & 15;
    const size_t NR = (size_t)NBATCH*NHEAD*NTOK;
    size_t row = (size_t)blockIdx.x*16 + wv*4 + g;
    bool isq = row < NR;
    bf16* ptr = isq ? (q + row*DHEAD) : (k + (row-NR)*DHEAD);
    float xv[8];
    float ss = 0.f;
    if (j < 12){
        bf16x8 vv = *(const bf16x8*)(ptr + j*8);
        #pragma unroll
        for (int e=0;e<8;e++){ float f = us2f((unsigned short)vv[e]); xv[e]=f; ss += f*f; }
    }
    #pragma unroll
    for (int off=8; off; off>>=1) ss += __shfl_xor(ss, off, 64);
    float inv = 1.f / fmaxf(sqrtf(ss), 1e-12f);
    if (isq){
        int h = (int)((row / NTOK) & (NHEAD-1));
        inv *= fminf(scale[h], 100.f);
    }
    if (j < 12){
        bf16x8 ov;
        #pragma unroll
        for (int e=0;e<8;e++){ bf16 t = f2b(xv[e]*inv); ov[e] = *(short*)&t; }
        *(bf16x8*)(ptr + j*8) = ov;
    }
}

// ---------------- MFMA attention ----------------
// v4: in-register softmax. Stage-2 lane mapping (nq=tid>>5, m=l32+32kk) holds the premixed
// scores in regs p_[7][8]; lane-local max -> 32-lane shfl reduce (row lives in one 32-group);
// exp in regs; 1/L folded into postmix. Deletes stage 3 + 2 barriers + ~110 LDS ops/lane.
__global__ __launch_bounds__(256) void attn_mfma(
    const bf16* __restrict__ q, const bf16* __restrict__ k, const bf16* __restrict__ vt,
    const float* __restrict__ p,    // premixed (841 x 8, o-indexed)
    const float* __restrict__ pre_w, const float* __restrict__ post_w,
    bf16* __restrict__ ao)
{
    const int id = blockIdx.x;
    const int r8 = id & 7, t8 = id >> 3;
    const int bx = t8 % 25, b = r8 + 8*(t8/25);
    const int n0 = bx*8;
    const int tid = threadIdx.x, wv = tid>>6, ln = tid&63;
    const int fr = ln&15, fq = ln>>4;
    __shared__ float S[NHEAD*8*SMS];         // 51,200 B f32 scores
    __shared__ float s_pre[64], s_post[64];
    bf16* Sb = (bf16*)S;                     // P bf16 alias, row stride SBS=224 (448B)
    if (tid < 64){ s_pre[tid]=pre_w[tid]; s_post[tid]=post_w[tid]; }

    // ---- stage 1: raw (pre-scaled) scores S[h][nq][m], 13 K-tiles, 2-deep k prefetch
    #pragma unroll
    for (int hh=0; hh<2; hh++){
        const int h = wv + hh*4;
        int qr = n0 + fr; if (qr > 196) qr = 196;
        const bf16* qrow = q + ((size_t)(b*NHEAD+h)*NTOK + qr)*DHEAD + fq*8;
        bf16x8 a0 = *(const bf16x8*)(qrow);
        bf16x8 a1 = *(const bf16x8*)(qrow+32);
        bf16x8 a2 = *(const bf16x8*)(qrow+64);
        const bf16* kb0 = k + (size_t)(b*NHEAD+h)*NTOK*DHEAD + fq*8;
        auto krow = [&](int mt){ int nr = mt*16+fr; if (nr>196) nr=196; return kb0 + (size_t)nr*DHEAD; };
        const bf16* kp0 = krow(0);
        bf16x8 c00 = *(const bf16x8*)(kp0), c01 = *(const bf16x8*)(kp0+32), c02 = *(const bf16x8*)(kp0+64);
        const bf16* kp1 = krow(1);
        bf16x8 c10 = *(const bf16x8*)(kp1), c11 = *(const bf16x8*)(kp1+32), c12 = *(const bf16x8*)(kp1+64);
        #pragma unroll
        for (int mt=0; mt<13; mt++){
            bf16x8 p0, p1, p2;
            if (mt < 11){
                const bf16* kn = krow(mt+2);
                p0 = *(const bf16x8*)(kn); p1 = *(const bf16x8*)(kn+32); p2 = *(const bf16x8*)(kn+64);
            }
            f32x4 acc = {};
            acc = __builtin_amdgcn_mfma_f32_16x16x32_bf16(a0, c00, acc,0,0,0);
            acc = __builtin_amdgcn_mfma_f32_16x16x32_bf16(a1, c01, acc,0,0,0);
            acc = __builtin_amdgcn_mfma_f32_16x16x32_bf16(a2, c02, acc,0,0,0);
            int col = mt*16 + fr;
            if (fq < 2 && col < SMS){
                #pragma unroll
                for (int i=0;i<4;i++)
                    S[(h*8 + fq*4+i)*SMS + col] = acc[i];
            }
            c00=c10; c01=c11; c02=c12;
            if (mt < 11){ c10=p0; c11=p1; c12=p2; }
        }
    }
    __syncthreads();

    // ---- stage 2: premix + premixed bias + geometric mask -> regs; lane-local max
    const int nq = tid >> 5, l32 = tid & 31;
    float p_[7][8];
    float ml[8];
    #pragma unroll
    for (int o=0;o<8;o++) ml[o] = -3.0e38f;
    {
        const int sco[8] = {1,1,4,4,7,7,1000,1000};
        int n = n0 + nq; if (n > 196) n = 196;
        const bool nAlways = (n == 0);
        int ri=0, ci=0;
        if (!nAlways){ ri=(n-1)/14; ci=(n-1)-ri*14; }
        #pragma unroll
        for (int kk=0; kk<7; kk++){
            int m = l32 + 32*kk;
            if (m >= 197){
                #pragma unroll
                for (int o=0;o<8;o++) p_[kk][o] = -1e9f;
                continue;
            }
            bool always = nAlways || (m==0);
            int rj=0, cj=0;
            if (m > 0){ rj=(m-1)/14; cj=(m-1)-rj*14; }
            int dr = ri-rj; if (dr<0) dr=-dr;
            int dc = ci-cj; if (dc<0) dc=-dc;
            int idx = always ? 730 : (ri-rj+13)*27 + (ci-cj+13);
            const float* pv = p + idx*8;
            float sh[8];
            #pragma unroll
            for (int h2=0;h2<8;h2++) sh[h2] = S[(h2*8+nq)*SMS+m];
            #pragma unroll
            for (int o=0;o<8;o++){
                float v = pv[o];
                #pragma unroll
                for (int h2=0;h2<8;h2++) v += s_pre[o*8+h2]*sh[h2];
                bool on = always || (dr<=sco[o] && dc<=sco[o]);
                v = on ? v : -1e9f;
                p_[kk][o] = v;
                ml[o] = fmaxf(ml[o], v);
            }
        }
    }
    __syncthreads();   // all S reads done before any Sb (aliasing) writes below

    // ---- stage 3: in-register softmax (per (o,nq) row; row spans this 32-lane group)
    float invl[8];
    {
        #pragma unroll
        for (int o=0;o<8;o++){
            float mx = ml[o];
            #pragma unroll
            for (int off=16; off; off>>=1) mx = fmaxf(mx, __shfl_xor(mx, off, 64));
            ml[o] = mx;
        }
        float sm[8];
        #pragma unroll
        for (int o=0;o<8;o++) sm[o]=0.f;
        #pragma unroll
        for (int kk=0;kk<7;kk++){
            #pragma unroll
            for (int o=0;o<8;o++){
                float e = __expf(p_[kk][o] - ml[o]);
                p_[kk][o] = e; sm[o] += e;
            }
        }
        #pragma unroll
        for (int o=0;o<8;o++){
            float s = sm[o];
            #pragma unroll
            for (int off=16; off; off>>=1) s += __shfl_xor(s, off, 64);
            invl[o] = 1.f/s;
        }
    }
    // ---- stage 3.5: postmix (1/L folded) -> bf16 P (cols 197..223 naturally zero)
    #pragma unroll
    for (int kk=0;kk<7;kk++){
        int m = l32 + 32*kk;   // covers 0..223 exactly
        float qn[8];
        #pragma unroll
        for (int o=0;o<8;o++) qn[o] = p_[kk][o]*invl[o];
        #pragma unroll
        for (int o2=0;o2<8;o2++){
            float v=0.f;
            #pragma unroll
            for (int o=0;o<8;o++) v += s_post[o2*8+o]*qn[o];
            Sb[(o2*8+nq)*SBS + m] = f2b(v);
        }
    }
    __syncthreads();

    // ---- stage 4: P @ V via MFMA; P frags hoisted, V double-buffered across dt
    const int frA = fr & 7;
    #pragma unroll
    for (int hh=0; hh<2; hh++){
        const int h = wv + hh*4;
        const bf16* vbase = vt + (size_t)(b*NHEAD+h)*DHEAD*VTS;
        bf16x8 pa[7];
        #pragma unroll
        for (int ks=0; ks<7; ks++)
            pa[ks] = *(const bf16x8*)(Sb + (h*8+frA)*SBS + ks*32 + fq*8);
        bf16x8 bv[7], bn[7];
        #pragma unroll
        for (int ks=0; ks<7; ks++)
            bv[ks] = *(const bf16x8*)(vbase + (size_t)fr*VTS + ks*32 + fq*8);
        #pragma unroll
        for (int dt=0; dt<6; dt++){
            if (dt < 5){
                #pragma unroll
                for (int ks=0; ks<7; ks++)
                    bn[ks] = *(const bf16x8*)(vbase + (size_t)((dt+1)*16+fr)*VTS + ks*32 + fq*8);
            }
            f32x4 acc = {};
            #pragma unroll
            for (int ks=0; ks<7; ks++)
                acc = __builtin_amdgcn_mfma_f32_16x16x32_bf16(pa[ks], bv[ks], acc,0,0,0);
            #pragma unroll
            for (int i=0;i<4;i++){
                int nqq = fq*4+i, n = n0+nqq;
                if (nqq < 8 && n < NTOK)
                    ao[((size_t)b*NTOK+n)*DIMC + h*DHEAD + dt*16+fr] = f2b(acc[i]);
            }
            #pragma unroll
            for (int ks=0; ks<7; ks++) bv[ks] = bn[ks];
        }
    }
}

// ---------------- m97-style MFMA GEMM: 128x128 tile, BK=64; 1D grid + bijective XCD swizzle (T1/m204)
enum { EPI_QKV=0, EPI_X1=1, EPI_GELU=2, EPI_OUT=3 };

template<int EPI>
__global__ __launch_bounds__(256) void gemm128(
    const bf16* __restrict__ A, int lda, int M,
    const bf16* __restrict__ B, int ldb,
    int K,
    const float* __restrict__ bias,
    const float* __restrict__ resid_f,  // X1: x (f32)
    const bf16* __restrict__ resid_b,   // OUT: x1b
    float* __restrict__ dst_f,          // OUT: final out
    bf16* __restrict__ dst_b, int lddb, // X1: x1b ; GELU: mid
    int row_off,                        // OUT: global row offset
    bf16* __restrict__ qo, bf16* __restrict__ ko, bf16* __restrict__ vto,
    int nbx)                            // x-tiles (N/128); grid is 1D = nbx*nby
{
    __shared__ bf16 As[2*128*32];   // two K-32 sub-tiles
    __shared__ bf16 Bs[2*128*32];
    const int tid = threadIdx.x;
    const int wv = tid >> 6, ln = tid & 63;
    const int fr = ln & 15, fq = ln >> 4;
    const int wr = (wv & 1)*64, wc = (wv >> 1)*64;
    // bijective XCD-chunk swizzle (m204): each XCD owns a contiguous wg range ->
    // blocks sharing an A-panel (same by) stay on one XCD's L2.
    const int nwgs = (int)gridDim.x;
    const int xcd = blockIdx.x & 7;
    const int qq = nwgs >> 3, rr = nwgs & 7;
    const int wg = (xcd < rr ? xcd*(qq+1) : rr*(qq+1) + (xcd-rr)*qq) + ((int)blockIdx.x >> 3);
    const int byi = wg / nbx, bxi = wg - byi*nbx;
    const int m0 = byi*128, n0 = bxi*128;
    const int lnrow = ln >> 2, lncol = (ln & 3)*8;
    f32x4 acc[4][4] = {};
    for (int k0=0; k0<K; k0+=64){
        #pragma unroll
        for (int t=0;t<2;t++){
            #pragma unroll
            for (int c=0;c<2;c++){
                int rA = m0 + (c*4+wv)*16 + lnrow;
                if (rA >= M) rA = M-1;
                gld16(A + (size_t)rA*lda + k0 + t*32 + lncol, &As[t*4096 + (c*4+wv)*16*32]);
                int rB = n0 + (c*4+wv)*16 + lnrow;
                gld16(B + (size_t)rB*ldb + k0 + t*32 + lncol, &Bs[t*4096 + (c*4+wv)*16*32]);
            }
        }
        __syncthreads();
        #pragma unroll
        for (int t=0;t<2;t++){
            bf16x8 af[4], bfv[4];
            #pragma unroll
            for (int i=0;i<4;i++){
                af[i]  = *(const bf16x8*)&As[t*4096 + (wr + i*16 + fr)*32 + fq*8];
                bfv[i] = *(const bf16x8*)&Bs[t*4096 + (wc + i*16 + fr)*32 + fq*8];
            }
            #pragma unroll
            for (int mi=0;mi<4;mi++)
                #pragma unroll
                for (int ni=0;ni<4;ni++)
                    acc[mi][ni] = __builtin_amdgcn_mfma_f32_16x16x32_bf16(af[mi], bfv[ni], acc[mi][ni],0,0,0);
        }
        __syncthreads();
    }
    #pragma unroll
    for (int mi=0;mi<4;mi++){
        #pragma unroll
        for (int ni=0;ni<4;ni++){
            #pragma unroll
            for (int i=0;i<4;i++){
                int row = m0 + wr + mi*16 + fq*4 + i;
                int col = n0 + wc + ni*16 + fr;
                if (row >= M) continue;
                float val = acc[mi][ni][i];
                if constexpr (EPI == EPI_QKV){
                    int which = col/768, rem = col - which*768;
                    int hh = rem/96, di = rem - hh*96;
                    int bb = row/NTOK, nn = row - bb*NTOK;
                    if (which == 0)      qo[(((size_t)bb*NHEAD+hh)*NTOK+nn)*DHEAD + di] = f2b(val);
                    else if (which == 1) ko[(((size_t)bb*NHEAD+hh)*NTOK+nn)*DHEAD + di] = f2b(val);
                    else {
                        vto[(((size_t)bb*NHEAD+hh)*DHEAD+di)*VTS + nn] = f2b(val);
                        if (nn < VTS - NTOK)   // fused vt pad-zero (cols 197..223)
                            vto[(((size_t)bb*NHEAD+hh)*DHEAD+di)*VTS + NTOK + nn] = f2b(0.f);
                    }
                } else if constexpr (EPI == EPI_X1){
                    dst_b[(size_t)row*DIMC + col] = f2b(val + bias[col] + resid_f[(size_t)row*DIMC + col]);
                } else if constexpr (EPI == EPI_GELU){
                    float t = val + bias[col];
                    t = 0.5f*t*(1.f + erff(t*0.70710678118654752f));
                    dst_b[(size_t)row*lddb + col] = f2b(t);
                } else { // EPI_OUT
                    size_t g = (size_t)(row + row_off)*DIMC + col;
                    dst_f[g] = val + bias[col] + b2f(resid_b[g]);
                }
            }
        }
    }
}

extern "C" void kernel_launch(void* const* d_in, const int* in_sizes, int n_in,
                              void* d_out, int out_size, void* d_ws, size_t ws_size,
                              hipStream_t stream)
{
    const float* x        = (const float*)d_in[0];
    const float* norm1_w  = (const float*)d_in[1];
    const float* norm1_b  = (const float*)d_in[2];
    const float* qkv_w    = (const float*)d_in[3];
    const float* scale    = (const float*)d_in[4];
    const float* pp_w     = (const float*)d_in[5];
    const float* pp_b     = (const float*)d_in[6];
    const float* ln1_w    = (const float*)d_in[7];
    const float* ln1_b    = (const float*)d_in[8];
    const float* fcp1_w   = (const float*)d_in[9];
    const float* fcp1_b   = (const float*)d_in[10];
    const float* ln2_w    = (const float*)d_in[11];
    const float* ln2_b    = (const float*)d_in[12];
    const float* fcp2_w   = (const float*)d_in[13];
    const float* fcp2_b   = (const float*)d_in[14];
    const float* ln3_w    = (const float*)d_in[15];
    const float* ln3_b    = (const float*)d_in[16];
    const float* fcp3_w   = (const float*)d_in[17];
    const float* fcp3_b   = (const float*)d_in[18];
    const float* pre_w    = (const float*)d_in[19];
    const float* post_w   = (const float*)d_in[20];
    const float* proj_w   = (const float*)d_in[21];
    const float* proj_b   = (const float*)d_in[22];
    const float* nrm2_w   = (const float*)d_in[23];
    const float* nrm2_b   = (const float*)d_in[24];
    const float* m1_w     = (const float*)d_in[25];
    const float* m1_b     = (const float*)d_in[26];
    const float* m2_w     = (const float*)d_in[27];
    const float* m2_b     = (const float*)d_in[28];
    const float* biases   = (const float*)d_in[30];
    float* out = (float*)d_out;

    char* ws = (char*)d_ws;
    float* p      = (float*)(ws + OFF_P);
    bf16*  qkvw_b = (bf16*)(ws + OFF_W);
    bf16*  prjw_b = (bf16*)(ws + OFF_W + SZ_QKVW);
    bf16*  m1w_b  = (bf16*)(ws + OFF_W + SZ_QKVW + SZ_PRJW);
    bf16*  m2w_b  = (bf16*)(ws + OFF_W + SZ_QKVW + SZ_PRJW + SZ_M1W);
    bf16*  h   = (bf16*)(ws + OFF_H);     // LN1 out -> ao -> mid (spans OFF_H..OFF_K)
    bf16*  qb  = (bf16*)(ws + OFF_Q);
    bf16*  kb  = (bf16*)(ws + OFF_K);     // -> h2
    bf16*  vt  = (bf16*)(ws + OFF_V);     // -> x1b
    bf16*  ao  = (bf16*)(ws + OFF_H);
    bf16*  x1b = (bf16*)(ws + OFF_V);
    bf16*  h2  = (bf16*)(ws + OFF_K);
    bf16*  mid = (bf16*)(ws + OFF_H);     // 6304x3072 bf16 = 38.7MB

    w_cvt_all<<<6912, 256, 0, stream>>>(qkv_w, proj_w, m1_w, m2_w, qkvw_b);
    pos_mlp<<<841, 64, 0, stream>>>(biases, pp_w, pp_b, ln1_w, ln1_b, fcp1_w, fcp1_b,
                                    ln2_w, ln2_b, fcp2_w, fcp2_b, ln3_w, ln3_b, fcp3_w, fcp3_b,
                                    pre_w, p);
    ln768<float><<<NROWS, 256, 0, stream>>>(x, norm1_w, norm1_b, h);
    gemm128<EPI_QKV><<<18*99, 256, 0, stream>>>(
        h, DIMC, NROWS, qkvw_b, DIMC, DIMC, nullptr, nullptr, nullptr, nullptr,
        nullptr, 0, 0, qb, kb, vt, 18);
    l2norm_qk<<<(NBATCH*NHEAD*NTOK*2)/16, 256, 0, stream>>>(qb, kb, scale);
    attn_mfma<<<1600, 256, 0, stream>>>(qb, kb, vt, p, pre_w, post_w, ao);
    gemm128<EPI_X1><<<6*99, 256, 0, stream>>>(
        ao, DIMC, NROWS, prjw_b, DIMC, DIMC, proj_b, x, nullptr, nullptr,
        x1b, 0, 0, nullptr, nullptr, nullptr, 6);
    ln768<bf16><<<NROWS, 256, 0, stream>>>(x1b, nrm2_w, nrm2_b, h2);
    for (int c=0; c<2; c++){
        const int r0 = c*MHALF;
        gemm128<EPI_GELU><<<24*50, 256, 0, stream>>>(
            h2 + (size_t)r0*DIMC, DIMC, MHALF, m1w_b, DIMC, DIMC, m1_b,
            nullptr, nullptr, nullptr, mid, 3072, 0, nullptr, nullptr, nullptr, 24);
        gemm128<EPI_OUT><<<6*50, 256, 0, stream>>>(
            mid, 3072, MHALF, m2w_b, 3072, 3072, m2_b,
            nullptr, x1b, out, nullptr, 0, r0, nullptr, nullptr, nullptr, 6);
    }
    (void)in_sizes; (void)n_in; (void)out_size; (void)ws_size;
}

// Round 8
// 780.699 us; speedup vs baseline: 1.0874x; 1.0075x over previous
//
#include <hip/hip_runtime.h>
#include <hip/hip_bf16.h>
#include <math.h>

typedef __hip_bfloat16 bf16;
typedef __attribute__((ext_vector_type(8))) short bf16x8;   // 8 bf16 (4 VGPRs)
typedef __attribute__((ext_vector_type(4))) float f32x4;

__device__ __forceinline__ float b2f(bf16 x){ return __bfloat162float(x); }
__device__ __forceinline__ bf16  f2b(float x){ return __float2bfloat16(x); }
__device__ __forceinline__ float us2f(unsigned short u){ bf16 t; *(unsigned short*)&t = u; return __bfloat162float(t); }

// async global->LDS 16B (m97 pattern): LDS dest = wave-uniform base + lane*16
__device__ __forceinline__ void gld16(const bf16* g, bf16* l){
    __builtin_amdgcn_global_load_lds(
        (const __attribute__((address_space(1))) unsigned int*)g,
        (__attribute__((address_space(3))) unsigned int*)l, 16, 0, 0);
}

#define NTOK 197
#define NBATCH 64
#define NHEAD 8
#define DHEAD 96
#define DIMC 768
#define NROWS (NBATCH * NTOK)   // 12608
#define VTS 224                 // vt row stride (bf16), cols 197..223 zero-padded (by QKV epilogue)
#define SMS 200                 // LDS score row stride (f32)
#define SBS 224                 // bf16 P row stride (448B, 16B-aligned); aliases S (barrier-fenced)
#define MHALF 6304              // MLP row-chunk

// ---------------- workspace layout (bytes) ----------------
#define OFF_P   0ull
#define OFF_W   32768ull
#define SZ_QKVW 3538944ull
#define SZ_PRJW 1179648ull
#define SZ_M1W  4718592ull
#define SZ_M2W  4718592ull
#define OFF_H   14188544ull     // h -> ao -> mid(38.7MB spans OFF_H..OFF_K)
#define SZ_H    19365888ull
#define OFF_Q   33554432ull     // q
#define OFF_K   52920320ull     // k -> h2
#define OFF_V   72286208ull     // vt (22.02MB) -> x1b ; end 94,306,304 (< proven 96.9MB)

// ---------------- fused f32 -> bf16 weight convert (4 segments) ----------------
__global__ __launch_bounds__(256) void w_cvt_all(
    const float* __restrict__ s0, const float* __restrict__ s1,
    const float* __restrict__ s2, const float* __restrict__ s3, bf16* __restrict__ d)
{
    int i = blockIdx.x*256 + threadIdx.x;   // quad index, total 1,769,472
    const float* s; int off;
    if (i < 442368){ s=s0; off=i; }
    else if (i < 589824){ s=s1; off=i-442368; }
    else if (i < 1179648){ s=s2; off=i-589824; }
    else { s=s3; off=i-1179648; }
    float4 v = ((const float4*)s)[off];
    bf16 t[4] = {f2b(v.x), f2b(v.y), f2b(v.z), f2b(v.w)};
    ((ushort4*)d)[i] = *(ushort4*)t;
}

// ---------------- position-bias MLP (841 rows, tiny, all f32) ----------------
// NOTE: output is PREMIXED over heads: pout[idx][o] = sum_h pre_w[o,h] * p[idx,h]
__global__ __launch_bounds__(64) void pos_mlp(
    const float* __restrict__ biases, const float* __restrict__ pp_w, const float* __restrict__ pp_b,
    const float* __restrict__ ln1w, const float* __restrict__ ln1b,
    const float* __restrict__ f1w,  const float* __restrict__ f1b,
    const float* __restrict__ ln2w, const float* __restrict__ ln2b,
    const float* __restrict__ f2w,  const float* __restrict__ f2b,
    const float* __restrict__ ln3w, const float* __restrict__ ln3b,
    const float* __restrict__ f3w,  const float* __restrict__ f3b,
    const float* __restrict__ pre_w,
    float* __restrict__ pout)
{
    const int row = blockIdx.x, j = threadIdx.x;
    __shared__ float va[48], vb[48], pf[8];
    float b0 = biases[row*2], b1 = biases[row*2+1];
    if (j < 48) va[j] = b0*pp_w[j*2] + b1*pp_w[j*2+1] + pp_b[j];
    __syncthreads();
    {   float s=0.f, s2=0.f;
        for (int i=0;i<48;i++){ float t=va[i]; s+=t; s2+=t*t; }
        float mean=s*(1.f/48.f), var=s2*(1.f/48.f)-mean*mean, inv=rsqrtf(var+1e-5f);
        float r=0.f;
        if (j < 48){
            r = f1b[j];
            for (int i=0;i<48;i++){
                float t = fmaxf((va[i]-mean)*inv*ln1w[i] + ln1b[i], 0.f);
                r += t * f1w[j*48+i];
            }
        }
        __syncthreads();
        if (j < 48) vb[j] = r;
    }
    __syncthreads();
    {   float s=0.f, s2=0.f;
        for (int i=0;i<48;i++){ float t=vb[i]; s+=t; s2+=t*t; }
        float mean=s*(1.f/48.f), var=s2*(1.f/48.f)-mean*mean, inv=rsqrtf(var+1e-5f);
        float r=0.f;
        if (j < 48){
            r = f2b[j];
            for (int i=0;i<48;i++){
                float t = fmaxf((vb[i]-mean)*inv*ln2w[i] + ln2b[i], 0.f);
                r += t * f2w[j*48+i];
            }
        }
        __syncthreads();
        if (j < 48) va[j] = r;
    }
    __syncthreads();
    {   float s=0.f, s2=0.f;
        for (int i=0;i<48;i++){ float t=va[i]; s+=t; s2+=t*t; }
        float mean=s*(1.f/48.f), var=s2*(1.f/48.f)-mean*mean, inv=rsqrtf(var+1e-5f);
        if (j < 8){
            float r = f3b[j];
            for (int i=0;i<48;i++){
                float t = fmaxf((va[i]-mean)*inv*ln3w[i] + ln3b[i], 0.f);
                r += t * f3w[j*48+i];
            }
            pf[j] = r;
        }
    }
    __syncthreads();
    if (j < 8){
        float s = 0.f;
        #pragma unroll
        for (int hh=0; hh<8; hh++) s += pre_w[j*8+hh]*pf[hh];
        pout[row*8+j] = s;
    }
}

// ---------------- LayerNorm over 768 (f32 or bf16 in, bf16 out), vectorized loads ----------------
template<typename TIN>
__global__ __launch_bounds__(256) void ln768(
    const TIN* __restrict__ x, const float* __restrict__ w, const float* __restrict__ b,
    bf16* __restrict__ out)
{
    const int row = blockIdx.x, tid = threadIdx.x;
    const int wv = tid >> 6, ln = tid & 63;
    __shared__ float rs[4], rs2[4];
    const TIN* xr = x + (size_t)row * DIMC;
    float v[4] = {0.f,0.f,0.f,0.f};
    if (tid < 192){
        if constexpr (sizeof(TIN) == 4){
            float4 t4 = ((const float4*)xr)[tid];
            v[0]=t4.x; v[1]=t4.y; v[2]=t4.z; v[3]=t4.w;
        } else {
            ushort4 t4 = ((const ushort4*)xr)[tid];
            v[0]=us2f(t4.x); v[1]=us2f(t4.y); v[2]=us2f(t4.z); v[3]=us2f(t4.w);
        }
    }
    float s = v[0]+v[1]+v[2]+v[3];
    float s2 = v[0]*v[0]+v[1]*v[1]+v[2]*v[2]+v[3]*v[3];
    #pragma unroll
    for (int off=32; off; off>>=1){ s += __shfl_xor(s,off,64); s2 += __shfl_xor(s2,off,64); }
    if (ln == 0){ rs[wv]=s; rs2[wv]=s2; }
    __syncthreads();
    s = rs[0]+rs[1]+rs[2]+rs[3]; s2 = rs2[0]+rs2[1]+rs2[2]+rs2[3];
    float mean = s*(1.f/768.f), var = s2*(1.f/768.f) - mean*mean;
    float inv = rsqrtf(var + 1e-5f);
    if (tid < 192){
        float4 w4 = ((const float4*)w)[tid];
        float4 b4 = ((const float4*)b)[tid];
        bf16 o[4];
        o[0] = f2b((v[0]-mean)*inv*w4.x + b4.x);
        o[1] = f2b((v[1]-mean)*inv*w4.y + b4.y);
        o[2] = f2b((v[2]-mean)*inv*w4.z + b4.z);
        o[3] = f2b((v[3]-mean)*inv*w4.w + b4.w);
        ((ushort4*)(out + (size_t)row*DIMC))[tid] = *(ushort4*)o;
    }
}

// ---------------- l2-normalize q,k rows (96 elems, bf16 in-place); q rows also * min(scale,100)
__global__ __launch_bounds__(256) void l2norm_qk(bf16* __restrict__ q, bf16* __restrict__ k,
                                                 const float* __restrict__ scale)
{
    const int wv = threadIdx.x >> 6, ln = threadIdx.x & 63;
    const int g = ln >> 4, j = ln & 15;
    const size_t NR = (size_t)NBATCH*NHEAD*NTOK;
    size_t row = (size_t)blockIdx.x*16 + wv*4 + g;
    bool isq = row < NR;
    bf16* ptr = isq ? (q + row*DHEAD) : (k + (row-NR)*DHEAD);
    float xv[8];
    float ss = 0.f;
    if (j < 12){
        bf16x8 vv = *(const bf16x8*)(ptr + j*8);
        #pragma unroll
        for (int e=0;e<8;e++){ float f = us2f((unsigned short)vv[e]); xv[e]=f; ss += f*f; }
    }
    #pragma unroll
    for (int off=8; off; off>>=1) ss += __shfl_xor(ss, off, 64);
    float inv = 1.f / fmaxf(sqrtf(ss), 1e-12f);
    if (isq){
        int h = (int)((row / NTOK) & (NHEAD-1));
        inv *= fminf(scale[h], 100.f);
    }
    if (j < 12){
        bf16x8 ov;
        #pragma unroll
        for (int e=0;e<8;e++){ bf16 t = f2b(xv[e]*inv); ov[e] = *(short*)&t; }
        *(bf16x8*)(ptr + j*8) = ov;
    }
}

// ---------------- MFMA attention ----------------
// v5: 512 threads, one wave per head. Stage-1/4 serial chains halve per wave and
// LDS-capped occupancy doubles (3 blocks x 8 waves = 24 waves/CU). Stages 2/3.5 are the
// proven round-5 code on tid<256; stage-3 softmax spread over all 8 waves. VGPR ~ round-5.
__global__ __launch_bounds__(512) void attn_mfma(
    const bf16* __restrict__ q, const bf16* __restrict__ k, const bf16* __restrict__ vt,
    const float* __restrict__ p,    // premixed (841 x 8, o-indexed)
    const float* __restrict__ pre_w, const float* __restrict__ post_w,
    bf16* __restrict__ ao)
{
    const int id = blockIdx.x;
    const int r8 = id & 7, t8 = id >> 3;
    const int bx = t8 % 25, b = r8 + 8*(t8/25);
    const int n0 = bx*8;
    const int tid = threadIdx.x, wv = tid>>6, ln = tid&63;
    const int fr = ln&15, fq = ln>>4;
    __shared__ float S[NHEAD*8*SMS];         // 51,200 B f32 scores
    __shared__ float s_pre[64], s_post[64];
    bf16* Sb = (bf16*)S;                     // P bf16 alias, row stride SBS=224 (448B)
    if (tid < 64){ s_pre[tid]=pre_w[tid]; s_post[tid]=post_w[tid]; }

    // ---- stage 1: wave wv computes head h=wv: S[h][nq][m], 13 K-tiles, 2-deep k prefetch
    {
        const int h = wv;
        int qr = n0 + fr; if (qr > 196) qr = 196;
        const bf16* qrow = q + ((size_t)(b*NHEAD+h)*NTOK + qr)*DHEAD + fq*8;
        bf16x8 a0 = *(const bf16x8*)(qrow);
        bf16x8 a1 = *(const bf16x8*)(qrow+32);
        bf16x8 a2 = *(const bf16x8*)(qrow+64);
        const bf16* kb0 = k + (size_t)(b*NHEAD+h)*NTOK*DHEAD + fq*8;
        auto krow = [&](int mt){ int nr = mt*16+fr; if (nr>196) nr=196; return kb0 + (size_t)nr*DHEAD; };
        const bf16* kp0 = krow(0);
        bf16x8 c00 = *(const bf16x8*)(kp0), c01 = *(const bf16x8*)(kp0+32), c02 = *(const bf16x8*)(kp0+64);
        const bf16* kp1 = krow(1);
        bf16x8 c10 = *(const bf16x8*)(kp1), c11 = *(const bf16x8*)(kp1+32), c12 = *(const bf16x8*)(kp1+64);
        #pragma unroll
        for (int mt=0; mt<13; mt++){
            bf16x8 p0, p1, p2;
            if (mt < 11){
                const bf16* kn = krow(mt+2);
                p0 = *(const bf16x8*)(kn); p1 = *(const bf16x8*)(kn+32); p2 = *(const bf16x8*)(kn+64);
            }
            f32x4 acc = {};
            acc = __builtin_amdgcn_mfma_f32_16x16x32_bf16(a0, c00, acc,0,0,0);
            acc = __builtin_amdgcn_mfma_f32_16x16x32_bf16(a1, c01, acc,0,0,0);
            acc = __builtin_amdgcn_mfma_f32_16x16x32_bf16(a2, c02, acc,0,0,0);
            int col = mt*16 + fr;
            if (fq < 2 && col < SMS){
                #pragma unroll
                for (int i=0;i<4;i++)
                    S[(h*8 + fq*4+i)*SMS + col] = acc[i];
            }
            c00=c10; c01=c11; c02=c12;
            if (mt < 11){ c10=p0; c11=p1; c12=p2; }
        }
    }
    __syncthreads();

    // ---- stage 2 (tid<256): premix + premixed bias + geometric mask (cols 197..199 -> -1e9)
    if (tid < 256){
        const int sco[8] = {1,1,4,4,7,7,1000,1000};
        const int nq = tid >> 5, l32 = tid & 31;
        int n = n0 + nq; if (n > 196) n = 196;
        const bool nAlways = (n == 0);
        int ri=0, ci=0;
        if (!nAlways){ ri=(n-1)/14; ci=(n-1)-ri*14; }
        for (int m = l32; m < SMS; m += 32){
            if (m >= 197){
                #pragma unroll
                for (int o=0;o<8;o++) S[(o*8+nq)*SMS+m] = -1e9f;
                continue;
            }
            bool always = nAlways || (m==0);
            int rj=0, cj=0;
            if (m > 0){ rj=(m-1)/14; cj=(m-1)-rj*14; }
            int dr = ri-rj; if (dr<0) dr=-dr;
            int dc = ci-cj; if (dc<0) dc=-dc;
            int idx = always ? 730 : (ri-rj+13)*27 + (ci-cj+13);
            const float* pv = p + idx*8;
            float sh[8];
            #pragma unroll
            for (int h2=0;h2<8;h2++) sh[h2] = S[(h2*8+nq)*SMS+m];
            float ov[8];
            #pragma unroll
            for (int o=0;o<8;o++){
                float v = pv[o];
                #pragma unroll
                for (int h2=0;h2<8;h2++) v += s_pre[o*8+h2]*sh[h2];
                bool on = always || (dr<=sco[o] && dc<=sco[o]);
                ov[o] = on ? v : -1e9f;
            }
            #pragma unroll
            for (int o=0;o<8;o++) S[(o*8+nq)*SMS+m] = ov[o];
        }
    }
    __syncthreads();

    // ---- stage 3: softmax per (o,nq) row over 200 cols — 8 waves, 4 rows concurrent, 2 passes
    {
        const int g = ln >> 4, l16 = ln & 15;
        #pragma unroll
        for (int rr=0; rr<2; rr++){
            float* row = &S[(wv*8 + rr*4 + g)*SMS];
            float mx = -3e38f;
            for (int m=l16; m<SMS; m+=16) mx = fmaxf(mx, row[m]);
            #pragma unroll
            for (int off=8; off; off>>=1) mx = fmaxf(mx, __shfl_xor(mx,off,64));
            float sum = 0.f;
            for (int m=l16; m<SMS; m+=16){ float e=__expf(row[m]-mx); row[m]=e; sum+=e; }
            #pragma unroll
            for (int off=8; off; off>>=1) sum += __shfl_xor(sum,off,64);
            float inv = 1.f/sum;
            for (int m=l16; m<SMS; m+=16) row[m] *= inv;
        }
    }
    __syncthreads();

    // ---- stage 3.5 (tid<256): postmix -> regs -> barrier -> bf16 P (stride SBS, pad cols zeroed)
    {
        const int nq = (tid >> 5) & 7, l32 = tid & 31;
        float ov[7][8];
        if (tid < 256){
            #pragma unroll
            for (int kk=0; kk<7; kk++){
                int m = l32 + 32*kk;
                if (m < 197){
                    float ph[8];
                    #pragma unroll
                    for (int o=0;o<8;o++) ph[o] = S[(o*8+nq)*SMS+m];
                    #pragma unroll
                    for (int o2=0;o2<8;o2++){
                        float v=0.f;
                        #pragma unroll
                        for (int o=0;o<8;o++) v += s_post[o2*8+o]*ph[o];
                        ov[kk][o2]=v;
                    }
                }
            }
        }
        __syncthreads();
        if (tid < 256){
            #pragma unroll
            for (int kk=0; kk<7; kk++){
                int m = l32 + 32*kk;   // covers 0..223 exactly
                #pragma unroll
                for (int o=0;o<8;o++)
                    Sb[(o*8+nq)*SBS + m] = (m < 197) ? f2b(ov[kk][o]) : f2b(0.f);
            }
        }
    }
    __syncthreads();

    // ---- stage 4: wave wv = head wv: P @ V via MFMA; P frags hoisted, V double-buffered
    {
        const int frA = fr & 7;
        const int h = wv;
        const bf16* vbase = vt + (size_t)(b*NHEAD+h)*DHEAD*VTS;
        bf16x8 pa[7];
        #pragma unroll
        for (int ks=0; ks<7; ks++)
            pa[ks] = *(const bf16x8*)(Sb + (h*8+frA)*SBS + ks*32 + fq*8);
        bf16x8 bv[7], bn[7];
        #pragma unroll
        for (int ks=0; ks<7; ks++)
            bv[ks] = *(const bf16x8*)(vbase + (size_t)fr*VTS + ks*32 + fq*8);
        #pragma unroll
        for (int dt=0; dt<6; dt++){
            if (dt < 5){
                #pragma unroll
                for (int ks=0; ks<7; ks++)
                    bn[ks] = *(const bf16x8*)(vbase + (size_t)((dt+1)*16+fr)*VTS + ks*32 + fq*8);
            }
            f32x4 acc = {};
            #pragma unroll
            for (int ks=0; ks<7; ks++)
                acc = __builtin_amdgcn_mfma_f32_16x16x32_bf16(pa[ks], bv[ks], acc,0,0,0);
            #pragma unroll
            for (int i=0;i<4;i++){
                int nqq = fq*4+i, n = n0+nqq;
                if (nqq < 8 && n < NTOK)
                    ao[((size_t)b*NTOK+n)*DIMC + h*DHEAD + dt*16+fr] = f2b(acc[i]);
            }
            #pragma unroll
            for (int ks=0; ks<7; ks++) bv[ks] = bn[ks];
        }
    }
}

// ---------------- m97-style MFMA GEMM: 128x128 tile, BK=64; 1D grid + bijective XCD swizzle (T1/m204)
enum { EPI_QKV=0, EPI_X1=1, EPI_GELU=2, EPI_OUT=3 };

template<int EPI>
__global__ __launch_bounds__(256) void gemm128(
    const bf16* __restrict__ A, int lda, int M,
    const bf16* __restrict__ B, int ldb,
    int K,
    const float* __restrict__ bias,
    const float* __restrict__ resid_f,  // X1: x (f32)
    const bf16* __restrict__ resid_b,   // OUT: x1b
    float* __restrict__ dst_f,          // OUT: final out
    bf16* __restrict__ dst_b, int lddb, // X1: x1b ; GELU: mid
    int row_off,                        // OUT: global row offset
    bf16* __restrict__ qo, bf16* __restrict__ ko, bf16* __restrict__ vto,
    int nbx)                            // x-tiles (N/128); grid is 1D = nbx*nby
{
    __shared__ bf16 As[2*128*32];   // two K-32 sub-tiles
    __shared__ bf16 Bs[2*128*32];
    const int tid = threadIdx.x;
    const int wv = tid >> 6, ln = tid & 63;
    const int fr = ln & 15, fq = ln >> 4;
    const int wr = (wv & 1)*64, wc = (wv >> 1)*64;
    // bijective XCD-chunk swizzle (m204): each XCD owns a contiguous wg range ->
    // blocks sharing an A-panel (same by) stay on one XCD's L2.
    const int nwgs = (int)gridDim.x;
    const int xcd = blockIdx.x & 7;
    const int qq = nwgs >> 3, rr = nwgs & 7;
    const int wg = (xcd < rr ? xcd*(qq+1) : rr*(qq+1) + (xcd-rr)*qq) + ((int)blockIdx.x >> 3);
    const int byi = wg / nbx, bxi = wg - byi*nbx;
    const int m0 = byi*128, n0 = bxi*128;
    const int lnrow = ln >> 2, lncol = (ln & 3)*8;
    f32x4 acc[4][4] = {};
    for (int k0=0; k0<K; k0+=64){
        #pragma unroll
        for (int t=0;t<2;t++){
            #pragma unroll
            for (int c=0;c<2;c++){
                int rA = m0 + (c*4+wv)*16 + lnrow;
                if (rA >= M) rA = M-1;
                gld16(A + (size_t)rA*lda + k0 + t*32 + lncol, &As[t*4096 + (c*4+wv)*16*32]);
                int rB = n0 + (c*4+wv)*16 + lnrow;
                gld16(B + (size_t)rB*ldb + k0 + t*32 + lncol, &Bs[t*4096 + (c*4+wv)*16*32]);
            }
        }
        __syncthreads();
        #pragma unroll
        for (int t=0;t<2;t++){
            bf16x8 af[4], bfv[4];
            #pragma unroll
            for (int i=0;i<4;i++){
                af[i]  = *(const bf16x8*)&As[t*4096 + (wr + i*16 + fr)*32 + fq*8];
                bfv[i] = *(const bf16x8*)&Bs[t*4096 + (wc + i*16 + fr)*32 + fq*8];
            }
            #pragma unroll
            for (int mi=0;mi<4;mi++)
                #pragma unroll
                for (int ni=0;ni<4;ni++)
                    acc[mi][ni] = __builtin_amdgcn_mfma_f32_16x16x32_bf16(af[mi], bfv[ni], acc[mi][ni],0,0,0);
        }
        __syncthreads();
    }
    #pragma unroll
    for (int mi=0;mi<4;mi++){
        #pragma unroll
        for (int ni=0;ni<4;ni++){
            #pragma unroll
            for (int i=0;i<4;i++){
                int row = m0 + wr + mi*16 + fq*4 + i;
                int col = n0 + wc + ni*16 + fr;
                if (row >= M) continue;
                float val = acc[mi][ni][i];
                if constexpr (EPI == EPI_QKV){
                    int which = col/768, rem = col - which*768;
                    int hh = rem/96, di = rem - hh*96;
                    int bb = row/NTOK, nn = row - bb*NTOK;
                    if (which == 0)      qo[(((size_t)bb*NHEAD+hh)*NTOK+nn)*DHEAD + di] = f2b(val);
                    else if (which == 1) ko[(((size_t)bb*NHEAD+hh)*NTOK+nn)*DHEAD + di] = f2b(val);
                    else {
                        vto[(((size_t)bb*NHEAD+hh)*DHEAD+di)*VTS + nn] = f2b(val);
                        if (nn < VTS - NTOK)   // fused vt pad-zero (cols 197..223)
                            vto[(((size_t)bb*NHEAD+hh)*DHEAD+di)*VTS + NTOK + nn] = f2b(0.f);
                    }
                } else if constexpr (EPI == EPI_X1){
                    dst_b[(size_t)row*DIMC + col] = f2b(val + bias[col] + resid_f[(size_t)row*DIMC + col]);
                } else if constexpr (EPI == EPI_GELU){
                    float t = val + bias[col];
                    t = 0.5f*t*(1.f + erff(t*0.70710678118654752f));
                    dst_b[(size_t)row*lddb + col] = f2b(t);
                } else { // EPI_OUT
                    size_t g = (size_t)(row + row_off)*DIMC + col;
                    dst_f[g] = val + bias[col] + b2f(resid_b[g]);
                }
            }
        }
    }
}

extern "C" void kernel_launch(void* const* d_in, const int* in_sizes, int n_in,
                              void* d_out, int out_size, void* d_ws, size_t ws_size,
                              hipStream_t stream)
{
    const float* x        = (const float*)d_in[0];
    const float* norm1_w  = (const float*)d_in[1];
    const float* norm1_b  = (const float*)d_in[2];
    const float* qkv_w    = (const float*)d_in[3];
    const float* scale    = (const float*)d_in[4];
    const float* pp_w     = (const float*)d_in[5];
    const float* pp_b     = (const float*)d_in[6];
    const float* ln1_w    = (const float*)d_in[7];
    const float* ln1_b    = (const float*)d_in[8];
    const float* fcp1_w   = (const float*)d_in[9];
    const float* fcp1_b   = (const float*)d_in[10];
    const float* ln2_w    = (const float*)d_in[11];
    const float* ln2_b    = (const float*)d_in[12];
    const float* fcp2_w   = (const float*)d_in[13];
    const float* fcp2_b   = (const float*)d_in[14];
    const float* ln3_w    = (const float*)d_in[15];
    const float* ln3_b    = (const float*)d_in[16];
    const float* fcp3_w   = (const float*)d_in[17];
    const float* fcp3_b   = (const float*)d_in[18];
    const float* pre_w    = (const float*)d_in[19];
    const float* post_w   = (const float*)d_in[20];
    const float* proj_w   = (const float*)d_in[21];
    const float* proj_b   = (const float*)d_in[22];
    const float* nrm2_w   = (const float*)d_in[23];
    const float* nrm2_b   = (const float*)d_in[24];
    const float* m1_w     = (const float*)d_in[25];
    const float* m1_b     = (const float*)d_in[26];
    const float* m2_w     = (const float*)d_in[27];
    const float* m2_b     = (const float*)d_in[28];
    const float* biases   = (const float*)d_in[30];
    float* out = (float*)d_out;

    char* ws = (char*)d_ws;
    float* p      = (float*)(ws + OFF_P);
    bf16*  qkvw_b = (bf16*)(ws + OFF_W);
    bf16*  prjw_b = (bf16*)(ws + OFF_W + SZ_QKVW);
    bf16*  m1w_b  = (bf16*)(ws + OFF_W + SZ_QKVW + SZ_PRJW);
    bf16*  m2w_b  = (bf16*)(ws + OFF_W + SZ_QKVW + SZ_PRJW + SZ_M1W);
    bf16*  h   = (bf16*)(ws + OFF_H);     // LN1 out -> ao -> mid (spans OFF_H..OFF_K)
    bf16*  qb  = (bf16*)(ws + OFF_Q);
    bf16*  kb  = (bf16*)(ws + OFF_K);     // -> h2
    bf16*  vt  = (bf16*)(ws + OFF_V);     // -> x1b
    bf16*  ao  = (bf16*)(ws + OFF_H);
    bf16*  x1b = (bf16*)(ws + OFF_V);
    bf16*  h2  = (bf16*)(ws + OFF_K);
    bf16*  mid = (bf16*)(ws + OFF_H);     // 6304x3072 bf16 = 38.7MB

    w_cvt_all<<<6912, 256, 0, stream>>>(qkv_w, proj_w, m1_w, m2_w, qkvw_b);
    pos_mlp<<<841, 64, 0, stream>>>(biases, pp_w, pp_b, ln1_w, ln1_b, fcp1_w, fcp1_b,
                                    ln2_w, ln2_b, fcp2_w, fcp2_b, ln3_w, ln3_b, fcp3_w, fcp3_b,
                                    pre_w, p);
    ln768<float><<<NROWS, 256, 0, stream>>>(x, norm1_w, norm1_b, h);
    gemm128<EPI_QKV><<<18*99, 256, 0, stream>>>(
        h, DIMC, NROWS, qkvw_b, DIMC, DIMC, nullptr, nullptr, nullptr, nullptr,
        nullptr, 0, 0, qb, kb, vt, 18);
    l2norm_qk<<<(NBATCH*NHEAD*NTOK*2)/16, 256, 0, stream>>>(qb, kb, scale);
    attn_mfma<<<1600, 512, 0, stream>>>(qb, kb, vt, p, pre_w, post_w, ao);
    gemm128<EPI_X1><<<6*99, 256, 0, stream>>>(
        ao, DIMC, NROWS, prjw_b, DIMC, DIMC, proj_b, x, nullptr, nullptr,
        x1b, 0, 0, nullptr, nullptr, nullptr, 6);
    ln768<bf16><<<NROWS, 256, 0, stream>>>(x1b, nrm2_w, nrm2_b, h2);
    for (int c=0; c<2; c++){
        const int r0 = c*MHALF;
        gemm128<EPI_GELU><<<24*50, 256, 0, stream>>>(
            h2 + (size_t)r0*DIMC, DIMC, MHALF, m1w_b, DIMC, DIMC, m1_b,
            nullptr, nullptr, nullptr, mid, 3072, 0, nullptr, nullptr, nullptr, 24);
        gemm128<EPI_OUT><<<6*50, 256, 0, stream>>>(
            mid, 3072, MHALF, m2w_b, 3072, 3072, m2_b,
            nullptr, x1b, out, nullptr, 0, r0, nullptr, nullptr, nullptr, 6);
    }
    (void)in_sizes; (void)n_in; (void)out_size; (void)ws_size;
}

// Round 9
// 768.495 us; speedup vs baseline: 1.1046x; 1.0159x over previous
//
#include <hip/hip_runtime.h>
#include <hip/hip_bf16.h>
#include <math.h>

typedef __hip_bfloat16 bf16;
typedef __attribute__((ext_vector_type(8))) short bf16x8;   // 8 bf16 (4 VGPRs)
typedef __attribute__((ext_vector_type(4))) float f32x4;

__device__ __forceinline__ float b2f(bf16 x){ return __bfloat162float(x); }
__device__ __forceinline__ bf16  f2b(float x){ return __float2bfloat16(x); }
__device__ __forceinline__ float us2f(unsigned short u){ bf16 t; *(unsigned short*)&t = u; return __bfloat162float(t); }

// async global->LDS 16B (m97 pattern): LDS dest = wave-uniform base + lane*16
__device__ __forceinline__ void gld16(const bf16* g, bf16* l){
    __builtin_amdgcn_global_load_lds(
        (const __attribute__((address_space(1))) unsigned int*)g,
        (__attribute__((address_space(3))) unsigned int*)l, 16, 0, 0);
}

// l2-normalize a 96-elem row held as 3 bf16x8 fragments across 4 lanes (ln, ln^16, ln^32, ln^48)
// (fr fixed, fq varies). extra = additional scalar factor folded into the normalization.
__device__ __forceinline__ void norm3(bf16x8& x0, bf16x8& x1, bf16x8& x2, float extra){
    float v[24];
    #pragma unroll
    for (int e=0;e<8;e++){
        v[e]    = us2f((unsigned short)x0[e]);
        v[8+e]  = us2f((unsigned short)x1[e]);
        v[16+e] = us2f((unsigned short)x2[e]);
    }
    float ss = 0.f;
    #pragma unroll
    for (int e=0;e<24;e++) ss += v[e]*v[e];
    ss += __shfl_xor(ss, 16, 64);
    ss += __shfl_xor(ss, 32, 64);
    float inv = extra / fmaxf(sqrtf(ss), 1e-12f);
    #pragma unroll
    for (int e=0;e<8;e++){
        bf16 t0=f2b(v[e]*inv), t1=f2b(v[8+e]*inv), t2=f2b(v[16+e]*inv);
        x0[e]=*(short*)&t0; x1[e]=*(short*)&t1; x2[e]=*(short*)&t2;
    }
}

#define NTOK 197
#define NBATCH 64
#define NHEAD 8
#define DHEAD 96
#define DIMC 768
#define NROWS (NBATCH * NTOK)   // 12608
#define VTS 224                 // vt row stride (bf16), cols 197..223 zero-padded (by QKV epilogue)
#define SMS 200                 // LDS score row stride (f32)
#define SBS 224                 // bf16 P row stride (448B, 16B-aligned); aliases S (barrier-fenced)
#define MHALF 6304              // MLP row-chunk

// ---------------- workspace layout (bytes) ----------------
#define OFF_P   0ull
#define OFF_W   32768ull
#define SZ_QKVW 3538944ull
#define SZ_PRJW 1179648ull
#define SZ_M1W  4718592ull
#define SZ_M2W  4718592ull
#define OFF_H   14188544ull     // h -> ao -> mid(38.7MB spans OFF_H..OFF_K)
#define SZ_H    19365888ull
#define OFF_Q   33554432ull     // q
#define OFF_K   52920320ull     // k -> h2
#define OFF_V   72286208ull     // vt (22.02MB) -> x1b ; end 94,306,304 (< proven 96.9MB)

// ---------------- fused f32 -> bf16 weight convert (4 segments) ----------------
__global__ __launch_bounds__(256) void w_cvt_all(
    const float* __restrict__ s0, const float* __restrict__ s1,
    const float* __restrict__ s2, const float* __restrict__ s3, bf16* __restrict__ d)
{
    int i = blockIdx.x*256 + threadIdx.x;   // quad index, total 1,769,472
    const float* s; int off;
    if (i < 442368){ s=s0; off=i; }
    else if (i < 589824){ s=s1; off=i-442368; }
    else if (i < 1179648){ s=s2; off=i-589824; }
    else { s=s3; off=i-1179648; }
    float4 v = ((const float4*)s)[off];
    bf16 t[4] = {f2b(v.x), f2b(v.y), f2b(v.z), f2b(v.w)};
    ((ushort4*)d)[i] = *(ushort4*)t;
}

// ---------------- position-bias MLP (841 rows, tiny, all f32) ----------------
// NOTE: output is PREMIXED over heads: pout[idx][o] = sum_h pre_w[o,h] * p[idx,h]
__global__ __launch_bounds__(64) void pos_mlp(
    const float* __restrict__ biases, const float* __restrict__ pp_w, const float* __restrict__ pp_b,
    const float* __restrict__ ln1w, const float* __restrict__ ln1b,
    const float* __restrict__ f1w,  const float* __restrict__ f1b,
    const float* __restrict__ ln2w, const float* __restrict__ ln2b,
    const float* __restrict__ f2w,  const float* __restrict__ f2b,
    const float* __restrict__ ln3w, const float* __restrict__ ln3b,
    const float* __restrict__ f3w,  const float* __restrict__ f3b,
    const float* __restrict__ pre_w,
    float* __restrict__ pout)
{
    const int row = blockIdx.x, j = threadIdx.x;
    __shared__ float va[48], vb[48], pf[8];
    float b0 = biases[row*2], b1 = biases[row*2+1];
    if (j < 48) va[j] = b0*pp_w[j*2] + b1*pp_w[j*2+1] + pp_b[j];
    __syncthreads();
    {   float s=0.f, s2=0.f;
        for (int i=0;i<48;i++){ float t=va[i]; s+=t; s2+=t*t; }
        float mean=s*(1.f/48.f), var=s2*(1.f/48.f)-mean*mean, inv=rsqrtf(var+1e-5f);
        float r=0.f;
        if (j < 48){
            r = f1b[j];
            for (int i=0;i<48;i++){
                float t = fmaxf((va[i]-mean)*inv*ln1w[i] + ln1b[i], 0.f);
                r += t * f1w[j*48+i];
            }
        }
        __syncthreads();
        if (j < 48) vb[j] = r;
    }
    __syncthreads();
    {   float s=0.f, s2=0.f;
        for (int i=0;i<48;i++){ float t=vb[i]; s+=t; s2+=t*t; }
        float mean=s*(1.f/48.f), var=s2*(1.f/48.f)-mean*mean, inv=rsqrtf(var+1e-5f);
        float r=0.f;
        if (j < 48){
            r = f2b[j];
            for (int i=0;i<48;i++){
                float t = fmaxf((vb[i]-mean)*inv*ln2w[i] + ln2b[i], 0.f);
                r += t * f2w[j*48+i];
            }
        }
        __syncthreads();
        if (j < 48) va[j] = r;
    }
    __syncthreads();
    {   float s=0.f, s2=0.f;
        for (int i=0;i<48;i++){ float t=va[i]; s+=t; s2+=t*t; }
        float mean=s*(1.f/48.f), var=s2*(1.f/48.f)-mean*mean, inv=rsqrtf(var+1e-5f);
        if (j < 8){
            float r = f3b[j];
            for (int i=0;i<48;i++){
                float t = fmaxf((va[i]-mean)*inv*ln3w[i] + ln3b[i], 0.f);
                r += t * f3w[j*48+i];
            }
            pf[j] = r;
        }
    }
    __syncthreads();
    if (j < 8){
        float s = 0.f;
        #pragma unroll
        for (int hh=0; hh<8; hh++) s += pre_w[j*8+hh]*pf[hh];
        pout[row*8+j] = s;
    }
}

// ---------------- LayerNorm over 768 (f32 or bf16 in, bf16 out), vectorized loads ----------------
template<typename TIN>
__global__ __launch_bounds__(256) void ln768(
    const TIN* __restrict__ x, const float* __restrict__ w, const float* __restrict__ b,
    bf16* __restrict__ out)
{
    const int row = blockIdx.x, tid = threadIdx.x;
    const int wv = tid >> 6, ln = tid & 63;
    __shared__ float rs[4], rs2[4];
    const TIN* xr = x + (size_t)row * DIMC;
    float v[4] = {0.f,0.f,0.f,0.f};
    if (tid < 192){
        if constexpr (sizeof(TIN) == 4){
            float4 t4 = ((const float4*)xr)[tid];
            v[0]=t4.x; v[1]=t4.y; v[2]=t4.z; v[3]=t4.w;
        } else {
            ushort4 t4 = ((const ushort4*)xr)[tid];
            v[0]=us2f(t4.x); v[1]=us2f(t4.y); v[2]=us2f(t4.z); v[3]=us2f(t4.w);
        }
    }
    float s = v[0]+v[1]+v[2]+v[3];
    float s2 = v[0]*v[0]+v[1]*v[1]+v[2]*v[2]+v[3]*v[3];
    #pragma unroll
    for (int off=32; off; off>>=1){ s += __shfl_xor(s,off,64); s2 += __shfl_xor(s2,off,64); }
    if (ln == 0){ rs[wv]=s; rs2[wv]=s2; }
    __syncthreads();
    s = rs[0]+rs[1]+rs[2]+rs[3]; s2 = rs2[0]+rs2[1]+rs2[2]+rs2[3];
    float mean = s*(1.f/768.f), var = s2*(1.f/768.f) - mean*mean;
    float inv = rsqrtf(var + 1e-5f);
    if (tid < 192){
        float4 w4 = ((const float4*)w)[tid];
        float4 b4 = ((const float4*)b)[tid];
        bf16 o[4];
        o[0] = f2b((v[0]-mean)*inv*w4.x + b4.x);
        o[1] = f2b((v[1]-mean)*inv*w4.y + b4.y);
        o[2] = f2b((v[2]-mean)*inv*w4.z + b4.z);
        o[3] = f2b((v[3]-mean)*inv*w4.w + b4.w);
        ((ushort4*)(out + (size_t)row*DIMC))[tid] = *(ushort4*)o;
    }
}

// ---------------- MFMA attention ----------------
// v6: 256-thread v3 structure (best measured: 133.4us) + fused q/k l2-normalization
// (norm3 at consumption preserves the 2-deep k prefetch; scale folded into q factor).
// Deletes the separate l2norm_qk kernel (77MB r+w dispatch).
__global__ __launch_bounds__(256) void attn_mfma(
    const bf16* __restrict__ q, const bf16* __restrict__ k, const bf16* __restrict__ vt,
    const float* __restrict__ p,    // premixed (841 x 8, o-indexed)
    const float* __restrict__ scale,
    const float* __restrict__ pre_w, const float* __restrict__ post_w,
    bf16* __restrict__ ao)
{
    const int id = blockIdx.x;
    const int r8 = id & 7, t8 = id >> 3;
    const int bx = t8 % 25, b = r8 + 8*(t8/25);
    const int n0 = bx*8;
    const int tid = threadIdx.x, wv = tid>>6, ln = tid&63;
    const int fr = ln&15, fq = ln>>4;
    __shared__ float S[NHEAD*8*SMS];         // 51,200 B f32 scores
    __shared__ float s_pre[64], s_post[64];
    bf16* Sb = (bf16*)S;                     // P bf16 alias, row stride SBS=224 (448B)
    if (tid < 64){ s_pre[tid]=pre_w[tid]; s_post[tid]=post_w[tid]; }

    // ---- stage 1: normalized scores S[h][nq][m], 13 K-tiles, 2-deep raw-k prefetch
    #pragma unroll
    for (int hh=0; hh<2; hh++){
        const int h = wv + hh*4;
        int qr = n0 + fr; if (qr > 196) qr = 196;
        const bf16* qrow = q + ((size_t)(b*NHEAD+h)*NTOK + qr)*DHEAD + fq*8;
        bf16x8 a0 = *(const bf16x8*)(qrow);
        bf16x8 a1 = *(const bf16x8*)(qrow+32);
        bf16x8 a2 = *(const bf16x8*)(qrow+64);
        norm3(a0, a1, a2, fminf(scale[h], 100.f));   // l2-normalize q row * min(scale,100)
        const bf16* kb0 = k + (size_t)(b*NHEAD+h)*NTOK*DHEAD + fq*8;
        auto krow = [&](int mt){ int nr = mt*16+fr; if (nr>196) nr=196; return kb0 + (size_t)nr*DHEAD; };
        const bf16* kp0 = krow(0);
        bf16x8 c00 = *(const bf16x8*)(kp0), c01 = *(const bf16x8*)(kp0+32), c02 = *(const bf16x8*)(kp0+64);
        const bf16* kp1 = krow(1);
        bf16x8 c10 = *(const bf16x8*)(kp1), c11 = *(const bf16x8*)(kp1+32), c12 = *(const bf16x8*)(kp1+64);
        #pragma unroll
        for (int mt=0; mt<13; mt++){
            bf16x8 p0, p1, p2;
            if (mt < 11){
                const bf16* kn = krow(mt+2);
                p0 = *(const bf16x8*)(kn); p1 = *(const bf16x8*)(kn+32); p2 = *(const bf16x8*)(kn+64);
            }
            // normalize current k row at consumption (keeps prefetch distance intact)
            bf16x8 k0 = c00, k1 = c01, k2 = c02;
            norm3(k0, k1, k2, 1.f);
            f32x4 acc = {};
            acc = __builtin_amdgcn_mfma_f32_16x16x32_bf16(a0, k0, acc,0,0,0);
            acc = __builtin_amdgcn_mfma_f32_16x16x32_bf16(a1, k1, acc,0,0,0);
            acc = __builtin_amdgcn_mfma_f32_16x16x32_bf16(a2, k2, acc,0,0,0);
            int col = mt*16 + fr;
            if (fq < 2 && col < SMS){
                #pragma unroll
                for (int i=0;i<4;i++)
                    S[(h*8 + fq*4+i)*SMS + col] = acc[i];
            }
            c00=c10; c01=c11; c02=c12;
            if (mt < 11){ c10=p0; c11=p1; c12=p2; }
        }
    }
    __syncthreads();

    // ---- stage 2: premix + premixed bias + geometric mask (cols 197..199 -> -1e9)
    {
        const int sco[8] = {1,1,4,4,7,7,1000,1000};
        const int nq = tid >> 5, l32 = tid & 31;
        int n = n0 + nq; if (n > 196) n = 196;
        const bool nAlways = (n == 0);
        int ri=0, ci=0;
        if (!nAlways){ ri=(n-1)/14; ci=(n-1)-ri*14; }
        for (int m = l32; m < SMS; m += 32){
            if (m >= 197){
                #pragma unroll
                for (int o=0;o<8;o++) S[(o*8+nq)*SMS+m] = -1e9f;
                continue;
            }
            bool always = nAlways || (m==0);
            int rj=0, cj=0;
            if (m > 0){ rj=(m-1)/14; cj=(m-1)-rj*14; }
            int dr = ri-rj; if (dr<0) dr=-dr;
            int dc = ci-cj; if (dc<0) dc=-dc;
            int idx = always ? 730 : (ri-rj+13)*27 + (ci-cj+13);
            const float* pv = p + idx*8;
            float sh[8];
            #pragma unroll
            for (int h2=0;h2<8;h2++) sh[h2] = S[(h2*8+nq)*SMS+m];
            float ov[8];
            #pragma unroll
            for (int o=0;o<8;o++){
                float v = pv[o];
                #pragma unroll
                for (int h2=0;h2<8;h2++) v += s_pre[o*8+h2]*sh[h2];
                bool on = always || (dr<=sco[o] && dc<=sco[o]);
                ov[o] = on ? v : -1e9f;
            }
            #pragma unroll
            for (int o=0;o<8;o++) S[(o*8+nq)*SMS+m] = ov[o];
        }
    }
    __syncthreads();

    // ---- stage 3: softmax per (o,nq) row over 200 cols — 16-lane groups, 4 rows/wave concurrent
    {
        const int g = ln >> 4, l16 = ln & 15;
        #pragma unroll
        for (int rr=0; rr<4; rr++){
            float* row = &S[(wv*16 + rr*4 + g)*SMS];
            float mx = -3e38f;
            for (int m=l16; m<SMS; m+=16) mx = fmaxf(mx, row[m]);
            #pragma unroll
            for (int off=8; off; off>>=1) mx = fmaxf(mx, __shfl_xor(mx,off,64));
            float sum = 0.f;
            for (int m=l16; m<SMS; m+=16){ float e=__expf(row[m]-mx); row[m]=e; sum+=e; }
            #pragma unroll
            for (int off=8; off; off>>=1) sum += __shfl_xor(sum,off,64);
            float inv = 1.f/sum;
            for (int m=l16; m<SMS; m+=16) row[m] *= inv;
        }
    }
    __syncthreads();

    // ---- stage 3.5: postmix -> regs -> barrier -> bf16 P (stride SBS, pad cols zeroed)
    {
        const int nq = tid >> 5, l32 = tid & 31;
        float ov[7][8];
        #pragma unroll
        for (int kk=0; kk<7; kk++){
            int m = l32 + 32*kk;
            if (m < 197){
                float ph[8];
                #pragma unroll
                for (int o=0;o<8;o++) ph[o] = S[(o*8+nq)*SMS+m];
                #pragma unroll
                for (int o2=0;o2<8;o2++){
                    float v=0.f;
                    #pragma unroll
                    for (int o=0;o<8;o++) v += s_post[o2*8+o]*ph[o];
                    ov[kk][o2]=v;
                }
            }
        }
        __syncthreads();
        #pragma unroll
        for (int kk=0; kk<7; kk++){
            int m = l32 + 32*kk;   // covers 0..223 exactly
            #pragma unroll
            for (int o=0;o<8;o++)
                Sb[(o*8+nq)*SBS + m] = (m < 197) ? f2b(ov[kk][o]) : f2b(0.f);
        }
    }
    __syncthreads();

    // ---- stage 4: P @ V via MFMA; P frags hoisted, V double-buffered across dt
    const int frA = fr & 7;
    #pragma unroll
    for (int hh=0; hh<2; hh++){
        const int h = wv + hh*4;
        const bf16* vbase = vt + (size_t)(b*NHEAD+h)*DHEAD*VTS;
        bf16x8 pa[7];
        #pragma unroll
        for (int ks=0; ks<7; ks++)
            pa[ks] = *(const bf16x8*)(Sb + (h*8+frA)*SBS + ks*32 + fq*8);
        bf16x8 bv[7], bn[7];
        #pragma unroll
        for (int ks=0; ks<7; ks++)
            bv[ks] = *(const bf16x8*)(vbase + (size_t)fr*VTS + ks*32 + fq*8);
        #pragma unroll
        for (int dt=0; dt<6; dt++){
            if (dt < 5){
                #pragma unroll
                for (int ks=0; ks<7; ks++)
                    bn[ks] = *(const bf16x8*)(vbase + (size_t)((dt+1)*16+fr)*VTS + ks*32 + fq*8);
            }
            f32x4 acc = {};
            #pragma unroll
            for (int ks=0; ks<7; ks++)
                acc = __builtin_amdgcn_mfma_f32_16x16x32_bf16(pa[ks], bv[ks], acc,0,0,0);
            #pragma unroll
            for (int i=0;i<4;i++){
                int nqq = fq*4+i, n = n0+nqq;
                if (nqq < 8 && n < NTOK)
                    ao[((size_t)b*NTOK+n)*DIMC + h*DHEAD + dt*16+fr] = f2b(acc[i]);
            }
            #pragma unroll
            for (int ks=0; ks<7; ks++) bv[ks] = bn[ks];
        }
    }
}

// ---------------- m97-style MFMA GEMM: 128x128 tile, BK=64; 1D grid + bijective XCD swizzle (T1/m204)
enum { EPI_QKV=0, EPI_X1=1, EPI_GELU=2, EPI_OUT=3 };

template<int EPI>
__global__ __launch_bounds__(256) void gemm128(
    const bf16* __restrict__ A, int lda, int M,
    const bf16* __restrict__ B, int ldb,
    int K,
    const float* __restrict__ bias,
    const float* __restrict__ resid_f,  // X1: x (f32)
    const bf16* __restrict__ resid_b,   // OUT: x1b
    float* __restrict__ dst_f,          // OUT: final out
    bf16* __restrict__ dst_b, int lddb, // X1: x1b ; GELU: mid
    int row_off,                        // OUT: global row offset
    bf16* __restrict__ qo, bf16* __restrict__ ko, bf16* __restrict__ vto,
    int nbx)                            // x-tiles (N/128); grid is 1D = nbx*nby
{
    __shared__ bf16 As[2*128*32];   // two K-32 sub-tiles
    __shared__ bf16 Bs[2*128*32];
    const int tid = threadIdx.x;
    const int wv = tid >> 6, ln = tid & 63;
    const int fr = ln & 15, fq = ln >> 4;
    const int wr = (wv & 1)*64, wc = (wv >> 1)*64;
    // bijective XCD-chunk swizzle (m204): each XCD owns a contiguous wg range ->
    // blocks sharing an A-panel (same by) stay on one XCD's L2.
    const int nwgs = (int)gridDim.x;
    const int xcd = blockIdx.x & 7;
    const int qq = nwgs >> 3, rr = nwgs & 7;
    const int wg = (xcd < rr ? xcd*(qq+1) : rr*(qq+1) + (xcd-rr)*qq) + ((int)blockIdx.x >> 3);
    const int byi = wg / nbx, bxi = wg - byi*nbx;
    const int m0 = byi*128, n0 = bxi*128;
    const int lnrow = ln >> 2, lncol = (ln & 3)*8;
    f32x4 acc[4][4] = {};
    for (int k0=0; k0<K; k0+=64){
        #pragma unroll
        for (int t=0;t<2;t++){
            #pragma unroll
            for (int c=0;c<2;c++){
                int rA = m0 + (c*4+wv)*16 + lnrow;
                if (rA >= M) rA = M-1;
                gld16(A + (size_t)rA*lda + k0 + t*32 + lncol, &As[t*4096 + (c*4+wv)*16*32]);
                int rB = n0 + (c*4+wv)*16 + lnrow;
                gld16(B + (size_t)rB*ldb + k0 + t*32 + lncol, &Bs[t*4096 + (c*4+wv)*16*32]);
            }
        }
        __syncthreads();
        #pragma unroll
        for (int t=0;t<2;t++){
            bf16x8 af[4], bfv[4];
            #pragma unroll
            for (int i=0;i<4;i++){
                af[i]  = *(const bf16x8*)&As[t*4096 + (wr + i*16 + fr)*32 + fq*8];
                bfv[i] = *(const bf16x8*)&Bs[t*4096 + (wc + i*16 + fr)*32 + fq*8];
            }
            #pragma unroll
            for (int mi=0;mi<4;mi++)
                #pragma unroll
                for (int ni=0;ni<4;ni++)
                    acc[mi][ni] = __builtin_amdgcn_mfma_f32_16x16x32_bf16(af[mi], bfv[ni], acc[mi][ni],0,0,0);
        }
        __syncthreads();
    }
    #pragma unroll
    for (int mi=0;mi<4;mi++){
        #pragma unroll
        for (int ni=0;ni<4;ni++){
            #pragma unroll
            for (int i=0;i<4;i++){
                int row = m0 + wr + mi*16 + fq*4 + i;
                int col = n0 + wc + ni*16 + fr;
                if (row >= M) continue;
                float val = acc[mi][ni][i];
                if constexpr (EPI == EPI_QKV){
                    int which = col/768, rem = col - which*768;
                    int hh = rem/96, di = rem - hh*96;
                    int bb = row/NTOK, nn = row - bb*NTOK;
                    if (which == 0)      qo[(((size_t)bb*NHEAD+hh)*NTOK+nn)*DHEAD + di] = f2b(val);
                    else if (which == 1) ko[(((size_t)bb*NHEAD+hh)*NTOK+nn)*DHEAD + di] = f2b(val);
                    else {
                        vto[(((size_t)bb*NHEAD+hh)*DHEAD+di)*VTS + nn] = f2b(val);
                        if (nn < VTS - NTOK)   // fused vt pad-zero (cols 197..223)
                            vto[(((size_t)bb*NHEAD+hh)*DHEAD+di)*VTS + NTOK + nn] = f2b(0.f);
                    }
                } else if constexpr (EPI == EPI_X1){
                    dst_b[(size_t)row*DIMC + col] = f2b(val + bias[col] + resid_f[(size_t)row*DIMC + col]);
                } else if constexpr (EPI == EPI_GELU){
                    float t = val + bias[col];
                    t = 0.5f*t*(1.f + erff(t*0.70710678118654752f));
                    dst_b[(size_t)row*lddb + col] = f2b(t);
                } else { // EPI_OUT
                    size_t g = (size_t)(row + row_off)*DIMC + col;
                    dst_f[g] = val + bias[col] + b2f(resid_b[g]);
                }
            }
        }
    }
}

extern "C" void kernel_launch(void* const* d_in, const int* in_sizes, int n_in,
                              void* d_out, int out_size, void* d_ws, size_t ws_size,
                              hipStream_t stream)
{
    const float* x        = (const float*)d_in[0];
    const float* norm1_w  = (const float*)d_in[1];
    const float* norm1_b  = (const float*)d_in[2];
    const float* qkv_w    = (const float*)d_in[3];
    const float* scale    = (const float*)d_in[4];
    const float* pp_w     = (const float*)d_in[5];
    const float* pp_b     = (const float*)d_in[6];
    const float* ln1_w    = (const float*)d_in[7];
    const float* ln1_b    = (const float*)d_in[8];
    const float* fcp1_w   = (const float*)d_in[9];
    const float* fcp1_b   = (const float*)d_in[10];
    const float* ln2_w    = (const float*)d_in[11];
    const float* ln2_b    = (const float*)d_in[12];
    const float* fcp2_w   = (const float*)d_in[13];
    const float* fcp2_b   = (const float*)d_in[14];
    const float* ln3_w    = (const float*)d_in[15];
    const float* ln3_b    = (const float*)d_in[16];
    const float* fcp3_w   = (const float*)d_in[17];
    const float* fcp3_b   = (const float*)d_in[18];
    const float* pre_w    = (const float*)d_in[19];
    const float* post_w   = (const float*)d_in[20];
    const float* proj_w   = (const float*)d_in[21];
    const float* proj_b   = (const float*)d_in[22];
    const float* nrm2_w   = (const float*)d_in[23];
    const float* nrm2_b   = (const float*)d_in[24];
    const float* m1_w     = (const float*)d_in[25];
    const float* m1_b     = (const float*)d_in[26];
    const float* m2_w     = (const float*)d_in[27];
    const float* m2_b     = (const float*)d_in[28];
    const float* biases   = (const float*)d_in[30];
    float* out = (float*)d_out;

    char* ws = (char*)d_ws;
    float* p      = (float*)(ws + OFF_P);
    bf16*  qkvw_b = (bf16*)(ws + OFF_W);
    bf16*  prjw_b = (bf16*)(ws + OFF_W + SZ_QKVW);
    bf16*  m1w_b  = (bf16*)(ws + OFF_W + SZ_QKVW + SZ_PRJW);
    bf16*  m2w_b  = (bf16*)(ws + OFF_W + SZ_QKVW + SZ_PRJW + SZ_M1W);
    bf16*  h   = (bf16*)(ws + OFF_H);     // LN1 out -> ao -> mid (spans OFF_H..OFF_K)
    bf16*  qb  = (bf16*)(ws + OFF_Q);
    bf16*  kb  = (bf16*)(ws + OFF_K);     // -> h2
    bf16*  vt  = (bf16*)(ws + OFF_V);     // -> x1b
    bf16*  ao  = (bf16*)(ws + OFF_H);
    bf16*  x1b = (bf16*)(ws + OFF_V);
    bf16*  h2  = (bf16*)(ws + OFF_K);
    bf16*  mid = (bf16*)(ws + OFF_H);     // 6304x3072 bf16 = 38.7MB

    w_cvt_all<<<6912, 256, 0, stream>>>(qkv_w, proj_w, m1_w, m2_w, qkvw_b);
    pos_mlp<<<841, 64, 0, stream>>>(biases, pp_w, pp_b, ln1_w, ln1_b, fcp1_w, fcp1_b,
                                    ln2_w, ln2_b, fcp2_w, fcp2_b, ln3_w, ln3_b, fcp3_w, fcp3_b,
                                    pre_w, p);
    ln768<float><<<NROWS, 256, 0, stream>>>(x, norm1_w, norm1_b, h);
    gemm128<EPI_QKV><<<18*99, 256, 0, stream>>>(
        h, DIMC, NROWS, qkvw_b, DIMC, DIMC, nullptr, nullptr, nullptr, nullptr,
        nullptr, 0, 0, qb, kb, vt, 18);
    attn_mfma<<<1600, 256, 0, stream>>>(qb, kb, vt, p, scale, pre_w, post_w, ao);
    gemm128<EPI_X1><<<6*99, 256, 0, stream>>>(
        ao, DIMC, NROWS, prjw_b, DIMC, DIMC, proj_b, x, nullptr, nullptr,
        x1b, 0, 0, nullptr, nullptr, nullptr, 6);
    ln768<bf16><<<NROWS, 256, 0, stream>>>(x1b, nrm2_w, nrm2_b, h2);
    for (int c=0; c<2; c++){
        const int r0 = c*MHALF;
        gemm128<EPI_GELU><<<24*50, 256, 0, stream>>>(
            h2 + (size_t)r0*DIMC, DIMC, MHALF, m1w_b, DIMC, DIMC, m1_b,
            nullptr, nullptr, nullptr, mid, 3072, 0, nullptr, nullptr, nullptr, 24);
        gemm128<EPI_OUT><<<6*50, 256, 0, stream>>>(
            mid, 3072, MHALF, m2w_b, 3072, 3072, m2_b,
            nullptr, x1b, out, nullptr, 0, r0, nullptr, nullptr, nullptr, 6);
    }
    (void)in_sizes; (void)n_in; (void)out_size; (void)ws_size;
}

// Round 10
// 765.629 us; speedup vs baseline: 1.1088x; 1.0037x over previous
//
#include <hip/hip_runtime.h>
#include <hip/hip_bf16.h>
#include <math.h>

typedef __hip_bfloat16 bf16;
typedef __attribute__((ext_vector_type(8))) short bf16x8;   // 8 bf16 (4 VGPRs)
typedef __attribute__((ext_vector_type(4))) float f32x4;

__device__ __forceinline__ float b2f(bf16 x){ return __bfloat162float(x); }
__device__ __forceinline__ bf16  f2b(float x){ return __float2bfloat16(x); }
__device__ __forceinline__ float us2f(unsigned short u){ bf16 t; *(unsigned short*)&t = u; return __bfloat162float(t); }

// async global->LDS 16B (m97 pattern): LDS dest = wave-uniform base + lane*16
__device__ __forceinline__ void gld16(const bf16* g, bf16* l){
    __builtin_amdgcn_global_load_lds(
        (const __attribute__((address_space(1))) unsigned int*)g,
        (__attribute__((address_space(3))) unsigned int*)l, 16, 0, 0);
}

#define NTOK 197
#define NBATCH 64
#define NHEAD 8
#define DHEAD 96
#define DIMC 768
#define NROWS (NBATCH * NTOK)   // 12608
#define NQK   (NBATCH*NHEAD*NTOK)  // 100864 rows each for q,k
#define VTS 224                 // vt row stride (bf16), cols 197..223 zero-padded (by QKV epilogue)
#define SMS 200                 // LDS score row stride (f32)
#define SBS 224                 // bf16 P row stride (448B, 16B-aligned); aliases S (barrier-fenced)
#define MHALF 6304              // MLP row-chunk

// ---------------- workspace layout (bytes) ----------------
#define OFF_P   0ull
#define OFF_W   32768ull
#define SZ_QKVW 3538944ull
#define SZ_PRJW 1179648ull
#define SZ_M1W  4718592ull
#define SZ_M2W  4718592ull
#define OFF_H   14188544ull     // h -> ao -> mid(38.7MB spans OFF_H..OFF_K)
#define SZ_H    19365888ull
#define OFF_Q   33554432ull     // q
#define OFF_K   52920320ull     // k -> h2
#define OFF_V   72286208ull     // vt (22.02MB) -> x1b ; vt end 94,306,304
#define OFF_NRM 94306304ull     // inv norms: 2*NQK f32 = 806,912 B ; end 95,113,216 (< proven 96.9MB)

// ---------------- fused f32 -> bf16 weight convert (4 segments) ----------------
__global__ __launch_bounds__(256) void w_cvt_all(
    const float* __restrict__ s0, const float* __restrict__ s1,
    const float* __restrict__ s2, const float* __restrict__ s3, bf16* __restrict__ d)
{
    int i = blockIdx.x*256 + threadIdx.x;   // quad index, total 1,769,472
    const float* s; int off;
    if (i < 442368){ s=s0; off=i; }
    else if (i < 589824){ s=s1; off=i-442368; }
    else if (i < 1179648){ s=s2; off=i-589824; }
    else { s=s3; off=i-1179648; }
    float4 v = ((const float4*)s)[off];
    bf16 t[4] = {f2b(v.x), f2b(v.y), f2b(v.z), f2b(v.w)};
    ((ushort4*)d)[i] = *(ushort4*)t;
}

// ---------------- position-bias MLP (841 rows, tiny, all f32) ----------------
// NOTE: output is PREMIXED over heads: pout[idx][o] = sum_h pre_w[o,h] * p[idx,h]
__global__ __launch_bounds__(64) void pos_mlp(
    const float* __restrict__ biases, const float* __restrict__ pp_w, const float* __restrict__ pp_b,
    const float* __restrict__ ln1w, const float* __restrict__ ln1b,
    const float* __restrict__ f1w,  const float* __restrict__ f1b,
    const float* __restrict__ ln2w, const float* __restrict__ ln2b,
    const float* __restrict__ f2w,  const float* __restrict__ f2b,
    const float* __restrict__ ln3w, const float* __restrict__ ln3b,
    const float* __restrict__ f3w,  const float* __restrict__ f3b,
    const float* __restrict__ pre_w,
    float* __restrict__ pout)
{
    const int row = blockIdx.x, j = threadIdx.x;
    __shared__ float va[48], vb[48], pf[8];
    float b0 = biases[row*2], b1 = biases[row*2+1];
    if (j < 48) va[j] = b0*pp_w[j*2] + b1*pp_w[j*2+1] + pp_b[j];
    __syncthreads();
    {   float s=0.f, s2=0.f;
        for (int i=0;i<48;i++){ float t=va[i]; s+=t; s2+=t*t; }
        float mean=s*(1.f/48.f), var=s2*(1.f/48.f)-mean*mean, inv=rsqrtf(var+1e-5f);
        float r=0.f;
        if (j < 48){
            r = f1b[j];
            for (int i=0;i<48;i++){
                float t = fmaxf((va[i]-mean)*inv*ln1w[i] + ln1b[i], 0.f);
                r += t * f1w[j*48+i];
            }
        }
        __syncthreads();
        if (j < 48) vb[j] = r;
    }
    __syncthreads();
    {   float s=0.f, s2=0.f;
        for (int i=0;i<48;i++){ float t=vb[i]; s+=t; s2+=t*t; }
        float mean=s*(1.f/48.f), var=s2*(1.f/48.f)-mean*mean, inv=rsqrtf(var+1e-5f);
        float r=0.f;
        if (j < 48){
            r = f2b[j];
            for (int i=0;i<48;i++){
                float t = fmaxf((vb[i]-mean)*inv*ln2w[i] + ln2b[i], 0.f);
                r += t * f2w[j*48+i];
            }
        }
        __syncthreads();
        if (j < 48) va[j] = r;
    }
    __syncthreads();
    {   float s=0.f, s2=0.f;
        for (int i=0;i<48;i++){ float t=va[i]; s+=t; s2+=t*t; }
        float mean=s*(1.f/48.f), var=s2*(1.f/48.f)-mean*mean, inv=rsqrtf(var+1e-5f);
        if (j < 8){
            float r = f3b[j];
            for (int i=0;i<48;i++){
                float t = fmaxf((va[i]-mean)*inv*ln3w[i] + ln3b[i], 0.f);
                r += t * f3w[j*48+i];
            }
            pf[j] = r;
        }
    }
    __syncthreads();
    if (j < 8){
        float s = 0.f;
        #pragma unroll
        for (int hh=0; hh<8; hh++) s += pre_w[j*8+hh]*pf[hh];
        pout[row*8+j] = s;
    }
}

// ---------------- LayerNorm over 768 (f32 or bf16 in, bf16 out), vectorized loads ----------------
template<typename TIN>
__global__ __launch_bounds__(256) void ln768(
    const TIN* __restrict__ x, const float* __restrict__ w, const float* __restrict__ b,
    bf16* __restrict__ out)
{
    const int row = blockIdx.x, tid = threadIdx.x;
    const int wv = tid >> 6, ln = tid & 63;
    __shared__ float rs[4], rs2[4];
    const TIN* xr = x + (size_t)row * DIMC;
    float v[4] = {0.f,0.f,0.f,0.f};
    if (tid < 192){
        if constexpr (sizeof(TIN) == 4){
            float4 t4 = ((const float4*)xr)[tid];
            v[0]=t4.x; v[1]=t4.y; v[2]=t4.z; v[3]=t4.w;
        } else {
            ushort4 t4 = ((const ushort4*)xr)[tid];
            v[0]=us2f(t4.x); v[1]=us2f(t4.y); v[2]=us2f(t4.z); v[3]=us2f(t4.w);
        }
    }
    float s = v[0]+v[1]+v[2]+v[3];
    float s2 = v[0]*v[0]+v[1]*v[1]+v[2]*v[2]+v[3]*v[3];
    #pragma unroll
    for (int off=32; off; off>>=1){ s += __shfl_xor(s,off,64); s2 += __shfl_xor(s2,off,64); }
    if (ln == 0){ rs[wv]=s; rs2[wv]=s2; }
    __syncthreads();
    s = rs[0]+rs[1]+rs[2]+rs[3]; s2 = rs2[0]+rs2[1]+rs2[2]+rs2[3];
    float mean = s*(1.f/768.f), var = s2*(1.f/768.f) - mean*mean;
    float inv = rsqrtf(var + 1e-5f);
    if (tid < 192){
        float4 w4 = ((const float4*)w)[tid];
        float4 b4 = ((const float4*)b)[tid];
        bf16 o[4];
        o[0] = f2b((v[0]-mean)*inv*w4.x + b4.x);
        o[1] = f2b((v[1]-mean)*inv*w4.y + b4.y);
        o[2] = f2b((v[2]-mean)*inv*w4.z + b4.z);
        o[3] = f2b((v[3]-mean)*inv*w4.w + b4.w);
        ((ushort4*)(out + (size_t)row*DIMC))[tid] = *(ushort4*)o;
    }
}

// ---------------- q/k row inverse norms (bilinear fold: normalization moves to score-scale) ----
// inv[row<NQK]   = min(scale[h],100)/max(|q_row|,1e-12)
// inv[NQK+row]   = 1/max(|k_row|,1e-12)
__global__ __launch_bounds__(256) void qknorm(
    const bf16* __restrict__ q, const bf16* __restrict__ k,
    const float* __restrict__ scale, float* __restrict__ inv)
{
    const int wv = threadIdx.x >> 6, ln = threadIdx.x & 63;
    const int g = ln >> 4, j = ln & 15;
    const size_t NR = (size_t)NQK;
    size_t row = (size_t)blockIdx.x*16 + wv*4 + g;
    bool isq = row < NR;
    const bf16* ptr = isq ? (q + row*DHEAD) : (k + (row-NR)*DHEAD);
    float ss = 0.f;
    if (j < 12){
        bf16x8 vv = *(const bf16x8*)(ptr + j*8);
        #pragma unroll
        for (int e=0;e<8;e++){ float f = us2f((unsigned short)vv[e]); ss += f*f; }
    }
    #pragma unroll
    for (int off=8; off; off>>=1) ss += __shfl_xor(ss, off, 64);
    if (j == 0){
        float iv = 1.f / fmaxf(sqrtf(ss), 1e-12f);
        if (isq){
            int h = (int)((row / NTOK) & (NHEAD-1));
            iv *= fminf(scale[h], 100.f);
        }
        inv[row] = iv;
    }
}

// ---------------- MFMA attention ----------------
// v7: v3 structure (best measured: 133.4us) with RAW q/k MFMA; l2 normalization applied
// bilinearly at the S-write (acc * invq[n] * invk[m], scalars from qknorm, L2-resident).
__global__ __launch_bounds__(256) void attn_mfma(
    const bf16* __restrict__ q, const bf16* __restrict__ k, const bf16* __restrict__ vt,
    const float* __restrict__ p,    // premixed (841 x 8, o-indexed)
    const float* __restrict__ inv,  // [2*NQK] row inverse norms (q w/ scale, then k)
    const float* __restrict__ pre_w, const float* __restrict__ post_w,
    bf16* __restrict__ ao)
{
    const int id = blockIdx.x;
    const int r8 = id & 7, t8 = id >> 3;
    const int bx = t8 % 25, b = r8 + 8*(t8/25);
    const int n0 = bx*8;
    const int tid = threadIdx.x, wv = tid>>6, ln = tid&63;
    const int fr = ln&15, fq = ln>>4;
    __shared__ float S[NHEAD*8*SMS];         // 51,200 B f32 scores
    __shared__ float s_pre[64], s_post[64];
    bf16* Sb = (bf16*)S;                     // P bf16 alias, row stride SBS=224 (448B)
    if (tid < 64){ s_pre[tid]=pre_w[tid]; s_post[tid]=post_w[tid]; }

    // ---- stage 1: raw scores scaled at write, 13 K-tiles, 2-deep k prefetch
    #pragma unroll
    for (int hh=0; hh<2; hh++){
        const int h = wv + hh*4;
        const float* iqh = inv + (size_t)(b*NHEAD+h)*NTOK;
        const float* ikh = inv + (size_t)NQK + (size_t)(b*NHEAD+h)*NTOK;
        float iqv[4];
        #pragma unroll
        for (int i=0;i<4;i++){
            int nidx = n0 + fq*4 + i; if (nidx > 196) nidx = 196;
            iqv[i] = iqh[nidx];
        }
        int qr = n0 + fr; if (qr > 196) qr = 196;
        const bf16* qrow = q + ((size_t)(b*NHEAD+h)*NTOK + qr)*DHEAD + fq*8;
        bf16x8 a0 = *(const bf16x8*)(qrow);
        bf16x8 a1 = *(const bf16x8*)(qrow+32);
        bf16x8 a2 = *(const bf16x8*)(qrow+64);
        const bf16* kb0 = k + (size_t)(b*NHEAD+h)*NTOK*DHEAD + fq*8;
        auto krow = [&](int mt){ int nr = mt*16+fr; if (nr>196) nr=196; return kb0 + (size_t)nr*DHEAD; };
        const bf16* kp0 = krow(0);
        bf16x8 c00 = *(const bf16x8*)(kp0), c01 = *(const bf16x8*)(kp0+32), c02 = *(const bf16x8*)(kp0+64);
        const bf16* kp1 = krow(1);
        bf16x8 c10 = *(const bf16x8*)(kp1), c11 = *(const bf16x8*)(kp1+32), c12 = *(const bf16x8*)(kp1+64);
        #pragma unroll
        for (int mt=0; mt<13; mt++){
            int mc = mt*16 + fr; if (mc > 196) mc = 196;
            float ik = ikh[mc];                     // issued before MFMAs; hides under them
            bf16x8 p0, p1, p2;
            if (mt < 11){
                const bf16* kn = krow(mt+2);
                p0 = *(const bf16x8*)(kn); p1 = *(const bf16x8*)(kn+32); p2 = *(const bf16x8*)(kn+64);
            }
            f32x4 acc = {};
            acc = __builtin_amdgcn_mfma_f32_16x16x32_bf16(a0, c00, acc,0,0,0);
            acc = __builtin_amdgcn_mfma_f32_16x16x32_bf16(a1, c01, acc,0,0,0);
            acc = __builtin_amdgcn_mfma_f32_16x16x32_bf16(a2, c02, acc,0,0,0);
            int col = mt*16 + fr;
            if (fq < 2 && col < SMS){
                #pragma unroll
                for (int i=0;i<4;i++)
                    S[(h*8 + fq*4+i)*SMS + col] = acc[i]*iqv[i]*ik;
            }
            c00=c10; c01=c11; c02=c12;
            if (mt < 11){ c10=p0; c11=p1; c12=p2; }
        }
    }
    __syncthreads();

    // ---- stage 2: premix + premixed bias + geometric mask (cols 197..199 -> -1e9)
    {
        const int sco[8] = {1,1,4,4,7,7,1000,1000};
        const int nq = tid >> 5, l32 = tid & 31;
        int n = n0 + nq; if (n > 196) n = 196;
        const bool nAlways = (n == 0);
        int ri=0, ci=0;
        if (!nAlways){ ri=(n-1)/14; ci=(n-1)-ri*14; }
        for (int m = l32; m < SMS; m += 32){
            if (m >= 197){
                #pragma unroll
                for (int o=0;o<8;o++) S[(o*8+nq)*SMS+m] = -1e9f;
                continue;
            }
            bool always = nAlways || (m==0);
            int rj=0, cj=0;
            if (m > 0){ rj=(m-1)/14; cj=(m-1)-rj*14; }
            int dr = ri-rj; if (dr<0) dr=-dr;
            int dc = ci-cj; if (dc<0) dc=-dc;
            int idx = always ? 730 : (ri-rj+13)*27 + (ci-cj+13);
            const float* pv = p + idx*8;
            float sh[8];
            #pragma unroll
            for (int h2=0;h2<8;h2++) sh[h2] = S[(h2*8+nq)*SMS+m];
            float ov[8];
            #pragma unroll
            for (int o=0;o<8;o++){
                float v = pv[o];
                #pragma unroll
                for (int h2=0;h2<8;h2++) v += s_pre[o*8+h2]*sh[h2];
                bool on = always || (dr<=sco[o] && dc<=sco[o]);
                ov[o] = on ? v : -1e9f;
            }
            #pragma unroll
            for (int o=0;o<8;o++) S[(o*8+nq)*SMS+m] = ov[o];
        }
    }
    __syncthreads();

    // ---- stage 3: softmax per (o,nq) row over 200 cols — 16-lane groups, 4 rows/wave concurrent
    {
        const int g = ln >> 4, l16 = ln & 15;
        #pragma unroll
        for (int rr=0; rr<4; rr++){
            float* row = &S[(wv*16 + rr*4 + g)*SMS];
            float mx = -3e38f;
            for (int m=l16; m<SMS; m+=16) mx = fmaxf(mx, row[m]);
            #pragma unroll
            for (int off=8; off; off>>=1) mx = fmaxf(mx, __shfl_xor(mx,off,64));
            float sum = 0.f;
            for (int m=l16; m<SMS; m+=16){ float e=__expf(row[m]-mx); row[m]=e; sum+=e; }
            #pragma unroll
            for (int off=8; off; off>>=1) sum += __shfl_xor(sum,off,64);
            float inv2 = 1.f/sum;
            for (int m=l16; m<SMS; m+=16) row[m] *= inv2;
        }
    }
    __syncthreads();

    // ---- stage 3.5: postmix -> regs -> barrier -> bf16 P (stride SBS, pad cols zeroed)
    {
        const int nq = tid >> 5, l32 = tid & 31;
        float ov[7][8];
        #pragma unroll
        for (int kk=0; kk<7; kk++){
            int m = l32 + 32*kk;
            if (m < 197){
                float ph[8];
                #pragma unroll
                for (int o=0;o<8;o++) ph[o] = S[(o*8+nq)*SMS+m];
                #pragma unroll
                for (int o2=0;o2<8;o2++){
                    float v=0.f;
                    #pragma unroll
                    for (int o=0;o<8;o++) v += s_post[o2*8+o]*ph[o];
                    ov[kk][o2]=v;
                }
            }
        }
        __syncthreads();
        #pragma unroll
        for (int kk=0; kk<7; kk++){
            int m = l32 + 32*kk;   // covers 0..223 exactly
            #pragma unroll
            for (int o=0;o<8;o++)
                Sb[(o*8+nq)*SBS + m] = (m < 197) ? f2b(ov[kk][o]) : f2b(0.f);
        }
    }
    __syncthreads();

    // ---- stage 4: P @ V via MFMA; P frags hoisted, V double-buffered across dt
    const int frA = fr & 7;
    #pragma unroll
    for (int hh=0; hh<2; hh++){
        const int h = wv + hh*4;
        const bf16* vbase = vt + (size_t)(b*NHEAD+h)*DHEAD*VTS;
        bf16x8 pa[7];
        #pragma unroll
        for (int ks=0; ks<7; ks++)
            pa[ks] = *(const bf16x8*)(Sb + (h*8+frA)*SBS + ks*32 + fq*8);
        bf16x8 bv[7], bn[7];
        #pragma unroll
        for (int ks=0; ks<7; ks++)
            bv[ks] = *(const bf16x8*)(vbase + (size_t)fr*VTS + ks*32 + fq*8);
        #pragma unroll
        for (int dt=0; dt<6; dt++){
            if (dt < 5){
                #pragma unroll
                for (int ks=0; ks<7; ks++)
                    bn[ks] = *(const bf16x8*)(vbase + (size_t)((dt+1)*16+fr)*VTS + ks*32 + fq*8);
            }
            f32x4 acc = {};
            #pragma unroll
            for (int ks=0; ks<7; ks++)
                acc = __builtin_amdgcn_mfma_f32_16x16x32_bf16(pa[ks], bv[ks], acc,0,0,0);
            #pragma unroll
            for (int i=0;i<4;i++){
                int nqq = fq*4+i, n = n0+nqq;
                if (nqq < 8 && n < NTOK)
                    ao[((size_t)b*NTOK+n)*DIMC + h*DHEAD + dt*16+fr] = f2b(acc[i]);
            }
            #pragma unroll
            for (int ks=0; ks<7; ks++) bv[ks] = bn[ks];
        }
    }
}

// ---------------- m97-style MFMA GEMM: 128x128 tile, BK=64; 1D grid + bijective XCD swizzle (T1/m204)
enum { EPI_QKV=0, EPI_X1=1, EPI_GELU=2, EPI_OUT=3 };

template<int EPI>
__global__ __launch_bounds__(256) void gemm128(
    const bf16* __restrict__ A, int lda, int M,
    const bf16* __restrict__ B, int ldb,
    int K,
    const float* __restrict__ bias,
    const float* __restrict__ resid_f,  // X1: x (f32)
    const bf16* __restrict__ resid_b,   // OUT: x1b
    float* __restrict__ dst_f,          // OUT: final out
    bf16* __restrict__ dst_b, int lddb, // X1: x1b ; GELU: mid
    int row_off,                        // OUT: global row offset
    bf16* __restrict__ qo, bf16* __restrict__ ko, bf16* __restrict__ vto,
    int nbx)                            // x-tiles (N/128); grid is 1D = nbx*nby
{
    __shared__ bf16 As[2*128*32];   // two K-32 sub-tiles
    __shared__ bf16 Bs[2*128*32];
    const int tid = threadIdx.x;
    const int wv = tid >> 6, ln = tid & 63;
    const int fr = ln & 15, fq = ln >> 4;
    const int wr = (wv & 1)*64, wc = (wv >> 1)*64;
    // bijective XCD-chunk swizzle (m204): each XCD owns a contiguous wg range ->
    // blocks sharing an A-panel (same by) stay on one XCD's L2.
    const int nwgs = (int)gridDim.x;
    const int xcd = blockIdx.x & 7;
    const int qq = nwgs >> 3, rr = nwgs & 7;
    const int wg = (xcd < rr ? xcd*(qq+1) : rr*(qq+1) + (xcd-rr)*qq) + ((int)blockIdx.x >> 3);
    const int byi = wg / nbx, bxi = wg - byi*nbx;
    const int m0 = byi*128, n0 = bxi*128;
    const int lnrow = ln >> 2, lncol = (ln & 3)*8;
    f32x4 acc[4][4] = {};
    for (int k0=0; k0<K; k0+=64){
        #pragma unroll
        for (int t=0;t<2;t++){
            #pragma unroll
            for (int c=0;c<2;c++){
                int rA = m0 + (c*4+wv)*16 + lnrow;
                if (rA >= M) rA = M-1;
                gld16(A + (size_t)rA*lda + k0 + t*32 + lncol, &As[t*4096 + (c*4+wv)*16*32]);
                int rB = n0 + (c*4+wv)*16 + lnrow;
                gld16(B + (size_t)rB*ldb + k0 + t*32 + lncol, &Bs[t*4096 + (c*4+wv)*16*32]);
            }
        }
        __syncthreads();
        #pragma unroll
        for (int t=0;t<2;t++){
            bf16x8 af[4], bfv[4];
            #pragma unroll
            for (int i=0;i<4;i++){
                af[i]  = *(const bf16x8*)&As[t*4096 + (wr + i*16 + fr)*32 + fq*8];
                bfv[i] = *(const bf16x8*)&Bs[t*4096 + (wc + i*16 + fr)*32 + fq*8];
            }
            #pragma unroll
            for (int mi=0;mi<4;mi++)
                #pragma unroll
                for (int ni=0;ni<4;ni++)
                    acc[mi][ni] = __builtin_amdgcn_mfma_f32_16x16x32_bf16(af[mi], bfv[ni], acc[mi][ni],0,0,0);
        }
        __syncthreads();
    }
    #pragma unroll
    for (int mi=0;mi<4;mi++){
        #pragma unroll
        for (int ni=0;ni<4;ni++){
            #pragma unroll
            for (int i=0;i<4;i++){
                int row = m0 + wr + mi*16 + fq*4 + i;
                int col = n0 + wc + ni*16 + fr;
                if (row >= M) continue;
                float val = acc[mi][ni][i];
                if constexpr (EPI == EPI_QKV){
                    int which = col/768, rem = col - which*768;
                    int hh = rem/96, di = rem - hh*96;
                    int bb = row/NTOK, nn = row - bb*NTOK;
                    if (which == 0)      qo[(((size_t)bb*NHEAD+hh)*NTOK+nn)*DHEAD + di] = f2b(val);
                    else if (which == 1) ko[(((size_t)bb*NHEAD+hh)*NTOK+nn)*DHEAD + di] = f2b(val);
                    else {
                        vto[(((size_t)bb*NHEAD+hh)*DHEAD+di)*VTS + nn] = f2b(val);
                        if (nn < VTS - NTOK)   // fused vt pad-zero (cols 197..223)
                            vto[(((size_t)bb*NHEAD+hh)*DHEAD+di)*VTS + NTOK + nn] = f2b(0.f);
                    }
                } else if constexpr (EPI == EPI_X1){
                    dst_b[(size_t)row*DIMC + col] = f2b(val + bias[col] + resid_f[(size_t)row*DIMC + col]);
                } else if constexpr (EPI == EPI_GELU){
                    float t = val + bias[col];
                    t = 0.5f*t*(1.f + erff(t*0.70710678118654752f));
                    dst_b[(size_t)row*lddb + col] = f2b(t);
                } else { // EPI_OUT
                    size_t g = (size_t)(row + row_off)*DIMC + col;
                    dst_f[g] = val + bias[col] + b2f(resid_b[g]);
                }
            }
        }
    }
}

extern "C" void kernel_launch(void* const* d_in, const int* in_sizes, int n_in,
                              void* d_out, int out_size, void* d_ws, size_t ws_size,
                              hipStream_t stream)
{
    const float* x        = (const float*)d_in[0];
    const float* norm1_w  = (const float*)d_in[1];
    const float* norm1_b  = (const float*)d_in[2];
    const float* qkv_w    = (const float*)d_in[3];
    const float* scale    = (const float*)d_in[4];
    const float* pp_w     = (const float*)d_in[5];
    const float* pp_b     = (const float*)d_in[6];
    const float* ln1_w    = (const float*)d_in[7];
    const float* ln1_b    = (const float*)d_in[8];
    const float* fcp1_w   = (const float*)d_in[9];
    const float* fcp1_b   = (const float*)d_in[10];
    const float* ln2_w    = (const float*)d_in[11];
    const float* ln2_b    = (const float*)d_in[12];
    const float* fcp2_w   = (const float*)d_in[13];
    const float* fcp2_b   = (const float*)d_in[14];
    const float* ln3_w    = (const float*)d_in[15];
    const float* ln3_b    = (const float*)d_in[16];
    const float* fcp3_w   = (const float*)d_in[17];
    const float* fcp3_b   = (const float*)d_in[18];
    const float* pre_w    = (const float*)d_in[19];
    const float* post_w   = (const float*)d_in[20];
    const float* proj_w   = (const float*)d_in[21];
    const float* proj_b   = (const float*)d_in[22];
    const float* nrm2_w   = (const float*)d_in[23];
    const float* nrm2_b   = (const float*)d_in[24];
    const float* m1_w     = (const float*)d_in[25];
    const float* m1_b     = (const float*)d_in[26];
    const float* m2_w     = (const float*)d_in[27];
    const float* m2_b     = (const float*)d_in[28];
    const float* biases   = (const float*)d_in[30];
    float* out = (float*)d_out;

    char* ws = (char*)d_ws;
    float* p      = (float*)(ws + OFF_P);
    bf16*  qkvw_b = (bf16*)(ws + OFF_W);
    bf16*  prjw_b = (bf16*)(ws + OFF_W + SZ_QKVW);
    bf16*  m1w_b  = (bf16*)(ws + OFF_W + SZ_QKVW + SZ_PRJW);
    bf16*  m2w_b  = (bf16*)(ws + OFF_W + SZ_QKVW + SZ_PRJW + SZ_M1W);
    bf16*  h   = (bf16*)(ws + OFF_H);     // LN1 out -> ao -> mid (spans OFF_H..OFF_K)
    bf16*  qb  = (bf16*)(ws + OFF_Q);
    bf16*  kb  = (bf16*)(ws + OFF_K);     // -> h2
    bf16*  vt  = (bf16*)(ws + OFF_V);     // -> x1b
    float* inv = (float*)(ws + OFF_NRM);
    bf16*  ao  = (bf16*)(ws + OFF_H);
    bf16*  x1b = (bf16*)(ws + OFF_V);
    bf16*  h2  = (bf16*)(ws + OFF_K);
    bf16*  mid = (bf16*)(ws + OFF_H);     // 6304x3072 bf16 = 38.7MB

    w_cvt_all<<<6912, 256, 0, stream>>>(qkv_w, proj_w, m1_w, m2_w, qkvw_b);
    pos_mlp<<<841, 64, 0, stream>>>(biases, pp_w, pp_b, ln1_w, ln1_b, fcp1_w, fcp1_b,
                                    ln2_w, ln2_b, fcp2_w, fcp2_b, ln3_w, ln3_b, fcp3_w, fcp3_b,
                                    pre_w, p);
    ln768<float><<<NROWS, 256, 0, stream>>>(x, norm1_w, norm1_b, h);
    gemm128<EPI_QKV><<<18*99, 256, 0, stream>>>(
        h, DIMC, NROWS, qkvw_b, DIMC, DIMC, nullptr, nullptr, nullptr, nullptr,
        nullptr, 0, 0, qb, kb, vt, 18);
    qknorm<<<(2*NQK)/16, 256, 0, stream>>>(qb, kb, scale, inv);
    attn_mfma<<<1600, 256, 0, stream>>>(qb, kb, vt, p, inv, pre_w, post_w, ao);
    gemm128<EPI_X1><<<6*99, 256, 0, stream>>>(
        ao, DIMC, NROWS, prjw_b, DIMC, DIMC, proj_b, x, nullptr, nullptr,
        x1b, 0, 0, nullptr, nullptr, nullptr, 6);
    ln768<bf16><<<NROWS, 256, 0, stream>>>(x1b, nrm2_w, nrm2_b, h2);
    for (int c=0; c<2; c++){
        const int r0 = c*MHALF;
        gemm128<EPI_GELU><<<24*50, 256, 0, stream>>>(
            h2 + (size_t)r0*DIMC, DIMC, MHALF, m1w_b, DIMC, DIMC, m1_b,
            nullptr, nullptr, nullptr, mid, 3072, 0, nullptr, nullptr, nullptr, 24);
        gemm128<EPI_OUT><<<6*50, 256, 0, stream>>>(
            mid, 3072, MHALF, m2w_b, 3072, 3072, m2_b,
            nullptr, x1b, out, nullptr, 0, r0, nullptr, nullptr, nullptr, 6);
    }
    (void)in_sizes; (void)n_in; (void)out_size; (void)ws_size;
}

// Round 12
// 763.554 us; speedup vs baseline: 1.1118x; 1.0027x over previous
//
#include <hip/hip_runtime.h>
#include <hip/hip_bf16.h>
#include <math.h>

typedef __hip_bfloat16 bf16;
typedef __attribute__((ext_vector_type(8))) short bf16x8;   // 8 bf16 (4 VGPRs)
typedef __attribute__((ext_vector_type(4))) float f32x4;

__device__ __forceinline__ float b2f(bf16 x){ return __bfloat162float(x); }
__device__ __forceinline__ bf16  f2b(float x){ return __float2bfloat16(x); }
__device__ __forceinline__ float us2f(unsigned short u){ bf16 t; *(unsigned short*)&t = u; return __bfloat162float(t); }

// async global->LDS 16B (m97 pattern): LDS dest = wave-uniform base + lane*16
__device__ __forceinline__ void gld16(const bf16* g, bf16* l){
    __builtin_amdgcn_global_load_lds(
        (const __attribute__((address_space(1))) unsigned int*)g,
        (__attribute__((address_space(3))) unsigned int*)l, 16, 0, 0);
}

#define NTOK 197
#define NBATCH 64
#define NHEAD 8
#define DHEAD 96
#define DIMC 768
#define NROWS (NBATCH * NTOK)   // 12608
#define NQK   (NBATCH*NHEAD*NTOK)  // 100864 rows each for q,k
#define VTS 224                 // vt row stride (bf16), cols 197..223 zero-padded (by QKV epilogue)
#define SMS 200                 // LDS score row stride (f32)
#define SBS 224                 // bf16 P row stride (448B, 16B-aligned); aliases S (barrier-fenced)
#define MHALF 6304              // MLP row-chunk

// ---------------- workspace layout (bytes) ----------------
#define OFF_P   0ull
#define OFF_W   32768ull
#define SZ_QKVW 3538944ull
#define SZ_PRJW 1179648ull
#define SZ_M1W  4718592ull
#define SZ_M2W  4718592ull
#define OFF_H   14188544ull     // h -> ao -> mid(38.7MB spans OFF_H..OFF_K)
#define SZ_H    19365888ull
#define OFF_Q   33554432ull     // q
#define OFF_K   52920320ull     // k -> h2
#define OFF_V   72286208ull     // vt (22.02MB) -> x1b ; vt end 94,306,304
#define OFF_NRM 94306304ull     // inv norms: 2*NQK f32 = 806,912 B ; end 95,113,216 (< proven 96.9MB)

// ---------------- fused f32 -> bf16 weight convert (4 segments) ----------------
__global__ __launch_bounds__(256) void w_cvt_all(
    const float* __restrict__ s0, const float* __restrict__ s1,
    const float* __restrict__ s2, const float* __restrict__ s3, bf16* __restrict__ d)
{
    int i = blockIdx.x*256 + threadIdx.x;   // quad index, total 1,769,472
    const float* s; int off;
    if (i < 442368){ s=s0; off=i; }
    else if (i < 589824){ s=s1; off=i-442368; }
    else if (i < 1179648){ s=s2; off=i-589824; }
    else { s=s3; off=i-1179648; }
    float4 v = ((const float4*)s)[off];
    bf16 t[4] = {f2b(v.x), f2b(v.y), f2b(v.z), f2b(v.w)};
    ((ushort4*)d)[i] = *(ushort4*)t;
}

// ---------------- position-bias MLP (841 rows, tiny, all f32) ----------------
// NOTE: output is PREMIXED over heads: pout[idx][o] = sum_h pre_w[o,h] * p[idx,h]
__global__ __launch_bounds__(64) void pos_mlp(
    const float* __restrict__ biases, const float* __restrict__ pp_w, const float* __restrict__ pp_b,
    const float* __restrict__ ln1w, const float* __restrict__ ln1b,
    const float* __restrict__ f1w,  const float* __restrict__ f1b,
    const float* __restrict__ ln2w, const float* __restrict__ ln2b,
    const float* __restrict__ f2w,  const float* __restrict__ f2b,
    const float* __restrict__ ln3w, const float* __restrict__ ln3b,
    const float* __restrict__ f3w,  const float* __restrict__ f3b,
    const float* __restrict__ pre_w,
    float* __restrict__ pout)
{
    const int row = blockIdx.x, j = threadIdx.x;
    __shared__ float va[48], vb[48], pf[8];
    float b0 = biases[row*2], b1 = biases[row*2+1];
    if (j < 48) va[j] = b0*pp_w[j*2] + b1*pp_w[j*2+1] + pp_b[j];
    __syncthreads();
    {   float s=0.f, s2=0.f;
        for (int i=0;i<48;i++){ float t=va[i]; s+=t; s2+=t*t; }
        float mean=s*(1.f/48.f), var=s2*(1.f/48.f)-mean*mean, inv=rsqrtf(var+1e-5f);
        float r=0.f;
        if (j < 48){
            r = f1b[j];
            for (int i=0;i<48;i++){
                float t = fmaxf((va[i]-mean)*inv*ln1w[i] + ln1b[i], 0.f);
                r += t * f1w[j*48+i];
            }
        }
        __syncthreads();
        if (j < 48) vb[j] = r;
    }
    __syncthreads();
    {   float s=0.f, s2=0.f;
        for (int i=0;i<48;i++){ float t=vb[i]; s+=t; s2+=t*t; }
        float mean=s*(1.f/48.f), var=s2*(1.f/48.f)-mean*mean, inv=rsqrtf(var+1e-5f);
        float r=0.f;
        if (j < 48){
            r = f2b[j];
            for (int i=0;i<48;i++){
                float t = fmaxf((vb[i]-mean)*inv*ln2w[i] + ln2b[i], 0.f);
                r += t * f2w[j*48+i];
            }
        }
        __syncthreads();
        if (j < 48) va[j] = r;
    }
    __syncthreads();
    {   float s=0.f, s2=0.f;
        for (int i=0;i<48;i++){ float t=va[i]; s+=t; s2+=t*t; }
        float mean=s*(1.f/48.f), var=s2*(1.f/48.f)-mean*mean, inv=rsqrtf(var+1e-5f);
        if (j < 8){
            float r = f3b[j];
            for (int i=0;i<48;i++){
                float t = fmaxf((va[i]-mean)*inv*ln3w[i] + ln3b[i], 0.f);
                r += t * f3w[j*48+i];
            }
            pf[j] = r;
        }
    }
    __syncthreads();
    if (j < 8){
        float s = 0.f;
        #pragma unroll
        for (int hh=0; hh<8; hh++) s += pre_w[j*8+hh]*pf[hh];
        pout[row*8+j] = s;
    }
}

// ---------------- LayerNorm over 768 (f32 or bf16 in, bf16 out), vectorized loads ----------------
template<typename TIN>
__global__ __launch_bounds__(256) void ln768(
    const TIN* __restrict__ x, const float* __restrict__ w, const float* __restrict__ b,
    bf16* __restrict__ out)
{
    const int row = blockIdx.x, tid = threadIdx.x;
    const int wv = tid >> 6, ln = tid & 63;
    __shared__ float rs[4], rs2[4];
    const TIN* xr = x + (size_t)row * DIMC;
    float v[4] = {0.f,0.f,0.f,0.f};
    if (tid < 192){
        if constexpr (sizeof(TIN) == 4){
            float4 t4 = ((const float4*)xr)[tid];
            v[0]=t4.x; v[1]=t4.y; v[2]=t4.z; v[3]=t4.w;
        } else {
            ushort4 t4 = ((const ushort4*)xr)[tid];
            v[0]=us2f(t4.x); v[1]=us2f(t4.y); v[2]=us2f(t4.z); v[3]=us2f(t4.w);
        }
    }
    float s = v[0]+v[1]+v[2]+v[3];
    float s2 = v[0]*v[0]+v[1]*v[1]+v[2]*v[2]+v[3]*v[3];
    #pragma unroll
    for (int off=32; off; off>>=1){ s += __shfl_xor(s,off,64); s2 += __shfl_xor(s2,off,64); }
    if (ln == 0){ rs[wv]=s; rs2[wv]=s2; }
    __syncthreads();
    s = rs[0]+rs[1]+rs[2]+rs[3]; s2 = rs2[0]+rs2[1]+rs2[2]+rs2[3];
    float mean = s*(1.f/768.f), var = s2*(1.f/768.f) - mean*mean;
    float inv = rsqrtf(var + 1e-5f);
    if (tid < 192){
        float4 w4 = ((const float4*)w)[tid];
        float4 b4 = ((const float4*)b)[tid];
        bf16 o[4];
        o[0] = f2b((v[0]-mean)*inv*w4.x + b4.x);
        o[1] = f2b((v[1]-mean)*inv*w4.y + b4.y);
        o[2] = f2b((v[2]-mean)*inv*w4.z + b4.z);
        o[3] = f2b((v[3]-mean)*inv*w4.w + b4.w);
        ((ushort4*)(out + (size_t)row*DIMC))[tid] = *(ushort4*)o;
    }
}

// ---------------- q/k row inverse norms (bilinear fold: normalization moves to score-scale) ----
// inv[row<NQK]   = min(scale[h],100)/max(|q_row|,1e-12)
// inv[NQK+row]   = 1/max(|k_row|,1e-12)
__global__ __launch_bounds__(256) void qknorm(
    const bf16* __restrict__ q, const bf16* __restrict__ k,
    const float* __restrict__ scale, float* __restrict__ inv)
{
    const int wv = threadIdx.x >> 6, ln = threadIdx.x & 63;
    const int g = ln >> 4, j = ln & 15;
    const size_t NR = (size_t)NQK;
    size_t row = (size_t)blockIdx.x*16 + wv*4 + g;
    bool isq = row < NR;
    const bf16* ptr = isq ? (q + row*DHEAD) : (k + (row-NR)*DHEAD);
    float ss = 0.f;
    if (j < 12){
        bf16x8 vv = *(const bf16x8*)(ptr + j*8);
        #pragma unroll
        for (int e=0;e<8;e++){ float f = us2f((unsigned short)vv[e]); ss += f*f; }
    }
    #pragma unroll
    for (int off=8; off; off>>=1) ss += __shfl_xor(ss, off, 64);
    if (j == 0){
        float iv = 1.f / fmaxf(sqrtf(ss), 1e-12f);
        if (isq){
            int h = (int)((row / NTOK) & (NHEAD-1));
            iv *= fminf(scale[h], 100.f);
        }
        inv[row] = iv;
    }
}

// ---------------- MFMA attention ----------------
// v8: v7 + batch-hoisted ik loads. All 13 ikv[mt] per head load back-to-back BEFORE the
// mt loop (latency hides under first k-tile's MFMAs); S-write uses register-resident scale.
__global__ __launch_bounds__(256) void attn_mfma(
    const bf16* __restrict__ q, const bf16* __restrict__ k, const bf16* __restrict__ vt,
    const float* __restrict__ p,    // premixed (841 x 8, o-indexed)
    const float* __restrict__ inv,  // [2*NQK] row inverse norms (q w/ scale, then k)
    const float* __restrict__ pre_w, const float* __restrict__ post_w,
    bf16* __restrict__ ao)
{
    const int id = blockIdx.x;
    const int r8 = id & 7, t8 = id >> 3;
    const int bx = t8 % 25, b = r8 + 8*(t8/25);
    const int n0 = bx*8;
    const int tid = threadIdx.x, wv = tid>>6, ln = tid&63;
    const int fr = ln&15, fq = ln>>4;
    __shared__ float S[NHEAD*8*SMS];         // 51,200 B f32 scores
    __shared__ float s_pre[64], s_post[64];
    bf16* Sb = (bf16*)S;                     // P bf16 alias, row stride SBS=224 (448B)
    if (tid < 64){ s_pre[tid]=pre_w[tid]; s_post[tid]=post_w[tid]; }

    // ---- stage 1: raw scores scaled at write, 13 K-tiles, 2-deep k prefetch
    #pragma unroll
    for (int hh=0; hh<2; hh++){
        const int h = wv + hh*4;
        const float* iqh = inv + (size_t)(b*NHEAD+h)*NTOK;
        const float* ikh = inv + (size_t)NQK + (size_t)(b*NHEAD+h)*NTOK;
        float iqv[4];
        #pragma unroll
        for (int i=0;i<4;i++){
            int nidx = n0 + fq*4 + i; if (nidx > 196) nidx = 196;
            iqv[i] = iqh[nidx];
        }
        float ikv[13];
        #pragma unroll
        for (int mt=0; mt<13; mt++){
            int mc = mt*16 + fr; if (mc > 196) mc = 196;
            ikv[mt] = ikh[mc];      // 13 independent loads, all in flight together
        }
        int qr = n0 + fr; if (qr > 196) qr = 196;
        const bf16* qrow = q + ((size_t)(b*NHEAD+h)*NTOK + qr)*DHEAD + fq*8;
        bf16x8 a0 = *(const bf16x8*)(qrow);
        bf16x8 a1 = *(const bf16x8*)(qrow+32);
        bf16x8 a2 = *(const bf16x8*)(qrow+64);
        const bf16* kb0 = k + (size_t)(b*NHEAD+h)*NTOK*DHEAD + fq*8;
        auto krow = [&](int mt){ int nr = mt*16+fr; if (nr>196) nr=196; return kb0 + (size_t)nr*DHEAD; };
        const bf16* kp0 = krow(0);
        bf16x8 c00 = *(const bf16x8*)(kp0), c01 = *(const bf16x8*)(kp0+32), c02 = *(const bf16x8*)(kp0+64);
        const bf16* kp1 = krow(1);
        bf16x8 c10 = *(const bf16x8*)(kp1), c11 = *(const bf16x8*)(kp1+32), c12 = *(const bf16x8*)(kp1+64);
        #pragma unroll
        for (int mt=0; mt<13; mt++){
            bf16x8 p0, p1, p2;
            if (mt < 11){
                const bf16* kn = krow(mt+2);
                p0 = *(const bf16x8*)(kn); p1 = *(const bf16x8*)(kn+32); p2 = *(const bf16x8*)(kn+64);
            }
            f32x4 acc = {};
            acc = __builtin_amdgcn_mfma_f32_16x16x32_bf16(a0, c00, acc,0,0,0);
            acc = __builtin_amdgcn_mfma_f32_16x16x32_bf16(a1, c01, acc,0,0,0);
            acc = __builtin_amdgcn_mfma_f32_16x16x32_bf16(a2, c02, acc,0,0,0);
            int col = mt*16 + fr;
            if (fq < 2 && col < SMS){
                #pragma unroll
                for (int i=0;i<4;i++)
                    S[(h*8 + fq*4+i)*SMS + col] = acc[i]*iqv[i]*ikv[mt];
            }
            c00=c10; c01=c11; c02=c12;
            if (mt < 11){ c10=p0; c11=p1; c12=p2; }
        }
    }
    __syncthreads();

    // ---- stage 2: premix + premixed bias + geometric mask (cols 197..199 -> -1e9)
    {
        const int sco[8] = {1,1,4,4,7,7,1000,1000};
        const int nq = tid >> 5, l32 = tid & 31;
        int n = n0 + nq; if (n > 196) n = 196;
        const bool nAlways = (n == 0);
        int ri=0, ci=0;
        if (!nAlways){ ri=(n-1)/14; ci=(n-1)-ri*14; }
        for (int m = l32; m < SMS; m += 32){
            if (m >= 197){
                #pragma unroll
                for (int o=0;o<8;o++) S[(o*8+nq)*SMS+m] = -1e9f;
                continue;
            }
            bool always = nAlways || (m==0);
            int rj=0, cj=0;
            if (m > 0){ rj=(m-1)/14; cj=(m-1)-rj*14; }
            int dr = ri-rj; if (dr<0) dr=-dr;
            int dc = ci-cj; if (dc<0) dc=-dc;
            int idx = always ? 730 : (ri-rj+13)*27 + (ci-cj+13);
            const float* pv = p + idx*8;
            float sh[8];
            #pragma unroll
            for (int h2=0;h2<8;h2++) sh[h2] = S[(h2*8+nq)*SMS+m];
            float ov[8];
            #pragma unroll
            for (int o=0;o<8;o++){
                float v = pv[o];
                #pragma unroll
                for (int h2=0;h2<8;h2++) v += s_pre[o*8+h2]*sh[h2];
                bool on = always || (dr<=sco[o] && dc<=sco[o]);
                ov[o] = on ? v : -1e9f;
            }
            #pragma unroll
            for (int o=0;o<8;o++) S[(o*8+nq)*SMS+m] = ov[o];
        }
    }
    __syncthreads();

    // ---- stage 3: softmax per (o,nq) row over 200 cols — 16-lane groups, 4 rows/wave concurrent
    {
        const int g = ln >> 4, l16 = ln & 15;
        #pragma unroll
        for (int rr=0; rr<4; rr++){
            float* row = &S[(wv*16 + rr*4 + g)*SMS];
            float mx = -3e38f;
            for (int m=l16; m<SMS; m+=16) mx = fmaxf(mx, row[m]);
            #pragma unroll
            for (int off=8; off; off>>=1) mx = fmaxf(mx, __shfl_xor(mx,off,64));
            float sum = 0.f;
            for (int m=l16; m<SMS; m+=16){ float e=__expf(row[m]-mx); row[m]=e; sum+=e; }
            #pragma unroll
            for (int off=8; off; off>>=1) sum += __shfl_xor(sum,off,64);
            float inv2 = 1.f/sum;
            for (int m=l16; m<SMS; m+=16) row[m] *= inv2;
        }
    }
    __syncthreads();

    // ---- stage 3.5: postmix -> regs -> barrier -> bf16 P (stride SBS, pad cols zeroed)
    {
        const int nq = tid >> 5, l32 = tid & 31;
        float ov[7][8];
        #pragma unroll
        for (int kk=0; kk<7; kk++){
            int m = l32 + 32*kk;
            if (m < 197){
                float ph[8];
                #pragma unroll
                for (int o=0;o<8;o++) ph[o] = S[(o*8+nq)*SMS+m];
                #pragma unroll
                for (int o2=0;o2<8;o2++){
                    float v=0.f;
                    #pragma unroll
                    for (int o=0;o<8;o++) v += s_post[o2*8+o]*ph[o];
                    ov[kk][o2]=v;
                }
            }
        }
        __syncthreads();
        #pragma unroll
        for (int kk=0; kk<7; kk++){
            int m = l32 + 32*kk;   // covers 0..223 exactly
            #pragma unroll
            for (int o=0;o<8;o++)
                Sb[(o*8+nq)*SBS + m] = (m < 197) ? f2b(ov[kk][o]) : f2b(0.f);
        }
    }
    __syncthreads();

    // ---- stage 4: P @ V via MFMA; P frags hoisted, V double-buffered across dt
    const int frA = fr & 7;
    #pragma unroll
    for (int hh=0; hh<2; hh++){
        const int h = wv + hh*4;
        const bf16* vbase = vt + (size_t)(b*NHEAD+h)*DHEAD*VTS;
        bf16x8 pa[7];
        #pragma unroll
        for (int ks=0; ks<7; ks++)
            pa[ks] = *(const bf16x8*)(Sb + (h*8+frA)*SBS + ks*32 + fq*8);
        bf16x8 bv[7], bn[7];
        #pragma unroll
        for (int ks=0; ks<7; ks++)
            bv[ks] = *(const bf16x8*)(vbase + (size_t)fr*VTS + ks*32 + fq*8);
        #pragma unroll
        for (int dt=0; dt<6; dt++){
            if (dt < 5){
                #pragma unroll
                for (int ks=0; ks<7; ks++)
                    bn[ks] = *(const bf16x8*)(vbase + (size_t)((dt+1)*16+fr)*VTS + ks*32 + fq*8);
            }
            f32x4 acc = {};
            #pragma unroll
            for (int ks=0; ks<7; ks++)
                acc = __builtin_amdgcn_mfma_f32_16x16x32_bf16(pa[ks], bv[ks], acc,0,0,0);
            #pragma unroll
            for (int i=0;i<4;i++){
                int nqq = fq*4+i, n = n0+nqq;
                if (nqq < 8 && n < NTOK)
                    ao[((size_t)b*NTOK+n)*DIMC + h*DHEAD + dt*16+fr] = f2b(acc[i]);
            }
            #pragma unroll
            for (int ks=0; ks<7; ks++) bv[ks] = bn[ks];
        }
    }
}

// ---------------- m97-style MFMA GEMM: 128x128 tile, BK=64; 1D grid + bijective XCD swizzle (T1/m204)
enum { EPI_QKV=0, EPI_X1=1, EPI_GELU=2, EPI_OUT=3 };

template<int EPI>
__global__ __launch_bounds__(256) void gemm128(
    const bf16* __restrict__ A, int lda, int M,
    const bf16* __restrict__ B, int ldb,
    int K,
    const float* __restrict__ bias,
    const float* __restrict__ resid_f,  // X1: x (f32)
    const bf16* __restrict__ resid_b,   // OUT: x1b
    float* __restrict__ dst_f,          // OUT: final out
    bf16* __restrict__ dst_b, int lddb, // X1: x1b ; GELU: mid
    int row_off,                        // OUT: global row offset
    bf16* __restrict__ qo, bf16* __restrict__ ko, bf16* __restrict__ vto,
    int nbx)                            // x-tiles (N/128); grid is 1D = nbx*nby
{
    __shared__ bf16 As[2*128*32];   // two K-32 sub-tiles
    __shared__ bf16 Bs[2*128*32];
    const int tid = threadIdx.x;
    const int wv = tid >> 6, ln = tid & 63;
    const int fr = ln & 15, fq = ln >> 4;
    const int wr = (wv & 1)*64, wc = (wv >> 1)*64;
    // bijective XCD-chunk swizzle (m204): each XCD owns a contiguous wg range ->
    // blocks sharing an A-panel (same by) stay on one XCD's L2.
    const int nwgs = (int)gridDim.x;
    const int xcd = blockIdx.x & 7;
    const int qq = nwgs >> 3, rr = nwgs & 7;
    const int wg = (xcd < rr ? xcd*(qq+1) : rr*(qq+1) + (xcd-rr)*qq) + ((int)blockIdx.x >> 3);
    const int byi = wg / nbx, bxi = wg - byi*nbx;
    const int m0 = byi*128, n0 = bxi*128;
    const int lnrow = ln >> 2, lncol = (ln & 3)*8;
    f32x4 acc[4][4] = {};
    for (int k0=0; k0<K; k0+=64){
        #pragma unroll
        for (int t=0;t<2;t++){
            #pragma unroll
            for (int c=0;c<2;c++){
                int rA = m0 + (c*4+wv)*16 + lnrow;
                if (rA >= M) rA = M-1;
                gld16(A + (size_t)rA*lda + k0 + t*32 + lncol, &As[t*4096 + (c*4+wv)*16*32]);
                int rB = n0 + (c*4+wv)*16 + lnrow;
                gld16(B + (size_t)rB*ldb + k0 + t*32 + lncol, &Bs[t*4096 + (c*4+wv)*16*32]);
            }
        }
        __syncthreads();
        #pragma unroll
        for (int t=0;t<2;t++){
            bf16x8 af[4], bfv[4];
            #pragma unroll
            for (int i=0;i<4;i++){
                af[i]  = *(const bf16x8*)&As[t*4096 + (wr + i*16 + fr)*32 + fq*8];
                bfv[i] = *(const bf16x8*)&Bs[t*4096 + (wc + i*16 + fr)*32 + fq*8];
            }
            #pragma unroll
            for (int mi=0;mi<4;mi++)
                #pragma unroll
                for (int ni=0;ni<4;ni++)
                    acc[mi][ni] = __builtin_amdgcn_mfma_f32_16x16x32_bf16(af[mi], bfv[ni], acc[mi][ni],0,0,0);
        }
        __syncthreads();
    }
    #pragma unroll
    for (int mi=0;mi<4;mi++){
        #pragma unroll
        for (int ni=0;ni<4;ni++){
            #pragma unroll
            for (int i=0;i<4;i++){
                int row = m0 + wr + mi*16 + fq*4 + i;
                int col = n0 + wc + ni*16 + fr;
                if (row >= M) continue;
                float val = acc[mi][ni][i];
                if constexpr (EPI == EPI_QKV){
                    int which = col/768, rem = col - which*768;
                    int hh = rem/96, di = rem - hh*96;
                    int bb = row/NTOK, nn = row - bb*NTOK;
                    if (which == 0)      qo[(((size_t)bb*NHEAD+hh)*NTOK+nn)*DHEAD + di] = f2b(val);
                    else if (which == 1) ko[(((size_t)bb*NHEAD+hh)*NTOK+nn)*DHEAD + di] = f2b(val);
                    else {
                        vto[(((size_t)bb*NHEAD+hh)*DHEAD+di)*VTS + nn] = f2b(val);
                        if (nn < VTS - NTOK)   // fused vt pad-zero (cols 197..223)
                            vto[(((size_t)bb*NHEAD+hh)*DHEAD+di)*VTS + NTOK + nn] = f2b(0.f);
                    }
                } else if constexpr (EPI == EPI_X1){
                    dst_b[(size_t)row*DIMC + col] = f2b(val + bias[col] + resid_f[(size_t)row*DIMC + col]);
                } else if constexpr (EPI == EPI_GELU){
                    float t = val + bias[col];
                    t = 0.5f*t*(1.f + erff(t*0.70710678118654752f));
                    dst_b[(size_t)row*lddb + col] = f2b(t);
                } else { // EPI_OUT
                    size_t g = (size_t)(row + row_off)*DIMC + col;
                    dst_f[g] = val + bias[col] + b2f(resid_b[g]);
                }
            }
        }
    }
}

extern "C" void kernel_launch(void* const* d_in, const int* in_sizes, int n_in,
                              void* d_out, int out_size, void* d_ws, size_t ws_size,
                              hipStream_t stream)
{
    const float* x        = (const float*)d_in[0];
    const float* norm1_w  = (const float*)d_in[1];
    const float* norm1_b  = (const float*)d_in[2];
    const float* qkv_w    = (const float*)d_in[3];
    const float* scale    = (const float*)d_in[4];
    const float* pp_w     = (const float*)d_in[5];
    const float* pp_b     = (const float*)d_in[6];
    const float* ln1_w    = (const float*)d_in[7];
    const float* ln1_b    = (const float*)d_in[8];
    const float* fcp1_w   = (const float*)d_in[9];
    const float* fcp1_b   = (const float*)d_in[10];
    const float* ln2_w    = (const float*)d_in[11];
    const float* ln2_b    = (const float*)d_in[12];
    const float* fcp2_w   = (const float*)d_in[13];
    const float* fcp2_b   = (const float*)d_in[14];
    const float* ln3_w    = (const float*)d_in[15];
    const float* ln3_b    = (const float*)d_in[16];
    const float* fcp3_w   = (const float*)d_in[17];
    const float* fcp3_b   = (const float*)d_in[18];
    const float* pre_w    = (const float*)d_in[19];
    const float* post_w   = (const float*)d_in[20];
    const float* proj_w   = (const float*)d_in[21];
    const float* proj_b   = (const float*)d_in[22];
    const float* nrm2_w   = (const float*)d_in[23];
    const float* nrm2_b   = (const float*)d_in[24];
    const float* m1_w     = (const float*)d_in[25];
    const float* m1_b     = (const float*)d_in[26];
    const float* m2_w     = (const float*)d_in[27];
    const float* m2_b     = (const float*)d_in[28];
    const float* biases   = (const float*)d_in[30];
    float* out = (float*)d_out;

    char* ws = (char*)d_ws;
    float* p      = (float*)(ws + OFF_P);
    bf16*  qkvw_b = (bf16*)(ws + OFF_W);
    bf16*  prjw_b = (bf16*)(ws + OFF_W + SZ_QKVW);
    bf16*  m1w_b  = (bf16*)(ws + OFF_W + SZ_QKVW + SZ_PRJW);
    bf16*  m2w_b  = (bf16*)(ws + OFF_W + SZ_QKVW + SZ_PRJW + SZ_M1W);
    bf16*  h   = (bf16*)(ws + OFF_H);     // LN1 out -> ao -> mid (spans OFF_H..OFF_K)
    bf16*  qb  = (bf16*)(ws + OFF_Q);
    bf16*  kb  = (bf16*)(ws + OFF_K);     // -> h2
    bf16*  vt  = (bf16*)(ws + OFF_V);     // -> x1b
    float* inv = (float*)(ws + OFF_NRM);
    bf16*  ao  = (bf16*)(ws + OFF_H);
    bf16*  x1b = (bf16*)(ws + OFF_V);
    bf16*  h2  = (bf16*)(ws + OFF_K);
    bf16*  mid = (bf16*)(ws + OFF_H);     // 6304x3072 bf16 = 38.7MB

    w_cvt_all<<<6912, 256, 0, stream>>>(qkv_w, proj_w, m1_w, m2_w, qkvw_b);
    pos_mlp<<<841, 64, 0, stream>>>(biases, pp_w, pp_b, ln1_w, ln1_b, fcp1_w, fcp1_b,
                                    ln2_w, ln2_b, fcp2_w, fcp2_b, ln3_w, ln3_b, fcp3_w, fcp3_b,
                                    pre_w, p);
    ln768<float><<<NROWS, 256, 0, stream>>>(x, norm1_w, norm1_b, h);
    gemm128<EPI_QKV><<<18*99, 256, 0, stream>>>(
        h, DIMC, NROWS, qkvw_b, DIMC, DIMC, nullptr, nullptr, nullptr, nullptr,
        nullptr, 0, 0, qb, kb, vt, 18);
    qknorm<<<(2*NQK)/16, 256, 0, stream>>>(qb, kb, scale, inv);
    attn_mfma<<<1600, 256, 0, stream>>>(qb, kb, vt, p, inv, pre_w, post_w, ao);
    gemm128<EPI_X1><<<6*99, 256, 0, stream>>>(
        ao, DIMC, NROWS, prjw_b, DIMC, DIMC, proj_b, x, nullptr, nullptr,
        x1b, 0, 0, nullptr, nullptr, nullptr, 6);
    ln768<bf16><<<NROWS, 256, 0, stream>>>(x1b, nrm2_w, nrm2_b, h2);
    for (int c=0; c<2; c++){
        const int r0 = c*MHALF;
        gemm128<EPI_GELU><<<24*50, 256, 0, stream>>>(
            h2 + (size_t)r0*DIMC, DIMC, MHALF, m1w_b, DIMC, DIMC, m1_b,
            nullptr, nullptr, nullptr, mid, 3072, 0, nullptr, nullptr, nullptr, 24);
        gemm128<EPI_OUT><<<6*50, 256, 0, stream>>>(
            mid, 3072, MHALF, m2w_b, 3072, 3072, m2_b,
            nullptr, x1b, out, nullptr, 0, r0, nullptr, nullptr, nullptr, 6);
    }
    (void)in_sizes; (void)n_in; (void)out_size; (void)ws_size;
}